// Round 15
// baseline (248.358 us; speedup 1.0000x reference)
//
#include <hip/hip_runtime.h>
#include <math.h>

#define NN   4096
#define DIM  256
#define NE   131072
#define NH   4
#define DH   64
#define F1D  128
#define NG   16
#define AD   32

typedef unsigned short u16;
typedef unsigned int   u32;
typedef _Float16 f16;
typedef __attribute__((ext_vector_type(8))) _Float16 half8;
typedef __attribute__((ext_vector_type(4))) float f32x4;

enum { EPI_BIAS = 0, EPI_BNELU = 1 };
enum { MEPI_WO = 0, MEPI_FC1 = 1 };

#define MFMA16(a, b, c) __builtin_amdgcn_mfma_f32_16x16x32_f16(a, b, c, 0, 0, 0)

__device__ inline u16 f2h(float x) { union { f16 f; u16 u; } c; c.f = (f16)x; return c.u; }
// fp16 hi/lo split: x = hi + lo + eps, |eps| <= 2^-24 |x|  (fp32-grade)
__device__ inline void split16(float x, u16& h, u16& l) {
    union { f16 f; u16 u; } ch, cl;
    ch.f = (f16)x;
    cl.f = (f16)(x - (float)ch.f);
    h = ch.u; l = cl.u;
}

// ---------------- CSR build ----------------
__global__ void csr_count(const int* __restrict__ dst, int* __restrict__ cnt) {
    int e = blockIdx.x * 256 + threadIdx.x;
    atomicAdd(&cnt[dst[e]], 1);
}

__global__ __launch_bounds__(1024) void csr_scan(
    int* __restrict__ cnt, int* __restrict__ off)
{
    __shared__ int wsum[16];
    const int t = threadIdx.x;
    const int lane = t & 63;
    int4 v = *(const int4*)&cnt[t * 4];
    const int s = v.x + v.y + v.z + v.w;
    int acc = s;
    #pragma unroll
    for (int o = 1; o < 64; o <<= 1) {
        int u = __shfl_up(acc, o);
        if (lane >= o) acc += u;
    }
    if (lane == 63) wsum[t >> 6] = acc;
    __syncthreads();
    if (t < 16) {
        int w0 = wsum[t];
        int a2 = w0;
        #pragma unroll
        for (int o = 1; o < 16; o <<= 1) {
            int u = __shfl_up(a2, o);
            if (t >= o) a2 += u;
        }
        wsum[t] = a2 - w0;
    }
    __syncthreads();
    const int base = wsum[t >> 6] + (acc - s);
    off[t * 4 + 0] = base;
    off[t * 4 + 1] = base + v.x;
    off[t * 4 + 2] = base + v.x + v.y;
    off[t * 4 + 3] = base + v.x + v.y + v.z;
    *(int4*)&cnt[t * 4] = make_int4(0, 0, 0, 0);
    if (t == 1023) off[NN] = base + s;
}

__global__ void csr_fill(const int* __restrict__ dst, const int* __restrict__ src,
                         const float* __restrict__ eattr, const int* __restrict__ off,
                         int* __restrict__ cur, int* __restrict__ esrc,
                         float* __restrict__ ewt) {
    int e = blockIdx.x * 256 + threadIdx.x;
    int d = dst[e];
    int pos = off[d] + atomicAdd(&cur[d], 1);
    esrc[pos] = src[e];
    ewt[pos]  = eattr[e];
}

// ---------------- fused one-time prep: all weight/x converts + zero cur ----
__global__ __launch_bounds__(256) void prep_kernel(
    const float* __restrict__ x,
    const float* __restrict__ Ws, const float* __restrict__ Wn,
    const float* __restrict__ Wqkv, const float* __restrict__ Wo,
    const float* __restrict__ fc1W,
    u16* __restrict__ xh, u16* __restrict__ xl,
    u16* __restrict__ wch, u16* __restrict__ wcl,
    u16* __restrict__ w4h, u16* __restrict__ w4l,
    u16* __restrict__ f1h, u16* __restrict__ f1l,
    int* __restrict__ cur)
{
    const int b = blockIdx.x;
    const int t = threadIdx.x;
    if (b < 1024) {
        const int gid = b * 256 + t;
        const float4 v = *(const float4*)&x[(size_t)gid * 4];
        u16 h[4], l[4];
        split16(v.x, h[0], l[0]); split16(v.y, h[1], l[1]);
        split16(v.z, h[2], l[2]); split16(v.w, h[3], l[3]);
        *(uint2*)&xh[(size_t)gid * 4] =
            make_uint2((u32)h[0] | ((u32)h[1] << 16), (u32)h[2] | ((u32)h[3] << 16));
        *(uint2*)&xl[(size_t)gid * 4] =
            make_uint2((u32)l[0] | ((u32)l[1] << 16), (u32)l[2] | ((u32)l[3] << 16));
    } else if (b < 1408) {
        const int gid = (b - 1024) * 256 + t;
        const int L = gid / 32768;
        const int rem = gid % 32768;
        const int m = rem / 128;
        const int k4 = (rem % 128) * 4;
        const float* S = Ws + (size_t)L * 65536;
        const float* Nb = Wn + (size_t)L * 65536;
        u16 h[4], l[4];
        #pragma unroll
        for (int j = 0; j < 4; ++j) {
            const int k = k4 + j;
            const float v = (k < 256) ? S[(size_t)k * 256 + m]
                                      : Nb[(size_t)(k - 256) * 256 + m];
            split16(v, h[j], l[j]);
        }
        const size_t o = (size_t)L * 131072 + (size_t)m * 512 + k4;
        *(uint2*)&wch[o] = make_uint2((u32)h[0] | ((u32)h[1] << 16), (u32)h[2] | ((u32)h[3] << 16));
        *(uint2*)&wcl[o] = make_uint2((u32)l[0] | ((u32)l[1] << 16), (u32)l[2] | ((u32)l[3] << 16));
    } else if (b < 1664) {
        const int gid = (b - 1408) * 256 + t;
        const int mat = gid / 16384;
        const int rem = gid % 16384;
        const int m = rem / 64;
        const int k4 = (rem % 64) * 4;
        const float* W = (mat < 3) ? Wqkv + (size_t)mat * 65536 : Wo;
        u16 h[4], l[4];
        #pragma unroll
        for (int j = 0; j < 4; ++j)
            split16(W[(size_t)(k4 + j) * 256 + m], h[j], l[j]);
        const size_t o = (size_t)mat * 65536 + (size_t)m * 256 + k4;
        *(uint2*)&w4h[o] = make_uint2((u32)h[0] | ((u32)h[1] << 16), (u32)h[2] | ((u32)h[3] << 16));
        *(uint2*)&w4l[o] = make_uint2((u32)l[0] | ((u32)l[1] << 16), (u32)l[2] | ((u32)l[3] << 16));
    } else if (b < 1696) {
        const int gid = (b - 1664) * 256 + t;
        const int m = gid / 64;
        const int k4 = (gid % 64) * 4;
        u16 h[4], l[4];
        #pragma unroll
        for (int j = 0; j < 4; ++j)
            split16(fc1W[(size_t)(k4 + j) * F1D + m], h[j], l[j]);
        const size_t o = (size_t)m * 256 + k4;
        *(uint2*)&f1h[o] = make_uint2((u32)h[0] | ((u32)h[1] << 16), (u32)h[2] | ((u32)h[3] << 16));
        *(uint2*)&f1l[o] = make_uint2((u32)l[0] | ((u32)l[1] << 16), (u32)l[2] | ((u32)l[3] << 16));
    } else {
        const int gid = (b - 1696) * 256 + t;
        if (gid < NN / 4) *(int4*)&cur[gid * 4] = make_int4(0, 0, 0, 0);
    }
}

// ---------------- neighbor aggregation: 1 wave per node, fp16-plane out ---
template<bool LAST>
__global__ __launch_bounds__(256) void agg_kernel(
    const float* __restrict__ x, const int* __restrict__ esrc,
    const float* __restrict__ ewt, const int* __restrict__ off,
    u16* __restrict__ aggh, u16* __restrict__ aggl)
{
    const int node = blockIdx.x * 4 + (threadIdx.x >> 6);
    const int lane = threadIdx.x & 63;
    const int d4 = lane * 4;
    int j = off[node];
    const int j1 = off[node + 1];
    float4 acc = make_float4(0.f, 0.f, 0.f, 0.f);
    for (; j + 4 <= j1; j += 4) {
        const int s0 = esrc[j], s1 = esrc[j + 1], s2 = esrc[j + 2], s3 = esrc[j + 3];
        const float4 x0 = *(const float4*)&x[(size_t)s0 * DIM + d4];
        const float4 x1 = *(const float4*)&x[(size_t)s1 * DIM + d4];
        const float4 x2 = *(const float4*)&x[(size_t)s2 * DIM + d4];
        const float4 x3 = *(const float4*)&x[(size_t)s3 * DIM + d4];
        const float w0 = LAST ? ewt[j]     : 1.f;
        const float w1 = LAST ? ewt[j + 1] : 1.f;
        const float w2 = LAST ? ewt[j + 2] : 1.f;
        const float w3 = LAST ? ewt[j + 3] : 1.f;
        acc.x = fmaf(x0.x, w0, acc.x); acc.y = fmaf(x0.y, w0, acc.y);
        acc.z = fmaf(x0.z, w0, acc.z); acc.w = fmaf(x0.w, w0, acc.w);
        acc.x = fmaf(x1.x, w1, acc.x); acc.y = fmaf(x1.y, w1, acc.y);
        acc.z = fmaf(x1.z, w1, acc.z); acc.w = fmaf(x1.w, w1, acc.w);
        acc.x = fmaf(x2.x, w2, acc.x); acc.y = fmaf(x2.y, w2, acc.y);
        acc.z = fmaf(x2.z, w2, acc.z); acc.w = fmaf(x2.w, w2, acc.w);
        acc.x = fmaf(x3.x, w3, acc.x); acc.y = fmaf(x3.y, w3, acc.y);
        acc.z = fmaf(x3.z, w3, acc.z); acc.w = fmaf(x3.w, w3, acc.w);
    }
    for (; j < j1; ++j) {
        const int s = esrc[j];
        const float w = LAST ? ewt[j] : 1.f;
        const float4 xv = *(const float4*)&x[(size_t)s * DIM + d4];
        acc.x = fmaf(xv.x, w, acc.x); acc.y = fmaf(xv.y, w, acc.y);
        acc.z = fmaf(xv.z, w, acc.z); acc.w = fmaf(xv.w, w, acc.w);
    }
    u16 h[4], l[4];
    split16(acc.x, h[0], l[0]); split16(acc.y, h[1], l[1]);
    split16(acc.z, h[2], l[2]); split16(acc.w, h[3], l[3]);
    *(uint2*)&aggh[(size_t)node * DIM + d4] =
        make_uint2((u32)h[0] | ((u32)h[1] << 16), (u32)h[2] | ((u32)h[3] << 16));
    *(uint2*)&aggl[(size_t)node * DIM + d4] =
        make_uint2((u32)l[0] | ((u32)l[1] << 16), (u32)l[2] | ((u32)l[3] << 16));
}

// ---------------- conv MFMA GEMM: 32x64 tile (2 blocks/CU) ----------------
template<int EPI>
__global__ __launch_bounds__(256) void conv_mfma(
    const u16* __restrict__ xh, const u16* __restrict__ xl,
    const u16* __restrict__ gh, const u16* __restrict__ gl,
    const u16* __restrict__ bth, const u16* __restrict__ btl,
    const float* __restrict__ bias,
    const float* __restrict__ gamma, const float* __restrict__ beta,
    const float* __restrict__ bnmean, const float* __restrict__ bnvar,
    float* __restrict__ outf, u16* __restrict__ oh, u16* __restrict__ ol)
{
    __shared__ u16 lds[13824];           // 27648 B
    u16* As_h = lds;                     // [32][72]
    u16* As_l = lds + 2304;
    u16* Bs_h = lds + 4608;              // [64][72]
    u16* Bs_l = lds + 9216;
    #define TKP 72

    const int tid  = threadIdx.x;
    const int row0 = blockIdx.y * 32;
    const int col0 = blockIdx.x * 64;

    const int w   = tid >> 6;
    const int l15 = tid & 15, h4 = (tid & 63) >> 4;
    const int rh  = w & 1, ch = w >> 1;
    const int arow = tid >> 3, acs = (tid & 7) * 8;
    const int brow = tid & 63, bseg = tid >> 6;
    const int bc = bseg * 16;

    uint4 sah, sal, sbh0, sbh1, sbl0, sbl1;
    {
        sah = *((const uint4*)&xh[(size_t)(row0 + arow) * DIM + acs]);
        sal = *((const uint4*)&xl[(size_t)(row0 + arow) * DIM + acs]);
        const u16* pbh = bth + (size_t)(col0 + brow) * 512 + bc;
        const u16* pbl = btl + (size_t)(col0 + brow) * 512 + bc;
        sbh0 = ((const uint4*)pbh)[0]; sbh1 = ((const uint4*)pbh)[1];
        sbl0 = ((const uint4*)pbl)[0]; sbl1 = ((const uint4*)pbl)[1];
    }

    const f32x4 z4 = {0.f, 0.f, 0.f, 0.f};
    f32x4 acc[2] = {z4, z4};

    for (int kt = 0; kt < 8; ++kt) {
        *(uint4*)&As_h[arow * TKP + acs] = sah;
        *(uint4*)&As_l[arow * TKP + acs] = sal;
        *(uint4*)&Bs_h[brow * TKP + bc]     = sbh0;
        *(uint4*)&Bs_h[brow * TKP + bc + 8] = sbh1;
        *(uint4*)&Bs_l[brow * TKP + bc]     = sbl0;
        *(uint4*)&Bs_l[brow * TKP + bc + 8] = sbl1;
        if (kt + 1 < 8) {                 // early-issue prefetch
            const int kn = kt + 1;
            const u16 *pah, *pal;
            if (kn < 4) {
                pah = xh + (size_t)(row0 + arow) * DIM + kn * 64 + acs;
                pal = xl + (size_t)(row0 + arow) * DIM + kn * 64 + acs;
            } else {
                pah = gh + (size_t)(row0 + arow) * DIM + (kn - 4) * 64 + acs;
                pal = gl + (size_t)(row0 + arow) * DIM + (kn - 4) * 64 + acs;
            }
            sah = *((const uint4*)pah);
            sal = *((const uint4*)pal);
            const u16* pbh = bth + (size_t)(col0 + brow) * 512 + kn * 64 + bc;
            const u16* pbl = btl + (size_t)(col0 + brow) * 512 + kn * 64 + bc;
            sbh0 = ((const uint4*)pbh)[0]; sbh1 = ((const uint4*)pbh)[1];
            sbl0 = ((const uint4*)pbl)[0]; sbl1 = ((const uint4*)pbl)[1];
        }
        __syncthreads();

        __builtin_amdgcn_s_setprio(1);
        #pragma unroll
        for (int kc = 0; kc < 2; ++kc) {
            const int dc = kc * 32 + h4 * 8;
            half8 afh, afl, bfh[2], bfl[2];
            afh = *(const half8*)&As_h[(rh * 16 + l15) * TKP + dc];
            afl = *(const half8*)&As_l[(rh * 16 + l15) * TKP + dc];
            #pragma unroll
            for (int bb = 0; bb < 2; ++bb) {
                const int r = ch * 32 + bb * 16 + l15;
                bfh[bb] = *(const half8*)&Bs_h[r * TKP + dc];
                bfl[bb] = *(const half8*)&Bs_l[r * TKP + dc];
            }
            #pragma unroll
            for (int bb = 0; bb < 2; ++bb) {
                acc[bb] = MFMA16(afh, bfh[bb], acc[bb]);
                acc[bb] = MFMA16(afh, bfl[bb], acc[bb]);
                acc[bb] = MFMA16(afl, bfh[bb], acc[bb]);
            }
        }
        __builtin_amdgcn_s_setprio(0);
        __syncthreads();
    }

    #pragma unroll
    for (int bb = 0; bb < 2; ++bb) {
        const int c  = col0 + ch * 32 + bb * 16 + l15;
        const int r0 = row0 + rh * 16 + h4 * 4;
        #pragma unroll
        for (int i = 0; i < 4; ++i) {
            const int r = r0 + i;
            float t = acc[bb][i] + bias[c];
            if (EPI == EPI_BNELU) {
                t = gamma[c] * (t - bnmean[c]) * rsqrtf(bnvar[c] + 1e-5f) + beta[c];
                t = t > 0.f ? t : expm1f(t);
            }
            outf[(size_t)r * DIM + c] = t;
            u16 hh, ll;
            split16(t, hh, ll);
            oh[(size_t)r * DIM + c] = hh;
            ol[(size_t)r * DIM + c] = ll;
        }
    }
    #undef TKP
}

// ---------------- QKV MFMA GEMM (fp16 3-pass, early prefetch) -------------
__global__ __launch_bounds__(256) void qkv_mfma(
    const u16* __restrict__ xh, const u16* __restrict__ xl,
    const u16* __restrict__ wth, const u16* __restrict__ wtl,
    const float* __restrict__ bias,
    u16* __restrict__ qh_o, u16* __restrict__ ql_o,
    u16* __restrict__ kh_o, u16* __restrict__ kl_o,
    u16* __restrict__ vt_o)
{
    __shared__ u16 lds[4 * 4608];
    u16* As_h = lds;
    u16* As_l = lds + 4608;
    u16* Bs_h = lds + 9216;
    u16* Bs_l = lds + 13824;
    #define TKP 72

    const int tid  = threadIdx.x;
    const int row0 = blockIdx.y * 64;
    const int mat  = blockIdx.x >> 2;
    const int col0 = (blockIdx.x & 3) * 64;
    const float* biasp = bias + mat * DIM;

    const int w   = tid >> 6;
    const int l15 = tid & 15, h4 = (tid & 63) >> 4;
    const int rh  = w & 1, ch = w >> 1;
    const int lrow = tid & 63, lseg = tid >> 6;
    const int lc = lseg * 16;

    const size_t brow = (size_t)(mat * 256 + col0 + lrow) * 256;
    uint4 sah0, sah1, sal0, sal1, sbh0, sbh1, sbl0, sbl1;
    {
        const u16* pah = xh + (size_t)(row0 + lrow) * DIM + lc;
        const u16* pal = xl + (size_t)(row0 + lrow) * DIM + lc;
        sah0 = ((const uint4*)pah)[0]; sah1 = ((const uint4*)pah)[1];
        sal0 = ((const uint4*)pal)[0]; sal1 = ((const uint4*)pal)[1];
        sbh0 = ((const uint4*)(wth + brow + lc))[0]; sbh1 = ((const uint4*)(wth + brow + lc))[1];
        sbl0 = ((const uint4*)(wtl + brow + lc))[0]; sbl1 = ((const uint4*)(wtl + brow + lc))[1];
    }

    const f32x4 z4 = {0.f, 0.f, 0.f, 0.f};
    f32x4 acc[2][2] = {{z4, z4}, {z4, z4}};

    for (int kt = 0; kt < 4; ++kt) {
        *(uint4*)&As_h[lrow * TKP + lc]     = sah0;
        *(uint4*)&As_h[lrow * TKP + lc + 8] = sah1;
        *(uint4*)&As_l[lrow * TKP + lc]     = sal0;
        *(uint4*)&As_l[lrow * TKP + lc + 8] = sal1;
        *(uint4*)&Bs_h[lrow * TKP + lc]     = sbh0;
        *(uint4*)&Bs_h[lrow * TKP + lc + 8] = sbh1;
        *(uint4*)&Bs_l[lrow * TKP + lc]     = sbl0;
        *(uint4*)&Bs_l[lrow * TKP + lc + 8] = sbl1;
        if (kt + 1 < 4) {
            const int kb = (kt + 1) * 64 + lc;
            const u16* pah = xh + (size_t)(row0 + lrow) * DIM + kb;
            const u16* pal = xl + (size_t)(row0 + lrow) * DIM + kb;
            sah0 = ((const uint4*)pah)[0]; sah1 = ((const uint4*)pah)[1];
            sal0 = ((const uint4*)pal)[0]; sal1 = ((const uint4*)pal)[1];
            sbh0 = ((const uint4*)(wth + brow + kb))[0]; sbh1 = ((const uint4*)(wth + brow + kb))[1];
            sbl0 = ((const uint4*)(wtl + brow + kb))[0]; sbl1 = ((const uint4*)(wtl + brow + kb))[1];
        }
        __syncthreads();

        __builtin_amdgcn_s_setprio(1);
        #pragma unroll
        for (int kc = 0; kc < 2; ++kc) {
            const int dc = kc * 32 + h4 * 8;
            half8 afh[2], afl[2], bfh[2], bfl[2];
            #pragma unroll
            for (int ab = 0; ab < 2; ++ab) {
                const int r = rh * 32 + ab * 16 + l15;
                afh[ab] = *(const half8*)&As_h[r * TKP + dc];
                afl[ab] = *(const half8*)&As_l[r * TKP + dc];
            }
            #pragma unroll
            for (int bb = 0; bb < 2; ++bb) {
                const int r = ch * 32 + bb * 16 + l15;
                bfh[bb] = *(const half8*)&Bs_h[r * TKP + dc];
                bfl[bb] = *(const half8*)&Bs_l[r * TKP + dc];
            }
            #pragma unroll
            for (int ab = 0; ab < 2; ++ab)
                #pragma unroll
                for (int bb = 0; bb < 2; ++bb) {
                    acc[ab][bb] = MFMA16(afh[ab], bfh[bb], acc[ab][bb]);
                    acc[ab][bb] = MFMA16(afh[ab], bfl[bb], acc[ab][bb]);
                    acc[ab][bb] = MFMA16(afl[ab], bfh[bb], acc[ab][bb]);
                }
        }
        __builtin_amdgcn_s_setprio(0);
        __syncthreads();
    }

    const float s = (mat == 0) ? 0.125f : 1.0f;
    u16* oph = (mat == 0) ? qh_o : kh_o;
    u16* opl = (mat == 0) ? ql_o : kl_o;
    #pragma unroll
    for (int ab = 0; ab < 2; ++ab)
        #pragma unroll
        for (int bb = 0; bb < 2; ++bb) {
            const int c  = col0 + ch * 32 + bb * 16 + l15;
            const int r0 = row0 + rh * 32 + ab * 16 + h4 * 4;
            if (mat < 2) {
                #pragma unroll
                for (int i = 0; i < 4; ++i) {
                    const int r = r0 + i;
                    const float t = (acc[ab][bb][i] + biasp[c]) * s;
                    u16 hh, ll;
                    split16(t, hh, ll);
                    oph[(size_t)r * DIM + c] = hh;
                    opl[(size_t)r * DIM + c] = ll;
                }
            } else {
                u16 v[4];
                #pragma unroll
                for (int i = 0; i < 4; ++i)
                    v[i] = f2h(acc[ab][bb][i] + biasp[c]);
                *(uint2*)&vt_o[(size_t)c * NN + r0] =
                    make_uint2((u32)v[0] | ((u32)v[1] << 16), (u32)v[2] | ((u32)v[3] << 16));
            }
        }
    #undef TKP
}

// ---------------- MFMA fp16 GEMM, 32x64 tile (Wo / fc1) -------------------
// Same staging/fragment layout as conv_mfma (bit-identical per-output order).
template<int MEPI>
__global__ __launch_bounds__(256) void mfma_gemm32(
    const u16* __restrict__ Ah, const u16* __restrict__ Al,
    const u16* __restrict__ Bth, const u16* __restrict__ Btl,
    const float* __restrict__ bias, const float* __restrict__ resid,
    float* __restrict__ outf, u16* __restrict__ outh, u16* __restrict__ outl,
    int K, int M)
{
    __shared__ u16 lds[13824];           // 27648 B
    u16* As_h = lds;                     // [32][72]
    u16* As_l = lds + 2304;
    u16* Bs_h = lds + 4608;              // [64][72]
    u16* Bs_l = lds + 9216;
    #define TKP 72

    const int tid  = threadIdx.x;
    const int row0 = blockIdx.y * 32;
    const int col0 = blockIdx.x * 64;

    const int w   = tid >> 6;
    const int l15 = tid & 15, h4 = (tid & 63) >> 4;
    const int rh  = w & 1, ch = w >> 1;
    const int arow = tid >> 3, acs = (tid & 7) * 8;
    const int brow = tid & 63, bseg = tid >> 6;
    const int bc = bseg * 16;

    uint4 sah, sal, sbh0, sbh1, sbl0, sbl1;
    {
        sah = *((const uint4*)&Ah[(size_t)(row0 + arow) * K + acs]);
        sal = *((const uint4*)&Al[(size_t)(row0 + arow) * K + acs]);
        const u16* pbh = Bth + (size_t)(col0 + brow) * K + bc;
        const u16* pbl = Btl + (size_t)(col0 + brow) * K + bc;
        sbh0 = ((const uint4*)pbh)[0]; sbh1 = ((const uint4*)pbh)[1];
        sbl0 = ((const uint4*)pbl)[0]; sbl1 = ((const uint4*)pbl)[1];
    }

    const f32x4 z4 = {0.f, 0.f, 0.f, 0.f};
    f32x4 acc[2] = {z4, z4};
    const int NKT2 = K / 64;

    for (int kt = 0; kt < NKT2; ++kt) {
        *(uint4*)&As_h[arow * TKP + acs] = sah;
        *(uint4*)&As_l[arow * TKP + acs] = sal;
        *(uint4*)&Bs_h[brow * TKP + bc]     = sbh0;
        *(uint4*)&Bs_h[brow * TKP + bc + 8] = sbh1;
        *(uint4*)&Bs_l[brow * TKP + bc]     = sbl0;
        *(uint4*)&Bs_l[brow * TKP + bc + 8] = sbl1;
        if (kt + 1 < NKT2) {              // early-issue prefetch
            const int kb = (kt + 1) * 64;
            sah = *((const uint4*)&Ah[(size_t)(row0 + arow) * K + kb + acs]);
            sal = *((const uint4*)&Al[(size_t)(row0 + arow) * K + kb + acs]);
            const u16* pbh = Bth + (size_t)(col0 + brow) * K + kb + bc;
            const u16* pbl = Btl + (size_t)(col0 + brow) * K + kb + bc;
            sbh0 = ((const uint4*)pbh)[0]; sbh1 = ((const uint4*)pbh)[1];
            sbl0 = ((const uint4*)pbl)[0]; sbl1 = ((const uint4*)pbl)[1];
        }
        __syncthreads();

        __builtin_amdgcn_s_setprio(1);
        #pragma unroll
        for (int kc = 0; kc < 2; ++kc) {
            const int dc = kc * 32 + h4 * 8;
            half8 afh, afl, bfh[2], bfl[2];
            afh = *(const half8*)&As_h[(rh * 16 + l15) * TKP + dc];
            afl = *(const half8*)&As_l[(rh * 16 + l15) * TKP + dc];
            #pragma unroll
            for (int bb = 0; bb < 2; ++bb) {
                const int r = ch * 32 + bb * 16 + l15;
                bfh[bb] = *(const half8*)&Bs_h[r * TKP + dc];
                bfl[bb] = *(const half8*)&Bs_l[r * TKP + dc];
            }
            #pragma unroll
            for (int bb = 0; bb < 2; ++bb) {
                acc[bb] = MFMA16(afh, bfh[bb], acc[bb]);
                acc[bb] = MFMA16(afh, bfl[bb], acc[bb]);
                acc[bb] = MFMA16(afl, bfh[bb], acc[bb]);
            }
        }
        __builtin_amdgcn_s_setprio(0);
        __syncthreads();
    }

    #pragma unroll
    for (int bb = 0; bb < 2; ++bb) {
        const int c  = col0 + ch * 32 + bb * 16 + l15;
        const int r0 = row0 + rh * 16 + h4 * 4;
        #pragma unroll
        for (int i = 0; i < 4; ++i) {
            const int r = r0 + i;
            float t = acc[bb][i] + bias[c];
            if (MEPI == MEPI_WO) {
                t += resid[(size_t)r * M + c];
                u16 hh, ll;
                split16(t, hh, ll);
                outh[(size_t)r * M + c] = hh;
                outl[(size_t)r * M + c] = ll;
            } else {    // FC1: bias + ELU -> fp32 feats
                t = t > 0.f ? t : expm1f(t);
                outf[(size_t)r * M + c] = t;
            }
        }
    }
    #undef TKP
}

// ---------------- MFMA flash attention (round-15) -------------------------
// 8-wave QB=128, SINGLE-buffered K/V (2 barriers/tile) at 46.6 KB LDS ->
// 3 blocks/CU = 24 waves/CU (1.5x round-14 TLP). Early register prefetch
// of tile t+1 issued before the stage barrier. Defer-max (THR=8): skip
// rescale when the whole wave's tile max is within 8 of the running max.
#define QB 128
#define KB 64
#define NSPLIT 4
#define NKT (NN / KB)
#define KP 72

__global__ __launch_bounds__(512, 3) void attn_kernel(
    const u16* __restrict__ qhi, const u16* __restrict__ qlo,
    const u16* __restrict__ khi, const u16* __restrict__ klo,
    const u16* __restrict__ vT,
    float* __restrict__ op0, float* __restrict__ op1,
    float* __restrict__ op2, float* __restrict__ op3,
    float* __restrict__ mpart, float* __restrict__ lpart)
{
    __shared__ u16 lds[23296];            // 46592 B -> 3 blocks/CU
    u16* Kh = lds;                        // [64][72]
    u16* Kl = lds + 4608;
    u16* Vt = lds + 9216;                 // [d][k] per-head
    u16* Pb = lds + 13824;                // [128][72] P fp16 (wave-local rows)
    u16* Qh = lds;                        // overlay [128][72] (init phase only)
    u16* Ql = lds + 9216;                 // overlay (init phase only)
    float* frow = (float*)(lds + 23040);  // [128] rescale factors

    const int tid = threadIdx.x;
    const int h   = blockIdx.y;
    const int q0  = blockIdx.x * QB;
    const int sp  = blockIdx.z;
    const int kt0 = sp * (NKT / NSPLIT);  // 16 tiles/block
    const int kt1 = kt0 + NKT / NSPLIT;

    const int w   = tid >> 6;             // wave 0..7 -> q rows w*16..+15
    const int l15 = tid & 15, h4 = (tid & 63) >> 4;
    const int lrow = tid & 63, lseg = tid >> 6;   // staging: 8 segs x 8 u16
    const int gq8 = h * DH + lseg * 8;

    {   // stage Q (once, into overlay region): 128 rows x 64 d
        const int qrow = tid >> 2, qseg = tid & 3;
        const u16* s0 = qhi + (size_t)(q0 + qrow) * DIM + h * DH + qseg * 16;
        const u16* s1 = qlo + (size_t)(q0 + qrow) * DIM + h * DH + qseg * 16;
        uint4 a = ((const uint4*)s0)[0], b = ((const uint4*)s0)[1];
        uint4 c = ((const uint4*)s1)[0], d = ((const uint4*)s1)[1];
        *(uint4*)&Qh[qrow * KP + qseg * 16]     = a;
        *(uint4*)&Qh[qrow * KP + qseg * 16 + 8] = b;
        *(uint4*)&Ql[qrow * KP + qseg * 16]     = c;
        *(uint4*)&Ql[qrow * KP + qseg * 16 + 8] = d;
    }

    uint4 rk, rl, rv;                     // staging registers
    auto load_tile = [&](int kt_ld) {
        const int key0 = kt_ld * KB;
        rk = *(const uint4*)(khi + (size_t)(key0 + lrow) * DIM + gq8);
        rl = *(const uint4*)(klo + (size_t)(key0 + lrow) * DIM + gq8);
        rv = *(const uint4*)(vT + (size_t)(h * DH + lrow) * NN + key0 + lseg * 8);
    };
    load_tile(kt0);
    __syncthreads();                              // Q staged

    half8 qf[2][2];                               // [kc][hi/lo]
    #pragma unroll
    for (int kc = 0; kc < 2; ++kc) {
        const int r = w * 16 + l15;
        const int dc = kc * 32 + h4 * 8;
        qf[kc][0] = *(const half8*)&Qh[r * KP + dc];
        qf[kc][1] = *(const half8*)&Ql[r * KP + dc];
    }
    __syncthreads();                              // hoist done; overlay safe

    const f32x4 z4 = {0.f, 0.f, 0.f, 0.f};
    f32x4 oacc[4] = {z4, z4, z4, z4};             // d-blocks 0..3 for own 16 q
    float m_run[4], l_run[4];
    #pragma unroll
    for (int i = 0; i < 4; ++i) { m_run[i] = -3.0e38f; l_run[i] = 0.f; }

    for (int t = kt0; t < kt1; ++t) {
        // stage tile t (regs -> LDS), issue loads for t+1
        *(uint4*)&Kh[lrow * KP + lseg * 8] = rk;
        *(uint4*)&Kl[lrow * KP + lseg * 8] = rl;
        *(uint4*)&Vt[lrow * KP + lseg * 8] = rv;
        if (t + 1 < kt1) load_tile(t + 1);
        __syncthreads();                          // B1: tile staged

        // ---- S = Q K^T (3-pass fp16 hi/lo): 16 q-rows x 64 k per wave ----
        f32x4 sc[4] = {z4, z4, z4, z4};
        __builtin_amdgcn_s_setprio(1);
        #pragma unroll
        for (int kc = 0; kc < 2; ++kc) {
            const int dc = kc * 32 + h4 * 8;
            half8 kfh[4], kfl[4];
            #pragma unroll
            for (int kcb = 0; kcb < 4; ++kcb) {
                const int r = kcb * 16 + l15;
                kfh[kcb] = *(const half8*)&Kh[r * KP + dc];
                kfl[kcb] = *(const half8*)&Kl[r * KP + dc];
            }
            #pragma unroll
            for (int kcb = 0; kcb < 4; ++kcb) {
                sc[kcb] = MFMA16(qf[kc][0], kfh[kcb], sc[kcb]);
                sc[kcb] = MFMA16(qf[kc][0], kfl[kcb], sc[kcb]);
                sc[kcb] = MFMA16(qf[kc][1], kfh[kcb], sc[kcb]);
            }
        }
        __builtin_amdgcn_s_setprio(0);

        // ---- wave-local softmax with defer-max (THR=8) ----
        float pm[4];
        #pragma unroll
        for (int i = 0; i < 4; ++i) {
            float v = fmaxf(fmaxf(sc[0][i], sc[1][i]), fmaxf(sc[2][i], sc[3][i]));
            #pragma unroll
            for (int off = 1; off < 16; off <<= 1)
                v = fmaxf(v, __shfl_xor(v, off));
            pm[i] = v;
        }
        const int ok = (pm[0] - m_run[0] <= 8.f) && (pm[1] - m_run[1] <= 8.f) &&
                       (pm[2] - m_run[2] <= 8.f) && (pm[3] - m_run[3] <= 8.f);
        float p[4][4];
        if (__all(ok)) {
            // no rescale: keep old max (P bounded by e^8, fp16-safe)
            #pragma unroll
            for (int i = 0; i < 4; ++i) {
                p[0][i] = __expf(sc[0][i] - m_run[i]);
                p[1][i] = __expf(sc[1][i] - m_run[i]);
                p[2][i] = __expf(sc[2][i] - m_run[i]);
                p[3][i] = __expf(sc[3][i] - m_run[i]);
                float ls = (p[0][i] + p[1][i]) + (p[2][i] + p[3][i]);
                #pragma unroll
                for (int off = 1; off < 16; off <<= 1) ls += __shfl_xor(ls, off);
                l_run[i] += ls;
            }
        } else {
            float fr[4];
            #pragma unroll
            for (int i = 0; i < 4; ++i) {
                const float mnew = fmaxf(m_run[i], pm[i]);
                fr[i] = __expf(m_run[i] - mnew);
                m_run[i] = mnew;
                p[0][i] = __expf(sc[0][i] - mnew);
                p[1][i] = __expf(sc[1][i] - mnew);
                p[2][i] = __expf(sc[2][i] - mnew);
                p[3][i] = __expf(sc[3][i] - mnew);
                float ls = (p[0][i] + p[1][i]) + (p[2][i] + p[3][i]);
                #pragma unroll
                for (int off = 1; off < 16; off <<= 1) ls += __shfl_xor(ls, off);
                l_run[i] = l_run[i] * fr[i] + ls;
            }
            if (l15 == 0) {
                #pragma unroll
                for (int i = 0; i < 4; ++i)
                    frow[w * 16 + h4 * 4 + i] = fr[i];
            }
            // wave-local LDS: compiler waitcnt orders the read below
            const float frq = frow[w * 16 + l15];
            #pragma unroll
            for (int db = 0; db < 4; ++db) oacc[db] *= frq;
        }
        // P store (wave-local rows): rows w*16+h4*4+i, cols kcb*16+l15
        #pragma unroll
        for (int kcb = 0; kcb < 4; ++kcb) {
            const int kk = kcb * 16 + l15;
            #pragma unroll
            for (int i = 0; i < 4; ++i)
                Pb[(w * 16 + h4 * 4 + i) * KP + kk] = f2h(p[kcb][i]);
        }
        // ---- PV: wave-local (compiler orders Pb read-after-write) ----
        __builtin_amdgcn_s_setprio(1);
        #pragma unroll
        for (int kc = 0; kc < 2; ++kc) {
            const half8 pf = *(const half8*)&Pb[(w * 16 + l15) * KP + kc * 32 + h4 * 8];
            #pragma unroll
            for (int db = 0; db < 4; ++db) {
                const half8 vf = *(const half8*)&Vt[(db * 16 + l15) * KP + kc * 32 + h4 * 8];
                oacc[db] = MFMA16(vf, pf, oacc[db]);
            }
        }
        __builtin_amdgcn_s_setprio(0);
        __syncthreads();                          // B2: all reads done
    }

    float* ob = (sp == 0) ? op0 : ((sp == 1) ? op1 : ((sp == 2) ? op2 : op3));
    #pragma unroll
    for (int db = 0; db < 4; ++db)
        *(f32x4*)&ob[(size_t)(q0 + w * 16 + l15) * DIM + h * DH + db * 16 + h4 * 4] = oacc[db];
    if (l15 == 0) {
        #pragma unroll
        for (int i = 0; i < 4; ++i) {
            const int r = w * 16 + h4 * 4 + i;
            mpart[((size_t)sp * NN + q0 + r) * NH + h] = m_run[i];
            lpart[((size_t)sp * NN + q0 + r) * NH + h] = l_run[i];
        }
    }
}

// merge the 4 partials -> fp16 hi/lo planes (feeds the MFMA Wo GEMM)
__global__ __launch_bounds__(256) void attn_combine(
    const float* __restrict__ o0, const float* __restrict__ o1,
    const float* __restrict__ o2, const float* __restrict__ o3,
    const float* __restrict__ mp, const float* __restrict__ lp,
    u16* __restrict__ ohi, u16* __restrict__ olo)
{
    const int gid = blockIdx.x * 256 + threadIdx.x;
    const int row = gid >> 6;
    const int c4  = (gid & 63) * 4;
    const int h   = c4 >> 6;
    float m[4], wgt[4];
    #pragma unroll
    for (int z = 0; z < 4; ++z) m[z] = mp[((size_t)z * NN + row) * NH + h];
    const float M = fmaxf(fmaxf(m[0], m[1]), fmaxf(m[2], m[3]));
    float den = 0.f;
    #pragma unroll
    for (int z = 0; z < 4; ++z) {
        wgt[z] = __expf(m[z] - M);
        den += lp[((size_t)z * NN + row) * NH + h] * wgt[z];
    }
    const float inv = 1.f / den;
    const float4 a = *(const float4*)&o0[(size_t)row * DIM + c4];
    const float4 b = *(const float4*)&o1[(size_t)row * DIM + c4];
    const float4 c = *(const float4*)&o2[(size_t)row * DIM + c4];
    const float4 d = *(const float4*)&o3[(size_t)row * DIM + c4];
    float r[4];
    r[0] = (a.x * wgt[0] + b.x * wgt[1] + c.x * wgt[2] + d.x * wgt[3]) * inv;
    r[1] = (a.y * wgt[0] + b.y * wgt[1] + c.y * wgt[2] + d.y * wgt[3]) * inv;
    r[2] = (a.z * wgt[0] + b.z * wgt[1] + c.z * wgt[2] + d.z * wgt[3]) * inv;
    r[3] = (a.w * wgt[0] + b.w * wgt[1] + c.w * wgt[2] + d.w * wgt[3]) * inv;
    u16 hh[4], ll[4];
    #pragma unroll
    for (int j = 0; j < 4; ++j) split16(r[j], hh[j], ll[j]);
    *(uint2*)&ohi[(size_t)row * DIM + c4] =
        make_uint2((u32)hh[0] | ((u32)hh[1] << 16), (u32)hh[2] | ((u32)hh[3] << 16));
    *(uint2*)&olo[(size_t)row * DIM + c4] =
        make_uint2((u32)ll[0] | ((u32)ll[1] << 16), (u32)ll[2] | ((u32)ll[3] << 16));
}

// ---------------- per-node group adapter: 4 nodes per 256-thr block -------
__global__ __launch_bounds__(256) void adapter_kernel(
    const float* __restrict__ feats, const int* __restrict__ grp,
    const float* __restrict__ AW1, const float* __restrict__ Ab1,
    const float* __restrict__ AW2, const float* __restrict__ Ab2,
    float* __restrict__ out)
{
    const int wv = threadIdx.x >> 6;
    const int n = blockIdx.x * 4 + wv;
    const int lane = threadIdx.x & 63;
    __shared__ float f[4][F1D];
    f[wv][lane]      = feats[(size_t)n * F1D + lane];
    f[wv][lane + 64] = feats[(size_t)n * F1D + 64 + lane];
    // wave-local LDS: compiler waitcnt orders reads (no barrier needed)
    const int g = grp[n];
    const float* W1 = AW1 + (size_t)g * F1D * AD;
    const int a = lane & 31;
    const int half = lane >> 5;
    float hsum = 0.f;
    for (int d = 0; d < 64; ++d)
        hsum = fmaf(f[wv][half * 64 + d], W1[(half * 64 + d) * AD + a], hsum);
    hsum += __shfl_xor(hsum, 32);
    hsum = fmaxf(hsum + Ab1[g * AD + a], 0.f);
    float p = hsum * AW2[g * AD + a];
    #pragma unroll
    for (int mm = 1; mm < 32; mm <<= 1) p += __shfl_xor(p, mm);
    if (lane == 0) out[n] = p + Ab2[g];
}

// ---------------- host-side orchestration ----------------
extern "C" void kernel_launch(void* const* d_in, const int* in_sizes, int n_in,
                              void* d_out, int out_size, void* d_ws, size_t ws_size,
                              hipStream_t stream)
{
    const float* x_in   = (const float*)d_in[0];
    const float* eattr  = (const float*)d_in[1];
    const float* Wself  = (const float*)d_in[2];
    const float* Wnbr   = (const float*)d_in[3];
    const float* convb  = (const float*)d_in[4];
    const float* gamma  = (const float*)d_in[5];
    const float* beta   = (const float*)d_in[6];
    const float* bnmean = (const float*)d_in[7];
    const float* bnvar  = (const float*)d_in[8];
    const float* Wqkv   = (const float*)d_in[9];
    const float* bqkv   = (const float*)d_in[10];
    const float* Wo     = (const float*)d_in[11];
    const float* bo     = (const float*)d_in[12];
    const float* fc1W   = (const float*)d_in[13];
    const float* fc1b   = (const float*)d_in[14];
    const float* AW1    = (const float*)d_in[15];
    const float* Ab1    = (const float*)d_in[16];
    const float* AW2    = (const float*)d_in[17];
    const float* Ab2    = (const float*)d_in[18];
    const int*   eidx   = (const int*)d_in[19];
    const int*   grp    = (const int*)d_in[20];
    const int* srcArr = eidx;
    const int* dstArr = eidx + NE;

    float* fws = (float*)d_ws;
    const size_t NM = (size_t)NN * DIM;
    float* bufA  = fws;                  // x L0 / x L2 (residual)
    float* bufB  = fws + NM;             // attn op0
    float* bufC  = fws + 2 * NM;         // x L1 / attn op1
    float* feats = fws + 3 * NM;         // NN x F1D
    float* mpart = fws + 3 * NM + NM / 2;         // [4][NN][NH]
    float* lpart = mpart + 4 * NN * NH;
    u16* up = (u16*)(lpart + 4 * NN * NH);
    u16* xpAh = up;             u16* xpAl = xpAh + NM;   // x planes ping
    u16* xpBh = xpAl + NM;      u16* xpBl = xpBh + NM;   // x planes pong
    u16* aggh = xpBl + NM;      u16* aggl = aggh + NM;   // agg planes
    u16* qh = aggl + NM;        u16* ql = qh + NM;       // Q planes / combine out
    u16* kh = ql + NM;          u16* kl = kh + NM;       // K planes / Wo out
    u16* vt = kl + NM;                                   // V^T fp16 [256][NN]
    u16* wcath = vt + NM;                                // [3][256][512]
    u16* wcatl = wcath + 3 * 131072;
    u16* wt4h  = wcatl + 3 * 131072;                     // [4][256][256] qkv+wo
    u16* wt4l  = wt4h + 4 * 65536;
    u16* fc1h  = wt4l + 4 * 65536;                       // [128][256]
    u16* fc1l  = fc1h + 32768;
    int*   esrc = (int*)(fc1l + 32768);                  // NE
    float* ewt  = (float*)(esrc + NE);                   // NE
    int* off    = (int*)(ewt + NE);                      // NN+1
    int* cur    = off + NN + 1;                          // NN
    float* outp = (float*)d_out;

    float* op2 = (float*)xpAh;           // attn partial overlays
    float* op3 = (float*)xpBh;

    // fused prep: all converts + zero(cur)
    prep_kernel<<<1700, 256, 0, stream>>>(
        x_in, Wself, Wnbr, Wqkv, Wo, fc1W,
        xpAh, xpAl, wcath, wcatl, wt4h, wt4l, fc1h, fc1l, cur);

    // CSR build (csr_scan zeroes cur for csr_fill)
    csr_count<<<NE / 256, 256, 0, stream>>>(dstArr, cur);
    csr_scan<<<1, 1024, 0, stream>>>(cur, off);
    csr_fill<<<NE / 256, 256, 0, stream>>>(dstArr, srcArr, eattr, off, cur, esrc, ewt);

    const dim3 gc(DIM / 64, NN / 32);    // 32-row conv tiles: 512 blocks
    const int rgrid = NN * DIM / 4 / 256;

    // conv layer 0: x_in -> bufA (fp32) + xpB planes
    agg_kernel<false><<<NN / 4, 256, 0, stream>>>(x_in, esrc, ewt, off, aggh, aggl);
    conv_mfma<EPI_BNELU><<<gc, 256, 0, stream>>>(
        xpAh, xpAl, aggh, aggl, wcath, wcatl, convb,
        gamma, beta, bnmean, bnvar, bufA, xpBh, xpBl);
    // conv layer 1: bufA -> bufC + xpA planes
    agg_kernel<false><<<NN / 4, 256, 0, stream>>>(bufA, esrc, ewt, off, aggh, aggl);
    conv_mfma<EPI_BNELU><<<gc, 256, 0, stream>>>(
        xpBh, xpBl, aggh, aggl, wcath + 131072, wcatl + 131072, convb + DIM,
        gamma + DIM, beta + DIM, bnmean + DIM, bnvar + DIM, bufC, xpAh, xpAl);
    // conv layer 2 (edge-weighted, bias only): bufC -> bufA + xpB planes
    agg_kernel<true><<<NN / 4, 256, 0, stream>>>(bufC, esrc, ewt, off, aggh, aggl);
    conv_mfma<EPI_BIAS><<<gc, 256, 0, stream>>>(
        xpAh, xpAl, aggh, aggl, wcath + 262144, wcatl + 262144, convb + 2 * DIM,
        nullptr, nullptr, nullptr, nullptr, bufA, xpBh, xpBl);

    // QKV (fp16 3-pass MFMA) -> Q/K planes (Q/8) + V^T
    qkv_mfma<<<dim3(12, NN / 64), 256, 0, stream>>>(
        xpBh, xpBl, wt4h, wt4l, bqkv, qh, ql, kh, kl, vt);

    // flash attention (8-wave QB=128, 4-way key split) -> partials -> combine
    attn_kernel<<<dim3(NN / QB, NH, NSPLIT), 512, 0, stream>>>(
        qh, ql, kh, kl, vt, bufB, bufC, op2, op3, mpart, lpart);
    attn_combine<<<rgrid, 256, 0, stream>>>(
        bufB, bufC, op2, op3, mpart, lpart, qh, ql);

    // Wo + residual (fp16 3-pass MFMA, 32x64 tiles): kh/kl = planes(...)
    mfma_gemm32<MEPI_WO><<<dim3(DIM / 64, NN / 32), 256, 0, stream>>>(
        qh, ql, wt4h + 3 * 65536, wt4l + 3 * 65536, bo, bufA,
        nullptr, kh, kl, DIM, DIM);

    // fc1 + ELU (fp16 3-pass MFMA, 32x64 tiles): feats = elu(x' @ fc1W + fc1b)
    mfma_gemm32<MEPI_FC1><<<dim3(F1D / 64, NN / 32), 256, 0, stream>>>(
        kh, kl, fc1h, fc1l, fc1b, nullptr, feats, nullptr, nullptr, DIM, F1D);

    // adapter routing -> out
    adapter_kernel<<<NN / 4, 256, 0, stream>>>(feats, grp, AW1, Ab1, AW2, Ab2, outp);
}

// Round 16
// 233.749 us; speedup vs baseline: 1.0625x; 1.0625x over previous
//
#include <hip/hip_runtime.h>
#include <math.h>

#define NN   4096
#define DIM  256
#define NE   131072
#define NH   4
#define DH   64
#define F1D  128
#define NG   16
#define AD   32

typedef unsigned short u16;
typedef unsigned int   u32;
typedef _Float16 f16;
typedef __attribute__((ext_vector_type(8))) _Float16 half8;
typedef __attribute__((ext_vector_type(4))) float f32x4;

enum { EPI_BIAS = 0, EPI_BNELU = 1 };
enum { MEPI_WO = 0, MEPI_FC1 = 1 };

#define MFMA16(a, b, c) __builtin_amdgcn_mfma_f32_16x16x32_f16(a, b, c, 0, 0, 0)

__device__ inline u16 f2h(float x) { union { f16 f; u16 u; } c; c.f = (f16)x; return c.u; }
// fp16 hi/lo split: x = hi + lo + eps, |eps| <= 2^-24 |x|  (fp32-grade)
__device__ inline void split16(float x, u16& h, u16& l) {
    union { f16 f; u16 u; } ch, cl;
    ch.f = (f16)x;
    cl.f = (f16)(x - (float)ch.f);
    h = ch.u; l = cl.u;
}

// ---------------- CSR build ----------------
__global__ void csr_count(const int* __restrict__ dst, int* __restrict__ cnt) {
    int e = blockIdx.x * 256 + threadIdx.x;
    atomicAdd(&cnt[dst[e]], 1);
}

__global__ __launch_bounds__(1024) void csr_scan(
    int* __restrict__ cnt, int* __restrict__ off)
{
    __shared__ int wsum[16];
    const int t = threadIdx.x;
    const int lane = t & 63;
    int4 v = *(const int4*)&cnt[t * 4];
    const int s = v.x + v.y + v.z + v.w;
    int acc = s;
    #pragma unroll
    for (int o = 1; o < 64; o <<= 1) {
        int u = __shfl_up(acc, o);
        if (lane >= o) acc += u;
    }
    if (lane == 63) wsum[t >> 6] = acc;
    __syncthreads();
    if (t < 16) {
        int w0 = wsum[t];
        int a2 = w0;
        #pragma unroll
        for (int o = 1; o < 16; o <<= 1) {
            int u = __shfl_up(a2, o);
            if (t >= o) a2 += u;
        }
        wsum[t] = a2 - w0;
    }
    __syncthreads();
    const int base = wsum[t >> 6] + (acc - s);
    off[t * 4 + 0] = base;
    off[t * 4 + 1] = base + v.x;
    off[t * 4 + 2] = base + v.x + v.y;
    off[t * 4 + 3] = base + v.x + v.y + v.z;
    *(int4*)&cnt[t * 4] = make_int4(0, 0, 0, 0);
    if (t == 1023) off[NN] = base + s;
}

__global__ void csr_fill(const int* __restrict__ dst, const int* __restrict__ src,
                         const float* __restrict__ eattr, const int* __restrict__ off,
                         int* __restrict__ cur, int* __restrict__ esrc,
                         float* __restrict__ ewt) {
    int e = blockIdx.x * 256 + threadIdx.x;
    int d = dst[e];
    int pos = off[d] + atomicAdd(&cur[d], 1);
    esrc[pos] = src[e];
    ewt[pos]  = eattr[e];
}

// ---------------- fused one-time prep: all weight/x converts + zero cur ----
__global__ __launch_bounds__(256) void prep_kernel(
    const float* __restrict__ x,
    const float* __restrict__ Ws, const float* __restrict__ Wn,
    const float* __restrict__ Wqkv, const float* __restrict__ Wo,
    const float* __restrict__ fc1W,
    u16* __restrict__ xh, u16* __restrict__ xl,
    u16* __restrict__ wch, u16* __restrict__ wcl,
    u16* __restrict__ w4h, u16* __restrict__ w4l,
    u16* __restrict__ f1h, u16* __restrict__ f1l,
    int* __restrict__ cur)
{
    const int b = blockIdx.x;
    const int t = threadIdx.x;
    if (b < 1024) {
        const int gid = b * 256 + t;
        const float4 v = *(const float4*)&x[(size_t)gid * 4];
        u16 h[4], l[4];
        split16(v.x, h[0], l[0]); split16(v.y, h[1], l[1]);
        split16(v.z, h[2], l[2]); split16(v.w, h[3], l[3]);
        *(uint2*)&xh[(size_t)gid * 4] =
            make_uint2((u32)h[0] | ((u32)h[1] << 16), (u32)h[2] | ((u32)h[3] << 16));
        *(uint2*)&xl[(size_t)gid * 4] =
            make_uint2((u32)l[0] | ((u32)l[1] << 16), (u32)l[2] | ((u32)l[3] << 16));
    } else if (b < 1408) {
        const int gid = (b - 1024) * 256 + t;
        const int L = gid / 32768;
        const int rem = gid % 32768;
        const int m = rem / 128;
        const int k4 = (rem % 128) * 4;
        const float* S = Ws + (size_t)L * 65536;
        const float* Nb = Wn + (size_t)L * 65536;
        u16 h[4], l[4];
        #pragma unroll
        for (int j = 0; j < 4; ++j) {
            const int k = k4 + j;
            const float v = (k < 256) ? S[(size_t)k * 256 + m]
                                      : Nb[(size_t)(k - 256) * 256 + m];
            split16(v, h[j], l[j]);
        }
        const size_t o = (size_t)L * 131072 + (size_t)m * 512 + k4;
        *(uint2*)&wch[o] = make_uint2((u32)h[0] | ((u32)h[1] << 16), (u32)h[2] | ((u32)h[3] << 16));
        *(uint2*)&wcl[o] = make_uint2((u32)l[0] | ((u32)l[1] << 16), (u32)l[2] | ((u32)l[3] << 16));
    } else if (b < 1664) {
        const int gid = (b - 1408) * 256 + t;
        const int mat = gid / 16384;
        const int rem = gid % 16384;
        const int m = rem / 64;
        const int k4 = (rem % 64) * 4;
        const float* W = (mat < 3) ? Wqkv + (size_t)mat * 65536 : Wo;
        u16 h[4], l[4];
        #pragma unroll
        for (int j = 0; j < 4; ++j)
            split16(W[(size_t)(k4 + j) * 256 + m], h[j], l[j]);
        const size_t o = (size_t)mat * 65536 + (size_t)m * 256 + k4;
        *(uint2*)&w4h[o] = make_uint2((u32)h[0] | ((u32)h[1] << 16), (u32)h[2] | ((u32)h[3] << 16));
        *(uint2*)&w4l[o] = make_uint2((u32)l[0] | ((u32)l[1] << 16), (u32)l[2] | ((u32)l[3] << 16));
    } else if (b < 1696) {
        const int gid = (b - 1664) * 256 + t;
        const int m = gid / 64;
        const int k4 = (gid % 64) * 4;
        u16 h[4], l[4];
        #pragma unroll
        for (int j = 0; j < 4; ++j)
            split16(fc1W[(size_t)(k4 + j) * F1D + m], h[j], l[j]);
        const size_t o = (size_t)m * 256 + k4;
        *(uint2*)&f1h[o] = make_uint2((u32)h[0] | ((u32)h[1] << 16), (u32)h[2] | ((u32)h[3] << 16));
        *(uint2*)&f1l[o] = make_uint2((u32)l[0] | ((u32)l[1] << 16), (u32)l[2] | ((u32)l[3] << 16));
    } else {
        const int gid = (b - 1696) * 256 + t;
        if (gid < NN / 4) *(int4*)&cur[gid * 4] = make_int4(0, 0, 0, 0);
    }
}

// ---------------- neighbor aggregation: 1 wave per node, fp16-plane out ---
template<bool LAST>
__global__ __launch_bounds__(256) void agg_kernel(
    const float* __restrict__ x, const int* __restrict__ esrc,
    const float* __restrict__ ewt, const int* __restrict__ off,
    u16* __restrict__ aggh, u16* __restrict__ aggl)
{
    const int node = blockIdx.x * 4 + (threadIdx.x >> 6);
    const int lane = threadIdx.x & 63;
    const int d4 = lane * 4;
    int j = off[node];
    const int j1 = off[node + 1];
    float4 acc = make_float4(0.f, 0.f, 0.f, 0.f);
    for (; j + 4 <= j1; j += 4) {
        const int s0 = esrc[j], s1 = esrc[j + 1], s2 = esrc[j + 2], s3 = esrc[j + 3];
        const float4 x0 = *(const float4*)&x[(size_t)s0 * DIM + d4];
        const float4 x1 = *(const float4*)&x[(size_t)s1 * DIM + d4];
        const float4 x2 = *(const float4*)&x[(size_t)s2 * DIM + d4];
        const float4 x3 = *(const float4*)&x[(size_t)s3 * DIM + d4];
        const float w0 = LAST ? ewt[j]     : 1.f;
        const float w1 = LAST ? ewt[j + 1] : 1.f;
        const float w2 = LAST ? ewt[j + 2] : 1.f;
        const float w3 = LAST ? ewt[j + 3] : 1.f;
        acc.x = fmaf(x0.x, w0, acc.x); acc.y = fmaf(x0.y, w0, acc.y);
        acc.z = fmaf(x0.z, w0, acc.z); acc.w = fmaf(x0.w, w0, acc.w);
        acc.x = fmaf(x1.x, w1, acc.x); acc.y = fmaf(x1.y, w1, acc.y);
        acc.z = fmaf(x1.z, w1, acc.z); acc.w = fmaf(x1.w, w1, acc.w);
        acc.x = fmaf(x2.x, w2, acc.x); acc.y = fmaf(x2.y, w2, acc.y);
        acc.z = fmaf(x2.z, w2, acc.z); acc.w = fmaf(x2.w, w2, acc.w);
        acc.x = fmaf(x3.x, w3, acc.x); acc.y = fmaf(x3.y, w3, acc.y);
        acc.z = fmaf(x3.z, w3, acc.z); acc.w = fmaf(x3.w, w3, acc.w);
    }
    for (; j < j1; ++j) {
        const int s = esrc[j];
        const float w = LAST ? ewt[j] : 1.f;
        const float4 xv = *(const float4*)&x[(size_t)s * DIM + d4];
        acc.x = fmaf(xv.x, w, acc.x); acc.y = fmaf(xv.y, w, acc.y);
        acc.z = fmaf(xv.z, w, acc.z); acc.w = fmaf(xv.w, w, acc.w);
    }
    u16 h[4], l[4];
    split16(acc.x, h[0], l[0]); split16(acc.y, h[1], l[1]);
    split16(acc.z, h[2], l[2]); split16(acc.w, h[3], l[3]);
    *(uint2*)&aggh[(size_t)node * DIM + d4] =
        make_uint2((u32)h[0] | ((u32)h[1] << 16), (u32)h[2] | ((u32)h[3] << 16));
    *(uint2*)&aggl[(size_t)node * DIM + d4] =
        make_uint2((u32)l[0] | ((u32)l[1] << 16), (u32)l[2] | ((u32)l[3] << 16));
}

// ---------------- conv MFMA GEMM: 32x64 tile (2 blocks/CU) ----------------
template<int EPI>
__global__ __launch_bounds__(256) void conv_mfma(
    const u16* __restrict__ xh, const u16* __restrict__ xl,
    const u16* __restrict__ gh, const u16* __restrict__ gl,
    const u16* __restrict__ bth, const u16* __restrict__ btl,
    const float* __restrict__ bias,
    const float* __restrict__ gamma, const float* __restrict__ beta,
    const float* __restrict__ bnmean, const float* __restrict__ bnvar,
    float* __restrict__ outf, u16* __restrict__ oh, u16* __restrict__ ol)
{
    __shared__ u16 lds[13824];           // 27648 B
    u16* As_h = lds;                     // [32][72]
    u16* As_l = lds + 2304;
    u16* Bs_h = lds + 4608;              // [64][72]
    u16* Bs_l = lds + 9216;
    #define TKP 72

    const int tid  = threadIdx.x;
    const int row0 = blockIdx.y * 32;
    const int col0 = blockIdx.x * 64;

    const int w   = tid >> 6;
    const int l15 = tid & 15, h4 = (tid & 63) >> 4;
    const int rh  = w & 1, ch = w >> 1;
    const int arow = tid >> 3, acs = (tid & 7) * 8;
    const int brow = tid & 63, bseg = tid >> 6;
    const int bc = bseg * 16;

    uint4 sah, sal, sbh0, sbh1, sbl0, sbl1;
    {
        sah = *((const uint4*)&xh[(size_t)(row0 + arow) * DIM + acs]);
        sal = *((const uint4*)&xl[(size_t)(row0 + arow) * DIM + acs]);
        const u16* pbh = bth + (size_t)(col0 + brow) * 512 + bc;
        const u16* pbl = btl + (size_t)(col0 + brow) * 512 + bc;
        sbh0 = ((const uint4*)pbh)[0]; sbh1 = ((const uint4*)pbh)[1];
        sbl0 = ((const uint4*)pbl)[0]; sbl1 = ((const uint4*)pbl)[1];
    }

    const f32x4 z4 = {0.f, 0.f, 0.f, 0.f};
    f32x4 acc[2] = {z4, z4};

    for (int kt = 0; kt < 8; ++kt) {
        *(uint4*)&As_h[arow * TKP + acs] = sah;
        *(uint4*)&As_l[arow * TKP + acs] = sal;
        *(uint4*)&Bs_h[brow * TKP + bc]     = sbh0;
        *(uint4*)&Bs_h[brow * TKP + bc + 8] = sbh1;
        *(uint4*)&Bs_l[brow * TKP + bc]     = sbl0;
        *(uint4*)&Bs_l[brow * TKP + bc + 8] = sbl1;
        if (kt + 1 < 8) {                 // early-issue prefetch
            const int kn = kt + 1;
            const u16 *pah, *pal;
            if (kn < 4) {
                pah = xh + (size_t)(row0 + arow) * DIM + kn * 64 + acs;
                pal = xl + (size_t)(row0 + arow) * DIM + kn * 64 + acs;
            } else {
                pah = gh + (size_t)(row0 + arow) * DIM + (kn - 4) * 64 + acs;
                pal = gl + (size_t)(row0 + arow) * DIM + (kn - 4) * 64 + acs;
            }
            sah = *((const uint4*)pah);
            sal = *((const uint4*)pal);
            const u16* pbh = bth + (size_t)(col0 + brow) * 512 + kn * 64 + bc;
            const u16* pbl = btl + (size_t)(col0 + brow) * 512 + kn * 64 + bc;
            sbh0 = ((const uint4*)pbh)[0]; sbh1 = ((const uint4*)pbh)[1];
            sbl0 = ((const uint4*)pbl)[0]; sbl1 = ((const uint4*)pbl)[1];
        }
        __syncthreads();

        __builtin_amdgcn_s_setprio(1);
        #pragma unroll
        for (int kc = 0; kc < 2; ++kc) {
            const int dc = kc * 32 + h4 * 8;
            half8 afh, afl, bfh[2], bfl[2];
            afh = *(const half8*)&As_h[(rh * 16 + l15) * TKP + dc];
            afl = *(const half8*)&As_l[(rh * 16 + l15) * TKP + dc];
            #pragma unroll
            for (int bb = 0; bb < 2; ++bb) {
                const int r = ch * 32 + bb * 16 + l15;
                bfh[bb] = *(const half8*)&Bs_h[r * TKP + dc];
                bfl[bb] = *(const half8*)&Bs_l[r * TKP + dc];
            }
            #pragma unroll
            for (int bb = 0; bb < 2; ++bb) {
                acc[bb] = MFMA16(afh, bfh[bb], acc[bb]);
                acc[bb] = MFMA16(afh, bfl[bb], acc[bb]);
                acc[bb] = MFMA16(afl, bfh[bb], acc[bb]);
            }
        }
        __builtin_amdgcn_s_setprio(0);
        __syncthreads();
    }

    #pragma unroll
    for (int bb = 0; bb < 2; ++bb) {
        const int c  = col0 + ch * 32 + bb * 16 + l15;
        const int r0 = row0 + rh * 16 + h4 * 4;
        #pragma unroll
        for (int i = 0; i < 4; ++i) {
            const int r = r0 + i;
            float t = acc[bb][i] + bias[c];
            if (EPI == EPI_BNELU) {
                t = gamma[c] * (t - bnmean[c]) * rsqrtf(bnvar[c] + 1e-5f) + beta[c];
                t = t > 0.f ? t : expm1f(t);
            }
            outf[(size_t)r * DIM + c] = t;
            u16 hh, ll;
            split16(t, hh, ll);
            oh[(size_t)r * DIM + c] = hh;
            ol[(size_t)r * DIM + c] = ll;
        }
    }
    #undef TKP
}

// ---------------- QKV MFMA GEMM (fp16 3-pass, early prefetch) -------------
__global__ __launch_bounds__(256) void qkv_mfma(
    const u16* __restrict__ xh, const u16* __restrict__ xl,
    const u16* __restrict__ wth, const u16* __restrict__ wtl,
    const float* __restrict__ bias,
    u16* __restrict__ qh_o, u16* __restrict__ ql_o,
    u16* __restrict__ kh_o, u16* __restrict__ kl_o,
    u16* __restrict__ vt_o)
{
    __shared__ u16 lds[4 * 4608];
    u16* As_h = lds;
    u16* As_l = lds + 4608;
    u16* Bs_h = lds + 9216;
    u16* Bs_l = lds + 13824;
    #define TKP 72

    const int tid  = threadIdx.x;
    const int row0 = blockIdx.y * 64;
    const int mat  = blockIdx.x >> 2;
    const int col0 = (blockIdx.x & 3) * 64;
    const float* biasp = bias + mat * DIM;

    const int w   = tid >> 6;
    const int l15 = tid & 15, h4 = (tid & 63) >> 4;
    const int rh  = w & 1, ch = w >> 1;
    const int lrow = tid & 63, lseg = tid >> 6;
    const int lc = lseg * 16;

    const size_t brow = (size_t)(mat * 256 + col0 + lrow) * 256;
    uint4 sah0, sah1, sal0, sal1, sbh0, sbh1, sbl0, sbl1;
    {
        const u16* pah = xh + (size_t)(row0 + lrow) * DIM + lc;
        const u16* pal = xl + (size_t)(row0 + lrow) * DIM + lc;
        sah0 = ((const uint4*)pah)[0]; sah1 = ((const uint4*)pah)[1];
        sal0 = ((const uint4*)pal)[0]; sal1 = ((const uint4*)pal)[1];
        sbh0 = ((const uint4*)(wth + brow + lc))[0]; sbh1 = ((const uint4*)(wth + brow + lc))[1];
        sbl0 = ((const uint4*)(wtl + brow + lc))[0]; sbl1 = ((const uint4*)(wtl + brow + lc))[1];
    }

    const f32x4 z4 = {0.f, 0.f, 0.f, 0.f};
    f32x4 acc[2][2] = {{z4, z4}, {z4, z4}};

    for (int kt = 0; kt < 4; ++kt) {
        *(uint4*)&As_h[lrow * TKP + lc]     = sah0;
        *(uint4*)&As_h[lrow * TKP + lc + 8] = sah1;
        *(uint4*)&As_l[lrow * TKP + lc]     = sal0;
        *(uint4*)&As_l[lrow * TKP + lc + 8] = sal1;
        *(uint4*)&Bs_h[lrow * TKP + lc]     = sbh0;
        *(uint4*)&Bs_h[lrow * TKP + lc + 8] = sbh1;
        *(uint4*)&Bs_l[lrow * TKP + lc]     = sbl0;
        *(uint4*)&Bs_l[lrow * TKP + lc + 8] = sbl1;
        if (kt + 1 < 4) {
            const int kb = (kt + 1) * 64 + lc;
            const u16* pah = xh + (size_t)(row0 + lrow) * DIM + kb;
            const u16* pal = xl + (size_t)(row0 + lrow) * DIM + kb;
            sah0 = ((const uint4*)pah)[0]; sah1 = ((const uint4*)pah)[1];
            sal0 = ((const uint4*)pal)[0]; sal1 = ((const uint4*)pal)[1];
            sbh0 = ((const uint4*)(wth + brow + kb))[0]; sbh1 = ((const uint4*)(wth + brow + kb))[1];
            sbl0 = ((const uint4*)(wtl + brow + kb))[0]; sbl1 = ((const uint4*)(wtl + brow + kb))[1];
        }
        __syncthreads();

        __builtin_amdgcn_s_setprio(1);
        #pragma unroll
        for (int kc = 0; kc < 2; ++kc) {
            const int dc = kc * 32 + h4 * 8;
            half8 afh[2], afl[2], bfh[2], bfl[2];
            #pragma unroll
            for (int ab = 0; ab < 2; ++ab) {
                const int r = rh * 32 + ab * 16 + l15;
                afh[ab] = *(const half8*)&As_h[r * TKP + dc];
                afl[ab] = *(const half8*)&As_l[r * TKP + dc];
            }
            #pragma unroll
            for (int bb = 0; bb < 2; ++bb) {
                const int r = ch * 32 + bb * 16 + l15;
                bfh[bb] = *(const half8*)&Bs_h[r * TKP + dc];
                bfl[bb] = *(const half8*)&Bs_l[r * TKP + dc];
            }
            #pragma unroll
            for (int ab = 0; ab < 2; ++ab)
                #pragma unroll
                for (int bb = 0; bb < 2; ++bb) {
                    acc[ab][bb] = MFMA16(afh[ab], bfh[bb], acc[ab][bb]);
                    acc[ab][bb] = MFMA16(afh[ab], bfl[bb], acc[ab][bb]);
                    acc[ab][bb] = MFMA16(afl[ab], bfh[bb], acc[ab][bb]);
                }
        }
        __builtin_amdgcn_s_setprio(0);
        __syncthreads();
    }

    const float s = (mat == 0) ? 0.125f : 1.0f;
    u16* oph = (mat == 0) ? qh_o : kh_o;
    u16* opl = (mat == 0) ? ql_o : kl_o;
    #pragma unroll
    for (int ab = 0; ab < 2; ++ab)
        #pragma unroll
        for (int bb = 0; bb < 2; ++bb) {
            const int c  = col0 + ch * 32 + bb * 16 + l15;
            const int r0 = row0 + rh * 32 + ab * 16 + h4 * 4;
            if (mat < 2) {
                #pragma unroll
                for (int i = 0; i < 4; ++i) {
                    const int r = r0 + i;
                    const float t = (acc[ab][bb][i] + biasp[c]) * s;
                    u16 hh, ll;
                    split16(t, hh, ll);
                    oph[(size_t)r * DIM + c] = hh;
                    opl[(size_t)r * DIM + c] = ll;
                }
            } else {
                u16 v[4];
                #pragma unroll
                for (int i = 0; i < 4; ++i)
                    v[i] = f2h(acc[ab][bb][i] + biasp[c]);
                *(uint2*)&vt_o[(size_t)c * NN + r0] =
                    make_uint2((u32)v[0] | ((u32)v[1] << 16), (u32)v[2] | ((u32)v[3] << 16));
            }
        }
    #undef TKP
}

// ---------------- MFMA fp16 GEMM, 32x64 tile (Wo / fc1) -------------------
template<int MEPI>
__global__ __launch_bounds__(256) void mfma_gemm32(
    const u16* __restrict__ Ah, const u16* __restrict__ Al,
    const u16* __restrict__ Bth, const u16* __restrict__ Btl,
    const float* __restrict__ bias, const float* __restrict__ resid,
    float* __restrict__ outf, u16* __restrict__ outh, u16* __restrict__ outl,
    int K, int M)
{
    __shared__ u16 lds[13824];           // 27648 B
    u16* As_h = lds;                     // [32][72]
    u16* As_l = lds + 2304;
    u16* Bs_h = lds + 4608;              // [64][72]
    u16* Bs_l = lds + 9216;
    #define TKP 72

    const int tid  = threadIdx.x;
    const int row0 = blockIdx.y * 32;
    const int col0 = blockIdx.x * 64;

    const int w   = tid >> 6;
    const int l15 = tid & 15, h4 = (tid & 63) >> 4;
    const int rh  = w & 1, ch = w >> 1;
    const int arow = tid >> 3, acs = (tid & 7) * 8;
    const int brow = tid & 63, bseg = tid >> 6;
    const int bc = bseg * 16;

    uint4 sah, sal, sbh0, sbh1, sbl0, sbl1;
    {
        sah = *((const uint4*)&Ah[(size_t)(row0 + arow) * K + acs]);
        sal = *((const uint4*)&Al[(size_t)(row0 + arow) * K + acs]);
        const u16* pbh = Bth + (size_t)(col0 + brow) * K + bc;
        const u16* pbl = Btl + (size_t)(col0 + brow) * K + bc;
        sbh0 = ((const uint4*)pbh)[0]; sbh1 = ((const uint4*)pbh)[1];
        sbl0 = ((const uint4*)pbl)[0]; sbl1 = ((const uint4*)pbl)[1];
    }

    const f32x4 z4 = {0.f, 0.f, 0.f, 0.f};
    f32x4 acc[2] = {z4, z4};
    const int NKT2 = K / 64;

    for (int kt = 0; kt < NKT2; ++kt) {
        *(uint4*)&As_h[arow * TKP + acs] = sah;
        *(uint4*)&As_l[arow * TKP + acs] = sal;
        *(uint4*)&Bs_h[brow * TKP + bc]     = sbh0;
        *(uint4*)&Bs_h[brow * TKP + bc + 8] = sbh1;
        *(uint4*)&Bs_l[brow * TKP + bc]     = sbl0;
        *(uint4*)&Bs_l[brow * TKP + bc + 8] = sbl1;
        if (kt + 1 < NKT2) {              // early-issue prefetch
            const int kb = (kt + 1) * 64;
            sah = *((const uint4*)&Ah[(size_t)(row0 + arow) * K + kb + acs]);
            sal = *((const uint4*)&Al[(size_t)(row0 + arow) * K + kb + acs]);
            const u16* pbh = Bth + (size_t)(col0 + brow) * K + kb + bc;
            const u16* pbl = Btl + (size_t)(col0 + brow) * K + kb + bc;
            sbh0 = ((const uint4*)pbh)[0]; sbh1 = ((const uint4*)pbh)[1];
            sbl0 = ((const uint4*)pbl)[0]; sbl1 = ((const uint4*)pbl)[1];
        }
        __syncthreads();

        __builtin_amdgcn_s_setprio(1);
        #pragma unroll
        for (int kc = 0; kc < 2; ++kc) {
            const int dc = kc * 32 + h4 * 8;
            half8 afh, afl, bfh[2], bfl[2];
            afh = *(const half8*)&As_h[(rh * 16 + l15) * TKP + dc];
            afl = *(const half8*)&As_l[(rh * 16 + l15) * TKP + dc];
            #pragma unroll
            for (int bb = 0; bb < 2; ++bb) {
                const int r = ch * 32 + bb * 16 + l15;
                bfh[bb] = *(const half8*)&Bs_h[r * TKP + dc];
                bfl[bb] = *(const half8*)&Bs_l[r * TKP + dc];
            }
            #pragma unroll
            for (int bb = 0; bb < 2; ++bb) {
                acc[bb] = MFMA16(afh, bfh[bb], acc[bb]);
                acc[bb] = MFMA16(afh, bfl[bb], acc[bb]);
                acc[bb] = MFMA16(afl, bfh[bb], acc[bb]);
            }
        }
        __builtin_amdgcn_s_setprio(0);
        __syncthreads();
    }

    #pragma unroll
    for (int bb = 0; bb < 2; ++bb) {
        const int c  = col0 + ch * 32 + bb * 16 + l15;
        const int r0 = row0 + rh * 16 + h4 * 4;
        #pragma unroll
        for (int i = 0; i < 4; ++i) {
            const int r = r0 + i;
            float t = acc[bb][i] + bias[c];
            if (MEPI == MEPI_WO) {
                t += resid[(size_t)r * M + c];
                u16 hh, ll;
                split16(t, hh, ll);
                outh[(size_t)r * M + c] = hh;
                outl[(size_t)r * M + c] = ll;
            } else {    // FC1: bias + ELU -> fp32 feats
                t = t > 0.f ? t : expm1f(t);
                outf[(size_t)r * M + c] = t;
            }
        }
    }
    #undef TKP
}

// ---------------- MFMA flash attention (round-16) -------------------------
// Round-14 structure (8-wave QB=128, LDS double-buffered K/V, ONE barrier
// per tile — proven 84 us) + defer-max (THR=8): skip the O-rescale when the
// wave's tile max is within 8 of the running max (P bounded by e^8).
#define QB 128
#define KB 64
#define NSPLIT 4
#define NKT (NN / KB)
#define KP 72

__global__ __launch_bounds__(512, 2) void attn_kernel(
    const u16* __restrict__ qhi, const u16* __restrict__ qlo,
    const u16* __restrict__ khi, const u16* __restrict__ klo,
    const u16* __restrict__ vT,
    float* __restrict__ op0, float* __restrict__ op1,
    float* __restrict__ op2, float* __restrict__ op3,
    float* __restrict__ mpart, float* __restrict__ lpart)
{
    __shared__ u16 lds[37120];            // 74240 B -> 2 blocks/CU
    u16* Kh0 = lds;                       // buf0 [64][72] x3
    u16* Kl0 = lds + 4608;
    u16* Vt0 = lds + 9216;
    u16* Kh1 = lds + 13824;               // buf1
    u16* Kl1 = lds + 18432;
    u16* Vt1 = lds + 23040;
    u16* Pb  = lds + 27648;               // [128][72] P fp16 (wave-local rows)
    u16* Qh  = lds;                       // overlay buf0 (init): [128][72]
    u16* Ql  = lds + 13824;               // overlay buf1 (init)
    float* frow = (float*)(lds + 36864);  // [128]

    const int tid = threadIdx.x;
    const int h   = blockIdx.y;
    const int q0  = blockIdx.x * QB;
    const int sp  = blockIdx.z;
    const int kt0 = sp * (NKT / NSPLIT);  // 16 tiles/block (even)
    const int kt1 = kt0 + NKT / NSPLIT;

    const int w   = tid >> 6;             // wave 0..7 -> q rows w*16..+15
    const int l15 = tid & 15, h4 = (tid & 63) >> 4;
    const int lrow = tid & 63, lseg = tid >> 6;   // staging: 8 segs x 8 u16
    const int gq8 = h * DH + lseg * 8;

    {   // stage Q (once, into overlay region): 128 rows x 64 d
        const int qrow = tid >> 2, qseg = tid & 3;
        const u16* s0 = qhi + (size_t)(q0 + qrow) * DIM + h * DH + qseg * 16;
        const u16* s1 = qlo + (size_t)(q0 + qrow) * DIM + h * DH + qseg * 16;
        uint4 a = ((const uint4*)s0)[0], b = ((const uint4*)s0)[1];
        uint4 c = ((const uint4*)s1)[0], d = ((const uint4*)s1)[1];
        *(uint4*)&Qh[qrow * KP + qseg * 16]     = a;
        *(uint4*)&Qh[qrow * KP + qseg * 16 + 8] = b;
        *(uint4*)&Ql[qrow * KP + qseg * 16]     = c;
        *(uint4*)&Ql[qrow * KP + qseg * 16 + 8] = d;
    }

    uint4 rk, rl, rv;                     // staging registers
    auto load_tile = [&](int kt_ld) {
        const int key0 = kt_ld * KB;
        rk = *(const uint4*)(khi + (size_t)(key0 + lrow) * DIM + gq8);
        rl = *(const uint4*)(klo + (size_t)(key0 + lrow) * DIM + gq8);
        rv = *(const uint4*)(vT + (size_t)(h * DH + lrow) * NN + key0 + lseg * 8);
    };
    load_tile(kt0);
    __syncthreads();                              // Q staged

    half8 qf[2][2];                               // [kc][hi/lo]
    #pragma unroll
    for (int kc = 0; kc < 2; ++kc) {
        const int r = w * 16 + l15;
        const int dc = kc * 32 + h4 * 8;
        qf[kc][0] = *(const half8*)&Qh[r * KP + dc];
        qf[kc][1] = *(const half8*)&Ql[r * KP + dc];
    }
    __syncthreads();                              // hoist done; overlay safe

    auto stage_to = [&](u16* Kh, u16* Kl, u16* Vt) {
        *(uint4*)&Kh[lrow * KP + lseg * 8] = rk;
        *(uint4*)&Kl[lrow * KP + lseg * 8] = rl;
        *(uint4*)&Vt[lrow * KP + lseg * 8] = rv;
    };

    stage_to(Kh0, Kl0, Vt0);                      // tile kt0 -> buf0
    load_tile(kt0 + 1);                           // tile kt0+1 -> regs
    __syncthreads();                              // buf0 ready

    const f32x4 z4 = {0.f, 0.f, 0.f, 0.f};
    f32x4 oacc[4] = {z4, z4, z4, z4};             // d-blocks 0..3 for own 16 q
    float m_run[4], l_run[4];
    #pragma unroll
    for (int i = 0; i < 4; ++i) { m_run[i] = -3.0e38f; l_run[i] = 0.f; }

    auto tile_body = [&](int t, u16* Kc, u16* Lc, u16* Vc,
                         u16* Kn, u16* Ln, u16* Vn) {
        if (t + 1 < kt1) stage_to(Kn, Ln, Vn);    // writes to the idle buffer
        if (t + 2 < kt1) load_tile(t + 2);        // early-issue global loads

        // ---- S = Q K^T (3-pass fp16 hi/lo): 16 q-rows x 64 k per wave ----
        f32x4 sc[4] = {z4, z4, z4, z4};
        __builtin_amdgcn_s_setprio(1);
        #pragma unroll
        for (int kc = 0; kc < 2; ++kc) {
            const int dc = kc * 32 + h4 * 8;
            half8 kfh[4], kfl[4];
            #pragma unroll
            for (int kcb = 0; kcb < 4; ++kcb) {
                const int r = kcb * 16 + l15;
                kfh[kcb] = *(const half8*)&Kc[r * KP + dc];
                kfl[kcb] = *(const half8*)&Lc[r * KP + dc];
            }
            #pragma unroll
            for (int kcb = 0; kcb < 4; ++kcb) {
                sc[kcb] = MFMA16(qf[kc][0], kfh[kcb], sc[kcb]);
                sc[kcb] = MFMA16(qf[kc][0], kfl[kcb], sc[kcb]);
                sc[kcb] = MFMA16(qf[kc][1], kfh[kcb], sc[kcb]);
            }
        }
        __builtin_amdgcn_s_setprio(0);

        // ---- wave-local softmax with defer-max (THR=8) ----
        float pm[4];
        #pragma unroll
        for (int i = 0; i < 4; ++i) {
            float v = fmaxf(fmaxf(sc[0][i], sc[1][i]), fmaxf(sc[2][i], sc[3][i]));
            #pragma unroll
            for (int off = 1; off < 16; off <<= 1)
                v = fmaxf(v, __shfl_xor(v, off));
            pm[i] = v;
        }
        const int ok = (pm[0] - m_run[0] <= 8.f) && (pm[1] - m_run[1] <= 8.f) &&
                       (pm[2] - m_run[2] <= 8.f) && (pm[3] - m_run[3] <= 8.f);
        float p[4][4];
        if (__all(ok)) {
            // no rescale: keep old max (P bounded by e^8, fp16-safe)
            #pragma unroll
            for (int i = 0; i < 4; ++i) {
                p[0][i] = __expf(sc[0][i] - m_run[i]);
                p[1][i] = __expf(sc[1][i] - m_run[i]);
                p[2][i] = __expf(sc[2][i] - m_run[i]);
                p[3][i] = __expf(sc[3][i] - m_run[i]);
                float ls = (p[0][i] + p[1][i]) + (p[2][i] + p[3][i]);
                #pragma unroll
                for (int off = 1; off < 16; off <<= 1) ls += __shfl_xor(ls, off);
                l_run[i] += ls;
            }
        } else {
            float fr[4];
            #pragma unroll
            for (int i = 0; i < 4; ++i) {
                const float mnew = fmaxf(m_run[i], pm[i]);
                fr[i] = __expf(m_run[i] - mnew);
                m_run[i] = mnew;
                p[0][i] = __expf(sc[0][i] - mnew);
                p[1][i] = __expf(sc[1][i] - mnew);
                p[2][i] = __expf(sc[2][i] - mnew);
                p[3][i] = __expf(sc[3][i] - mnew);
                float ls = (p[0][i] + p[1][i]) + (p[2][i] + p[3][i]);
                #pragma unroll
                for (int off = 1; off < 16; off <<= 1) ls += __shfl_xor(ls, off);
                l_run[i] = l_run[i] * fr[i] + ls;
            }
            if (l15 == 0) {
                #pragma unroll
                for (int i = 0; i < 4; ++i)
                    frow[w * 16 + h4 * 4 + i] = fr[i];
            }
            // wave-local LDS: compiler waitcnt orders the read below
            const float frq = frow[w * 16 + l15];
            #pragma unroll
            for (int db = 0; db < 4; ++db) oacc[db] *= frq;
        }
        // P store (wave-local rows): rows w*16+h4*4+i, cols kcb*16+l15
        #pragma unroll
        for (int kcb = 0; kcb < 4; ++kcb) {
            const int kk = kcb * 16 + l15;
            #pragma unroll
            for (int i = 0; i < 4; ++i)
                Pb[(w * 16 + h4 * 4 + i) * KP + kk] = f2h(p[kcb][i]);
        }
        // ---- PV: wave-local (compiler orders Pb read-after-write) ----
        __builtin_amdgcn_s_setprio(1);
        #pragma unroll
        for (int kc = 0; kc < 2; ++kc) {
            const half8 pf = *(const half8*)&Pb[(w * 16 + l15) * KP + kc * 32 + h4 * 8];
            #pragma unroll
            for (int db = 0; db < 4; ++db) {
                const half8 vf = *(const half8*)&Vc[(db * 16 + l15) * KP + kc * 32 + h4 * 8];
                oacc[db] = MFMA16(vf, pf, oacc[db]);
            }
        }
        __builtin_amdgcn_s_setprio(0);
        __syncthreads();   // single per-tile barrier: buf^1 staged + cur reads done
    };

    for (int t = kt0; t < kt1; t += 2) {
        tile_body(t,     Kh0, Kl0, Vt0, Kh1, Kl1, Vt1);
        tile_body(t + 1, Kh1, Kl1, Vt1, Kh0, Kl0, Vt0);
    }

    float* ob = (sp == 0) ? op0 : ((sp == 1) ? op1 : ((sp == 2) ? op2 : op3));
    #pragma unroll
    for (int db = 0; db < 4; ++db)
        *(f32x4*)&ob[(size_t)(q0 + w * 16 + l15) * DIM + h * DH + db * 16 + h4 * 4] = oacc[db];
    if (l15 == 0) {
        #pragma unroll
        for (int i = 0; i < 4; ++i) {
            const int r = w * 16 + h4 * 4 + i;
            mpart[((size_t)sp * NN + q0 + r) * NH + h] = m_run[i];
            lpart[((size_t)sp * NN + q0 + r) * NH + h] = l_run[i];
        }
    }
}

// merge the 4 partials -> fp16 hi/lo planes (feeds the MFMA Wo GEMM)
__global__ __launch_bounds__(256) void attn_combine(
    const float* __restrict__ o0, const float* __restrict__ o1,
    const float* __restrict__ o2, const float* __restrict__ o3,
    const float* __restrict__ mp, const float* __restrict__ lp,
    u16* __restrict__ ohi, u16* __restrict__ olo)
{
    const int gid = blockIdx.x * 256 + threadIdx.x;
    const int row = gid >> 6;
    const int c4  = (gid & 63) * 4;
    const int h   = c4 >> 6;
    float m[4], wgt[4];
    #pragma unroll
    for (int z = 0; z < 4; ++z) m[z] = mp[((size_t)z * NN + row) * NH + h];
    const float M = fmaxf(fmaxf(m[0], m[1]), fmaxf(m[2], m[3]));
    float den = 0.f;
    #pragma unroll
    for (int z = 0; z < 4; ++z) {
        wgt[z] = __expf(m[z] - M);
        den += lp[((size_t)z * NN + row) * NH + h] * wgt[z];
    }
    const float inv = 1.f / den;
    const float4 a = *(const float4*)&o0[(size_t)row * DIM + c4];
    const float4 b = *(const float4*)&o1[(size_t)row * DIM + c4];
    const float4 c = *(const float4*)&o2[(size_t)row * DIM + c4];
    const float4 d = *(const float4*)&o3[(size_t)row * DIM + c4];
    float r[4];
    r[0] = (a.x * wgt[0] + b.x * wgt[1] + c.x * wgt[2] + d.x * wgt[3]) * inv;
    r[1] = (a.y * wgt[0] + b.y * wgt[1] + c.y * wgt[2] + d.y * wgt[3]) * inv;
    r[2] = (a.z * wgt[0] + b.z * wgt[1] + c.z * wgt[2] + d.z * wgt[3]) * inv;
    r[3] = (a.w * wgt[0] + b.w * wgt[1] + c.w * wgt[2] + d.w * wgt[3]) * inv;
    u16 hh[4], ll[4];
    #pragma unroll
    for (int j = 0; j < 4; ++j) split16(r[j], hh[j], ll[j]);
    *(uint2*)&ohi[(size_t)row * DIM + c4] =
        make_uint2((u32)hh[0] | ((u32)hh[1] << 16), (u32)hh[2] | ((u32)hh[3] << 16));
    *(uint2*)&olo[(size_t)row * DIM + c4] =
        make_uint2((u32)ll[0] | ((u32)ll[1] << 16), (u32)ll[2] | ((u32)ll[3] << 16));
}

// ---------------- per-node group adapter: 4 nodes per 256-thr block -------
__global__ __launch_bounds__(256) void adapter_kernel(
    const float* __restrict__ feats, const int* __restrict__ grp,
    const float* __restrict__ AW1, const float* __restrict__ Ab1,
    const float* __restrict__ AW2, const float* __restrict__ Ab2,
    float* __restrict__ out)
{
    const int wv = threadIdx.x >> 6;
    const int n = blockIdx.x * 4 + wv;
    const int lane = threadIdx.x & 63;
    __shared__ float f[4][F1D];
    f[wv][lane]      = feats[(size_t)n * F1D + lane];
    f[wv][lane + 64] = feats[(size_t)n * F1D + 64 + lane];
    // wave-local LDS: compiler waitcnt orders reads (no barrier needed)
    const int g = grp[n];
    const float* W1 = AW1 + (size_t)g * F1D * AD;
    const int a = lane & 31;
    const int half = lane >> 5;
    float hsum = 0.f;
    for (int d = 0; d < 64; ++d)
        hsum = fmaf(f[wv][half * 64 + d], W1[(half * 64 + d) * AD + a], hsum);
    hsum += __shfl_xor(hsum, 32);
    hsum = fmaxf(hsum + Ab1[g * AD + a], 0.f);
    float p = hsum * AW2[g * AD + a];
    #pragma unroll
    for (int mm = 1; mm < 32; mm <<= 1) p += __shfl_xor(p, mm);
    if (lane == 0) out[n] = p + Ab2[g];
}

// ---------------- host-side orchestration ----------------
extern "C" void kernel_launch(void* const* d_in, const int* in_sizes, int n_in,
                              void* d_out, int out_size, void* d_ws, size_t ws_size,
                              hipStream_t stream)
{
    const float* x_in   = (const float*)d_in[0];
    const float* eattr  = (const float*)d_in[1];
    const float* Wself  = (const float*)d_in[2];
    const float* Wnbr   = (const float*)d_in[3];
    const float* convb  = (const float*)d_in[4];
    const float* gamma  = (const float*)d_in[5];
    const float* beta   = (const float*)d_in[6];
    const float* bnmean = (const float*)d_in[7];
    const float* bnvar  = (const float*)d_in[8];
    const float* Wqkv   = (const float*)d_in[9];
    const float* bqkv   = (const float*)d_in[10];
    const float* Wo     = (const float*)d_in[11];
    const float* bo     = (const float*)d_in[12];
    const float* fc1W   = (const float*)d_in[13];
    const float* fc1b   = (const float*)d_in[14];
    const float* AW1    = (const float*)d_in[15];
    const float* Ab1    = (const float*)d_in[16];
    const float* AW2    = (const float*)d_in[17];
    const float* Ab2    = (const float*)d_in[18];
    const int*   eidx   = (const int*)d_in[19];
    const int*   grp    = (const int*)d_in[20];
    const int* srcArr = eidx;
    const int* dstArr = eidx + NE;

    float* fws = (float*)d_ws;
    const size_t NM = (size_t)NN * DIM;
    float* bufA  = fws;                  // x L0 / x L2 (residual)
    float* bufB  = fws + NM;             // attn op0
    float* bufC  = fws + 2 * NM;         // x L1 / attn op1
    float* feats = fws + 3 * NM;         // NN x F1D
    float* mpart = fws + 3 * NM + NM / 2;         // [4][NN][NH]
    float* lpart = mpart + 4 * NN * NH;
    u16* up = (u16*)(lpart + 4 * NN * NH);
    u16* xpAh = up;             u16* xpAl = xpAh + NM;   // x planes ping
    u16* xpBh = xpAl + NM;      u16* xpBl = xpBh + NM;   // x planes pong
    u16* aggh = xpBl + NM;      u16* aggl = aggh + NM;   // agg planes
    u16* qh = aggl + NM;        u16* ql = qh + NM;       // Q planes / combine out
    u16* kh = ql + NM;          u16* kl = kh + NM;       // K planes / Wo out
    u16* vt = kl + NM;                                   // V^T fp16 [256][NN]
    u16* wcath = vt + NM;                                // [3][256][512]
    u16* wcatl = wcath + 3 * 131072;
    u16* wt4h  = wcatl + 3 * 131072;                     // [4][256][256] qkv+wo
    u16* wt4l  = wt4h + 4 * 65536;
    u16* fc1h  = wt4l + 4 * 65536;                       // [128][256]
    u16* fc1l  = fc1h + 32768;
    int*   esrc = (int*)(fc1l + 32768);                  // NE
    float* ewt  = (float*)(esrc + NE);                   // NE
    int* off    = (int*)(ewt + NE);                      // NN+1
    int* cur    = off + NN + 1;                          // NN
    float* outp = (float*)d_out;

    float* op2 = (float*)xpAh;           // attn partial overlays
    float* op3 = (float*)xpBh;

    // fused prep: all converts + zero(cur)
    prep_kernel<<<1700, 256, 0, stream>>>(
        x_in, Wself, Wnbr, Wqkv, Wo, fc1W,
        xpAh, xpAl, wcath, wcatl, wt4h, wt4l, fc1h, fc1l, cur);

    // CSR build (csr_scan zeroes cur for csr_fill)
    csr_count<<<NE / 256, 256, 0, stream>>>(dstArr, cur);
    csr_scan<<<1, 1024, 0, stream>>>(cur, off);
    csr_fill<<<NE / 256, 256, 0, stream>>>(dstArr, srcArr, eattr, off, cur, esrc, ewt);

    const dim3 gc(DIM / 64, NN / 32);    // 32-row conv tiles: 512 blocks
    const int rgrid = NN * DIM / 4 / 256;

    // conv layer 0: x_in -> bufA (fp32) + xpB planes
    agg_kernel<false><<<NN / 4, 256, 0, stream>>>(x_in, esrc, ewt, off, aggh, aggl);
    conv_mfma<EPI_BNELU><<<gc, 256, 0, stream>>>(
        xpAh, xpAl, aggh, aggl, wcath, wcatl, convb,
        gamma, beta, bnmean, bnvar, bufA, xpBh, xpBl);
    // conv layer 1: bufA -> bufC + xpA planes
    agg_kernel<false><<<NN / 4, 256, 0, stream>>>(bufA, esrc, ewt, off, aggh, aggl);
    conv_mfma<EPI_BNELU><<<gc, 256, 0, stream>>>(
        xpBh, xpBl, aggh, aggl, wcath + 131072, wcatl + 131072, convb + DIM,
        gamma + DIM, beta + DIM, bnmean + DIM, bnvar + DIM, bufC, xpAh, xpAl);
    // conv layer 2 (edge-weighted, bias only): bufC -> bufA + xpB planes
    agg_kernel<true><<<NN / 4, 256, 0, stream>>>(bufC, esrc, ewt, off, aggh, aggl);
    conv_mfma<EPI_BIAS><<<gc, 256, 0, stream>>>(
        xpAh, xpAl, aggh, aggl, wcath + 262144, wcatl + 262144, convb + 2 * DIM,
        nullptr, nullptr, nullptr, nullptr, bufA, xpBh, xpBl);

    // QKV (fp16 3-pass MFMA) -> Q/K planes (Q/8) + V^T
    qkv_mfma<<<dim3(12, NN / 64), 256, 0, stream>>>(
        xpBh, xpBl, wt4h, wt4l, bqkv, qh, ql, kh, kl, vt);

    // flash attention (8-wave QB=128, dbuf, 4-way key split) -> combine
    attn_kernel<<<dim3(NN / QB, NH, NSPLIT), 512, 0, stream>>>(
        qh, ql, kh, kl, vt, bufB, bufC, op2, op3, mpart, lpart);
    attn_combine<<<rgrid, 256, 0, stream>>>(
        bufB, bufC, op2, op3, mpart, lpart, qh, ql);

    // Wo + residual (fp16 3-pass MFMA, 32x64 tiles): kh/kl = planes(...)
    mfma_gemm32<MEPI_WO><<<dim3(DIM / 64, NN / 32), 256, 0, stream>>>(
        qh, ql, wt4h + 3 * 65536, wt4l + 3 * 65536, bo, bufA,
        nullptr, kh, kl, DIM, DIM);

    // fc1 + ELU (fp16 3-pass MFMA, 32x64 tiles): feats = elu(x' @ fc1W + fc1b)
    mfma_gemm32<MEPI_FC1><<<dim3(F1D / 64, NN / 32), 256, 0, stream>>>(
        kh, kl, fc1h, fc1l, fc1b, nullptr, feats, nullptr, nullptr, DIM, F1D);

    // adapter routing -> out
    adapter_kernel<<<NN / 4, 256, 0, stream>>>(feats, grp, AW1, Ab1, AW2, Ab2, outp);
}

// Round 17
// 211.639 us; speedup vs baseline: 1.1735x; 1.1045x over previous
//
#include <hip/hip_runtime.h>
#include <math.h>

#define NN   4096
#define DIM  256
#define NE   131072
#define NH   4
#define DH   64
#define F1D  128
#define NG   16
#define AD   32

typedef unsigned short u16;
typedef unsigned int   u32;
typedef _Float16 f16;
typedef __attribute__((ext_vector_type(8))) _Float16 half8;
typedef __attribute__((ext_vector_type(4))) float f32x4;

enum { EPI_BIAS = 0, EPI_BNELU = 1 };
enum { MEPI_WO = 0, MEPI_FC1 = 1 };

#define MFMA16(a, b, c) __builtin_amdgcn_mfma_f32_16x16x32_f16(a, b, c, 0, 0, 0)

__device__ inline u16 f2h(float x) { union { f16 f; u16 u; } c; c.f = (f16)x; return c.u; }
// fp16 hi/lo split: x = hi + lo + eps, |eps| <= 2^-24 |x|  (fp32-grade)
__device__ inline void split16(float x, u16& h, u16& l) {
    union { f16 f; u16 u; } ch, cl;
    ch.f = (f16)x;
    cl.f = (f16)(x - (float)ch.f);
    h = ch.u; l = cl.u;
}

// ---------------- CSR build ----------------
__global__ void csr_count(const int* __restrict__ dst, int* __restrict__ cnt) {
    int e = blockIdx.x * 256 + threadIdx.x;
    atomicAdd(&cnt[dst[e]], 1);
}

__global__ __launch_bounds__(1024) void csr_scan(
    int* __restrict__ cnt, int* __restrict__ off)
{
    __shared__ int wsum[16];
    const int t = threadIdx.x;
    const int lane = t & 63;
    int4 v = *(const int4*)&cnt[t * 4];
    const int s = v.x + v.y + v.z + v.w;
    int acc = s;
    #pragma unroll
    for (int o = 1; o < 64; o <<= 1) {
        int u = __shfl_up(acc, o);
        if (lane >= o) acc += u;
    }
    if (lane == 63) wsum[t >> 6] = acc;
    __syncthreads();
    if (t < 16) {
        int w0 = wsum[t];
        int a2 = w0;
        #pragma unroll
        for (int o = 1; o < 16; o <<= 1) {
            int u = __shfl_up(a2, o);
            if (t >= o) a2 += u;
        }
        wsum[t] = a2 - w0;
    }
    __syncthreads();
    const int base = wsum[t >> 6] + (acc - s);
    off[t * 4 + 0] = base;
    off[t * 4 + 1] = base + v.x;
    off[t * 4 + 2] = base + v.x + v.y;
    off[t * 4 + 3] = base + v.x + v.y + v.z;
    *(int4*)&cnt[t * 4] = make_int4(0, 0, 0, 0);
    if (t == 1023) off[NN] = base + s;
}

__global__ void csr_fill(const int* __restrict__ dst, const int* __restrict__ src,
                         const float* __restrict__ eattr, const int* __restrict__ off,
                         int* __restrict__ cur, int* __restrict__ esrc,
                         float* __restrict__ ewt) {
    int e = blockIdx.x * 256 + threadIdx.x;
    int d = dst[e];
    int pos = off[d] + atomicAdd(&cur[d], 1);
    esrc[pos] = src[e];
    ewt[pos]  = eattr[e];
}

// ---------------- fused one-time prep: all weight/x converts + zero cur ----
__global__ __launch_bounds__(256) void prep_kernel(
    const float* __restrict__ x,
    const float* __restrict__ Ws, const float* __restrict__ Wn,
    const float* __restrict__ Wqkv, const float* __restrict__ Wo,
    const float* __restrict__ fc1W,
    u16* __restrict__ xh, u16* __restrict__ xl,
    u16* __restrict__ wch, u16* __restrict__ wcl,
    u16* __restrict__ w4h, u16* __restrict__ w4l,
    u16* __restrict__ f1h, u16* __restrict__ f1l,
    int* __restrict__ cur)
{
    const int b = blockIdx.x;
    const int t = threadIdx.x;
    if (b < 1024) {
        const int gid = b * 256 + t;
        const float4 v = *(const float4*)&x[(size_t)gid * 4];
        u16 h[4], l[4];
        split16(v.x, h[0], l[0]); split16(v.y, h[1], l[1]);
        split16(v.z, h[2], l[2]); split16(v.w, h[3], l[3]);
        *(uint2*)&xh[(size_t)gid * 4] =
            make_uint2((u32)h[0] | ((u32)h[1] << 16), (u32)h[2] | ((u32)h[3] << 16));
        *(uint2*)&xl[(size_t)gid * 4] =
            make_uint2((u32)l[0] | ((u32)l[1] << 16), (u32)l[2] | ((u32)l[3] << 16));
    } else if (b < 1408) {
        const int gid = (b - 1024) * 256 + t;
        const int L = gid / 32768;
        const int rem = gid % 32768;
        const int m = rem / 128;
        const int k4 = (rem % 128) * 4;
        const float* S = Ws + (size_t)L * 65536;
        const float* Nb = Wn + (size_t)L * 65536;
        u16 h[4], l[4];
        #pragma unroll
        for (int j = 0; j < 4; ++j) {
            const int k = k4 + j;
            const float v = (k < 256) ? S[(size_t)k * 256 + m]
                                      : Nb[(size_t)(k - 256) * 256 + m];
            split16(v, h[j], l[j]);
        }
        const size_t o = (size_t)L * 131072 + (size_t)m * 512 + k4;
        *(uint2*)&wch[o] = make_uint2((u32)h[0] | ((u32)h[1] << 16), (u32)h[2] | ((u32)h[3] << 16));
        *(uint2*)&wcl[o] = make_uint2((u32)l[0] | ((u32)l[1] << 16), (u32)l[2] | ((u32)l[3] << 16));
    } else if (b < 1664) {
        const int gid = (b - 1408) * 256 + t;
        const int mat = gid / 16384;
        const int rem = gid % 16384;
        const int m = rem / 64;
        const int k4 = (rem % 64) * 4;
        const float* W = (mat < 3) ? Wqkv + (size_t)mat * 65536 : Wo;
        u16 h[4], l[4];
        #pragma unroll
        for (int j = 0; j < 4; ++j)
            split16(W[(size_t)(k4 + j) * 256 + m], h[j], l[j]);
        const size_t o = (size_t)mat * 65536 + (size_t)m * 256 + k4;
        *(uint2*)&w4h[o] = make_uint2((u32)h[0] | ((u32)h[1] << 16), (u32)h[2] | ((u32)h[3] << 16));
        *(uint2*)&w4l[o] = make_uint2((u32)l[0] | ((u32)l[1] << 16), (u32)l[2] | ((u32)l[3] << 16));
    } else if (b < 1696) {
        const int gid = (b - 1664) * 256 + t;
        const int m = gid / 64;
        const int k4 = (gid % 64) * 4;
        u16 h[4], l[4];
        #pragma unroll
        for (int j = 0; j < 4; ++j)
            split16(fc1W[(size_t)(k4 + j) * F1D + m], h[j], l[j]);
        const size_t o = (size_t)m * 256 + k4;
        *(uint2*)&f1h[o] = make_uint2((u32)h[0] | ((u32)h[1] << 16), (u32)h[2] | ((u32)h[3] << 16));
        *(uint2*)&f1l[o] = make_uint2((u32)l[0] | ((u32)l[1] << 16), (u32)l[2] | ((u32)l[3] << 16));
    } else {
        const int gid = (b - 1696) * 256 + t;
        if (gid < NN / 4) *(int4*)&cur[gid * 4] = make_int4(0, 0, 0, 0);
    }
}

// ---------------- neighbor aggregation: 1 wave per node, fp16-plane out ---
template<bool LAST>
__global__ __launch_bounds__(256) void agg_kernel(
    const float* __restrict__ x, const int* __restrict__ esrc,
    const float* __restrict__ ewt, const int* __restrict__ off,
    u16* __restrict__ aggh, u16* __restrict__ aggl)
{
    const int node = blockIdx.x * 4 + (threadIdx.x >> 6);
    const int lane = threadIdx.x & 63;
    const int d4 = lane * 4;
    int j = off[node];
    const int j1 = off[node + 1];
    float4 acc = make_float4(0.f, 0.f, 0.f, 0.f);
    for (; j + 4 <= j1; j += 4) {
        const int s0 = esrc[j], s1 = esrc[j + 1], s2 = esrc[j + 2], s3 = esrc[j + 3];
        const float4 x0 = *(const float4*)&x[(size_t)s0 * DIM + d4];
        const float4 x1 = *(const float4*)&x[(size_t)s1 * DIM + d4];
        const float4 x2 = *(const float4*)&x[(size_t)s2 * DIM + d4];
        const float4 x3 = *(const float4*)&x[(size_t)s3 * DIM + d4];
        const float w0 = LAST ? ewt[j]     : 1.f;
        const float w1 = LAST ? ewt[j + 1] : 1.f;
        const float w2 = LAST ? ewt[j + 2] : 1.f;
        const float w3 = LAST ? ewt[j + 3] : 1.f;
        acc.x = fmaf(x0.x, w0, acc.x); acc.y = fmaf(x0.y, w0, acc.y);
        acc.z = fmaf(x0.z, w0, acc.z); acc.w = fmaf(x0.w, w0, acc.w);
        acc.x = fmaf(x1.x, w1, acc.x); acc.y = fmaf(x1.y, w1, acc.y);
        acc.z = fmaf(x1.z, w1, acc.z); acc.w = fmaf(x1.w, w1, acc.w);
        acc.x = fmaf(x2.x, w2, acc.x); acc.y = fmaf(x2.y, w2, acc.y);
        acc.z = fmaf(x2.z, w2, acc.z); acc.w = fmaf(x2.w, w2, acc.w);
        acc.x = fmaf(x3.x, w3, acc.x); acc.y = fmaf(x3.y, w3, acc.y);
        acc.z = fmaf(x3.z, w3, acc.z); acc.w = fmaf(x3.w, w3, acc.w);
    }
    for (; j < j1; ++j) {
        const int s = esrc[j];
        const float w = LAST ? ewt[j] : 1.f;
        const float4 xv = *(const float4*)&x[(size_t)s * DIM + d4];
        acc.x = fmaf(xv.x, w, acc.x); acc.y = fmaf(xv.y, w, acc.y);
        acc.z = fmaf(xv.z, w, acc.z); acc.w = fmaf(xv.w, w, acc.w);
    }
    u16 h[4], l[4];
    split16(acc.x, h[0], l[0]); split16(acc.y, h[1], l[1]);
    split16(acc.z, h[2], l[2]); split16(acc.w, h[3], l[3]);
    *(uint2*)&aggh[(size_t)node * DIM + d4] =
        make_uint2((u32)h[0] | ((u32)h[1] << 16), (u32)h[2] | ((u32)h[3] << 16));
    *(uint2*)&aggl[(size_t)node * DIM + d4] =
        make_uint2((u32)l[0] | ((u32)l[1] << 16), (u32)l[2] | ((u32)l[3] << 16));
}

// ---------------- conv MFMA GEMM: 32x64 tile (2 blocks/CU) ----------------
template<int EPI>
__global__ __launch_bounds__(256) void conv_mfma(
    const u16* __restrict__ xh, const u16* __restrict__ xl,
    const u16* __restrict__ gh, const u16* __restrict__ gl,
    const u16* __restrict__ bth, const u16* __restrict__ btl,
    const float* __restrict__ bias,
    const float* __restrict__ gamma, const float* __restrict__ beta,
    const float* __restrict__ bnmean, const float* __restrict__ bnvar,
    float* __restrict__ outf, u16* __restrict__ oh, u16* __restrict__ ol)
{
    __shared__ u16 lds[13824];           // 27648 B
    u16* As_h = lds;                     // [32][72]
    u16* As_l = lds + 2304;
    u16* Bs_h = lds + 4608;              // [64][72]
    u16* Bs_l = lds + 9216;
    #define TKP 72

    const int tid  = threadIdx.x;
    const int row0 = blockIdx.y * 32;
    const int col0 = blockIdx.x * 64;

    const int w   = tid >> 6;
    const int l15 = tid & 15, h4 = (tid & 63) >> 4;
    const int rh  = w & 1, ch = w >> 1;
    const int arow = tid >> 3, acs = (tid & 7) * 8;
    const int brow = tid & 63, bseg = tid >> 6;
    const int bc = bseg * 16;

    uint4 sah, sal, sbh0, sbh1, sbl0, sbl1;
    {
        sah = *((const uint4*)&xh[(size_t)(row0 + arow) * DIM + acs]);
        sal = *((const uint4*)&xl[(size_t)(row0 + arow) * DIM + acs]);
        const u16* pbh = bth + (size_t)(col0 + brow) * 512 + bc;
        const u16* pbl = btl + (size_t)(col0 + brow) * 512 + bc;
        sbh0 = ((const uint4*)pbh)[0]; sbh1 = ((const uint4*)pbh)[1];
        sbl0 = ((const uint4*)pbl)[0]; sbl1 = ((const uint4*)pbl)[1];
    }

    const f32x4 z4 = {0.f, 0.f, 0.f, 0.f};
    f32x4 acc[2] = {z4, z4};

    for (int kt = 0; kt < 8; ++kt) {
        *(uint4*)&As_h[arow * TKP + acs] = sah;
        *(uint4*)&As_l[arow * TKP + acs] = sal;
        *(uint4*)&Bs_h[brow * TKP + bc]     = sbh0;
        *(uint4*)&Bs_h[brow * TKP + bc + 8] = sbh1;
        *(uint4*)&Bs_l[brow * TKP + bc]     = sbl0;
        *(uint4*)&Bs_l[brow * TKP + bc + 8] = sbl1;
        if (kt + 1 < 8) {                 // early-issue prefetch
            const int kn = kt + 1;
            const u16 *pah, *pal;
            if (kn < 4) {
                pah = xh + (size_t)(row0 + arow) * DIM + kn * 64 + acs;
                pal = xl + (size_t)(row0 + arow) * DIM + kn * 64 + acs;
            } else {
                pah = gh + (size_t)(row0 + arow) * DIM + (kn - 4) * 64 + acs;
                pal = gl + (size_t)(row0 + arow) * DIM + (kn - 4) * 64 + acs;
            }
            sah = *((const uint4*)pah);
            sal = *((const uint4*)pal);
            const u16* pbh = bth + (size_t)(col0 + brow) * 512 + kn * 64 + bc;
            const u16* pbl = btl + (size_t)(col0 + brow) * 512 + kn * 64 + bc;
            sbh0 = ((const uint4*)pbh)[0]; sbh1 = ((const uint4*)pbh)[1];
            sbl0 = ((const uint4*)pbl)[0]; sbl1 = ((const uint4*)pbl)[1];
        }
        __syncthreads();

        __builtin_amdgcn_s_setprio(1);
        #pragma unroll
        for (int kc = 0; kc < 2; ++kc) {
            const int dc = kc * 32 + h4 * 8;
            half8 afh, afl, bfh[2], bfl[2];
            afh = *(const half8*)&As_h[(rh * 16 + l15) * TKP + dc];
            afl = *(const half8*)&As_l[(rh * 16 + l15) * TKP + dc];
            #pragma unroll
            for (int bb = 0; bb < 2; ++bb) {
                const int r = ch * 32 + bb * 16 + l15;
                bfh[bb] = *(const half8*)&Bs_h[r * TKP + dc];
                bfl[bb] = *(const half8*)&Bs_l[r * TKP + dc];
            }
            #pragma unroll
            for (int bb = 0; bb < 2; ++bb) {
                acc[bb] = MFMA16(afh, bfh[bb], acc[bb]);
                acc[bb] = MFMA16(afh, bfl[bb], acc[bb]);
                acc[bb] = MFMA16(afl, bfh[bb], acc[bb]);
            }
        }
        __builtin_amdgcn_s_setprio(0);
        __syncthreads();
    }

    #pragma unroll
    for (int bb = 0; bb < 2; ++bb) {
        const int c  = col0 + ch * 32 + bb * 16 + l15;
        const int r0 = row0 + rh * 16 + h4 * 4;
        #pragma unroll
        for (int i = 0; i < 4; ++i) {
            const int r = r0 + i;
            float t = acc[bb][i] + bias[c];
            if (EPI == EPI_BNELU) {
                t = gamma[c] * (t - bnmean[c]) * rsqrtf(bnvar[c] + 1e-5f) + beta[c];
                t = t > 0.f ? t : expm1f(t);
            }
            outf[(size_t)r * DIM + c] = t;
            u16 hh, ll;
            split16(t, hh, ll);
            oh[(size_t)r * DIM + c] = hh;
            ol[(size_t)r * DIM + c] = ll;
        }
    }
    #undef TKP
}

// ---------------- QKV MFMA GEMM (fp16 3-pass, early prefetch) -------------
__global__ __launch_bounds__(256) void qkv_mfma(
    const u16* __restrict__ xh, const u16* __restrict__ xl,
    const u16* __restrict__ wth, const u16* __restrict__ wtl,
    const float* __restrict__ bias,
    u16* __restrict__ qh_o, u16* __restrict__ ql_o,
    u16* __restrict__ kh_o, u16* __restrict__ kl_o,
    u16* __restrict__ vt_o)
{
    __shared__ u16 lds[4 * 4608];
    u16* As_h = lds;
    u16* As_l = lds + 4608;
    u16* Bs_h = lds + 9216;
    u16* Bs_l = lds + 13824;
    #define TKP 72

    const int tid  = threadIdx.x;
    const int row0 = blockIdx.y * 64;
    const int mat  = blockIdx.x >> 2;
    const int col0 = (blockIdx.x & 3) * 64;
    const float* biasp = bias + mat * DIM;

    const int w   = tid >> 6;
    const int l15 = tid & 15, h4 = (tid & 63) >> 4;
    const int rh  = w & 1, ch = w >> 1;
    const int lrow = tid & 63, lseg = tid >> 6;
    const int lc = lseg * 16;

    const size_t brow = (size_t)(mat * 256 + col0 + lrow) * 256;
    uint4 sah0, sah1, sal0, sal1, sbh0, sbh1, sbl0, sbl1;
    {
        const u16* pah = xh + (size_t)(row0 + lrow) * DIM + lc;
        const u16* pal = xl + (size_t)(row0 + lrow) * DIM + lc;
        sah0 = ((const uint4*)pah)[0]; sah1 = ((const uint4*)pah)[1];
        sal0 = ((const uint4*)pal)[0]; sal1 = ((const uint4*)pal)[1];
        sbh0 = ((const uint4*)(wth + brow + lc))[0]; sbh1 = ((const uint4*)(wth + brow + lc))[1];
        sbl0 = ((const uint4*)(wtl + brow + lc))[0]; sbl1 = ((const uint4*)(wtl + brow + lc))[1];
    }

    const f32x4 z4 = {0.f, 0.f, 0.f, 0.f};
    f32x4 acc[2][2] = {{z4, z4}, {z4, z4}};

    for (int kt = 0; kt < 4; ++kt) {
        *(uint4*)&As_h[lrow * TKP + lc]     = sah0;
        *(uint4*)&As_h[lrow * TKP + lc + 8] = sah1;
        *(uint4*)&As_l[lrow * TKP + lc]     = sal0;
        *(uint4*)&As_l[lrow * TKP + lc + 8] = sal1;
        *(uint4*)&Bs_h[lrow * TKP + lc]     = sbh0;
        *(uint4*)&Bs_h[lrow * TKP + lc + 8] = sbh1;
        *(uint4*)&Bs_l[lrow * TKP + lc]     = sbl0;
        *(uint4*)&Bs_l[lrow * TKP + lc + 8] = sbl1;
        if (kt + 1 < 4) {
            const int kb = (kt + 1) * 64 + lc;
            const u16* pah = xh + (size_t)(row0 + lrow) * DIM + kb;
            const u16* pal = xl + (size_t)(row0 + lrow) * DIM + kb;
            sah0 = ((const uint4*)pah)[0]; sah1 = ((const uint4*)pah)[1];
            sal0 = ((const uint4*)pal)[0]; sal1 = ((const uint4*)pal)[1];
            sbh0 = ((const uint4*)(wth + brow + kb))[0]; sbh1 = ((const uint4*)(wth + brow + kb))[1];
            sbl0 = ((const uint4*)(wtl + brow + kb))[0]; sbl1 = ((const uint4*)(wtl + brow + kb))[1];
        }
        __syncthreads();

        __builtin_amdgcn_s_setprio(1);
        #pragma unroll
        for (int kc = 0; kc < 2; ++kc) {
            const int dc = kc * 32 + h4 * 8;
            half8 afh[2], afl[2], bfh[2], bfl[2];
            #pragma unroll
            for (int ab = 0; ab < 2; ++ab) {
                const int r = rh * 32 + ab * 16 + l15;
                afh[ab] = *(const half8*)&As_h[r * TKP + dc];
                afl[ab] = *(const half8*)&As_l[r * TKP + dc];
            }
            #pragma unroll
            for (int bb = 0; bb < 2; ++bb) {
                const int r = ch * 32 + bb * 16 + l15;
                bfh[bb] = *(const half8*)&Bs_h[r * TKP + dc];
                bfl[bb] = *(const half8*)&Bs_l[r * TKP + dc];
            }
            #pragma unroll
            for (int ab = 0; ab < 2; ++ab)
                #pragma unroll
                for (int bb = 0; bb < 2; ++bb) {
                    acc[ab][bb] = MFMA16(afh[ab], bfh[bb], acc[ab][bb]);
                    acc[ab][bb] = MFMA16(afh[ab], bfl[bb], acc[ab][bb]);
                    acc[ab][bb] = MFMA16(afl[ab], bfh[bb], acc[ab][bb]);
                }
        }
        __builtin_amdgcn_s_setprio(0);
        __syncthreads();
    }

    const float s = (mat == 0) ? 0.125f : 1.0f;
    u16* oph = (mat == 0) ? qh_o : kh_o;
    u16* opl = (mat == 0) ? ql_o : kl_o;
    #pragma unroll
    for (int ab = 0; ab < 2; ++ab)
        #pragma unroll
        for (int bb = 0; bb < 2; ++bb) {
            const int c  = col0 + ch * 32 + bb * 16 + l15;
            const int r0 = row0 + rh * 32 + ab * 16 + h4 * 4;
            if (mat < 2) {
                #pragma unroll
                for (int i = 0; i < 4; ++i) {
                    const int r = r0 + i;
                    const float t = (acc[ab][bb][i] + biasp[c]) * s;
                    u16 hh, ll;
                    split16(t, hh, ll);
                    oph[(size_t)r * DIM + c] = hh;
                    opl[(size_t)r * DIM + c] = ll;
                }
            } else {
                u16 v[4];
                #pragma unroll
                for (int i = 0; i < 4; ++i)
                    v[i] = f2h(acc[ab][bb][i] + biasp[c]);
                *(uint2*)&vt_o[(size_t)c * NN + r0] =
                    make_uint2((u32)v[0] | ((u32)v[1] << 16), (u32)v[2] | ((u32)v[3] << 16));
            }
        }
    #undef TKP
}

// ---------------- MFMA fp16 GEMM, 32x64 tile (Wo / fc1) -------------------
template<int MEPI>
__global__ __launch_bounds__(256) void mfma_gemm32(
    const u16* __restrict__ Ah, const u16* __restrict__ Al,
    const u16* __restrict__ Bth, const u16* __restrict__ Btl,
    const float* __restrict__ bias, const float* __restrict__ resid,
    float* __restrict__ outf, u16* __restrict__ outh, u16* __restrict__ outl,
    int K, int M)
{
    __shared__ u16 lds[13824];           // 27648 B
    u16* As_h = lds;                     // [32][72]
    u16* As_l = lds + 2304;
    u16* Bs_h = lds + 4608;              // [64][72]
    u16* Bs_l = lds + 9216;
    #define TKP 72

    const int tid  = threadIdx.x;
    const int row0 = blockIdx.y * 32;
    const int col0 = blockIdx.x * 64;

    const int w   = tid >> 6;
    const int l15 = tid & 15, h4 = (tid & 63) >> 4;
    const int rh  = w & 1, ch = w >> 1;
    const int arow = tid >> 3, acs = (tid & 7) * 8;
    const int brow = tid & 63, bseg = tid >> 6;
    const int bc = bseg * 16;

    uint4 sah, sal, sbh0, sbh1, sbl0, sbl1;
    {
        sah = *((const uint4*)&Ah[(size_t)(row0 + arow) * K + acs]);
        sal = *((const uint4*)&Al[(size_t)(row0 + arow) * K + acs]);
        const u16* pbh = Bth + (size_t)(col0 + brow) * K + bc;
        const u16* pbl = Btl + (size_t)(col0 + brow) * K + bc;
        sbh0 = ((const uint4*)pbh)[0]; sbh1 = ((const uint4*)pbh)[1];
        sbl0 = ((const uint4*)pbl)[0]; sbl1 = ((const uint4*)pbl)[1];
    }

    const f32x4 z4 = {0.f, 0.f, 0.f, 0.f};
    f32x4 acc[2] = {z4, z4};
    const int NKT2 = K / 64;

    for (int kt = 0; kt < NKT2; ++kt) {
        *(uint4*)&As_h[arow * TKP + acs] = sah;
        *(uint4*)&As_l[arow * TKP + acs] = sal;
        *(uint4*)&Bs_h[brow * TKP + bc]     = sbh0;
        *(uint4*)&Bs_h[brow * TKP + bc + 8] = sbh1;
        *(uint4*)&Bs_l[brow * TKP + bc]     = sbl0;
        *(uint4*)&Bs_l[brow * TKP + bc + 8] = sbl1;
        if (kt + 1 < NKT2) {              // early-issue prefetch
            const int kb = (kt + 1) * 64;
            sah = *((const uint4*)&Ah[(size_t)(row0 + arow) * K + kb + acs]);
            sal = *((const uint4*)&Al[(size_t)(row0 + arow) * K + kb + acs]);
            const u16* pbh = Bth + (size_t)(col0 + brow) * K + kb + bc;
            const u16* pbl = Btl + (size_t)(col0 + brow) * K + kb + bc;
            sbh0 = ((const uint4*)pbh)[0]; sbh1 = ((const uint4*)pbh)[1];
            sbl0 = ((const uint4*)pbl)[0]; sbl1 = ((const uint4*)pbl)[1];
        }
        __syncthreads();

        __builtin_amdgcn_s_setprio(1);
        #pragma unroll
        for (int kc = 0; kc < 2; ++kc) {
            const int dc = kc * 32 + h4 * 8;
            half8 afh, afl, bfh[2], bfl[2];
            afh = *(const half8*)&As_h[(rh * 16 + l15) * TKP + dc];
            afl = *(const half8*)&As_l[(rh * 16 + l15) * TKP + dc];
            #pragma unroll
            for (int bb = 0; bb < 2; ++bb) {
                const int r = ch * 32 + bb * 16 + l15;
                bfh[bb] = *(const half8*)&Bs_h[r * TKP + dc];
                bfl[bb] = *(const half8*)&Bs_l[r * TKP + dc];
            }
            #pragma unroll
            for (int bb = 0; bb < 2; ++bb) {
                acc[bb] = MFMA16(afh, bfh[bb], acc[bb]);
                acc[bb] = MFMA16(afh, bfl[bb], acc[bb]);
                acc[bb] = MFMA16(afl, bfh[bb], acc[bb]);
            }
        }
        __builtin_amdgcn_s_setprio(0);
        __syncthreads();
    }

    #pragma unroll
    for (int bb = 0; bb < 2; ++bb) {
        const int c  = col0 + ch * 32 + bb * 16 + l15;
        const int r0 = row0 + rh * 16 + h4 * 4;
        #pragma unroll
        for (int i = 0; i < 4; ++i) {
            const int r = r0 + i;
            float t = acc[bb][i] + bias[c];
            if (MEPI == MEPI_WO) {
                t += resid[(size_t)r * M + c];
                u16 hh, ll;
                split16(t, hh, ll);
                outh[(size_t)r * M + c] = hh;
                outl[(size_t)r * M + c] = ll;
            } else {    // FC1: bias + ELU -> fp32 feats
                t = t > 0.f ? t : expm1f(t);
                outf[(size_t)r * M + c] = t;
            }
        }
    }
    #undef TKP
}

// ---------------- MFMA flash attention (round-17) -------------------------
// Round-16 dbuf structure + SWAPPED QK^T: mfma(A=K, B=Q) gives S^T so each
// lane holds 16 k-values for ONE q (q = w*16 + l15). Softmax max/sum become
// local trees + 2 shfl_xor; m/l/rescale lane-local (no frow); the PV
// P-fragment is assembled via 16 __shfl among the 4 lanes sharing l15
// (no P LDS buffer at all). Defer-max (THR=8) kept.
#define QB 128
#define KB 64
#define NSPLIT 4
#define NKT (NN / KB)
#define KP 72

__global__ __launch_bounds__(512, 2) void attn_kernel(
    const u16* __restrict__ qhi, const u16* __restrict__ qlo,
    const u16* __restrict__ khi, const u16* __restrict__ klo,
    const u16* __restrict__ vT,
    float* __restrict__ op0, float* __restrict__ op1,
    float* __restrict__ op2, float* __restrict__ op3,
    float* __restrict__ mpart, float* __restrict__ lpart)
{
    __shared__ u16 lds[27648];            // 55296 B
    u16* Kh0 = lds;                       // buf0 [64][72] x3
    u16* Kl0 = lds + 4608;
    u16* Vt0 = lds + 9216;
    u16* Kh1 = lds + 13824;               // buf1
    u16* Kl1 = lds + 18432;
    u16* Vt1 = lds + 23040;
    u16* Qh  = lds;                       // overlay (init): [128][72]
    u16* Ql  = lds + 13824;               // overlay (init)

    const int tid = threadIdx.x;
    const int h   = blockIdx.y;
    const int q0  = blockIdx.x * QB;
    const int sp  = blockIdx.z;
    const int kt0 = sp * (NKT / NSPLIT);  // 16 tiles/block (even)
    const int kt1 = kt0 + NKT / NSPLIT;

    const int w   = tid >> 6;             // wave 0..7 -> q rows w*16..+15
    const int l15 = tid & 15, h4 = (tid & 63) >> 4;
    const int lrow = tid & 63, lseg = tid >> 6;   // staging: 8 segs x 8 u16
    const int gq8 = h * DH + lseg * 8;

    {   // stage Q (once, into overlay region): 128 rows x 64 d
        const int qrow = tid >> 2, qseg = tid & 3;
        const u16* s0 = qhi + (size_t)(q0 + qrow) * DIM + h * DH + qseg * 16;
        const u16* s1 = qlo + (size_t)(q0 + qrow) * DIM + h * DH + qseg * 16;
        uint4 a = ((const uint4*)s0)[0], b = ((const uint4*)s0)[1];
        uint4 c = ((const uint4*)s1)[0], d = ((const uint4*)s1)[1];
        *(uint4*)&Qh[qrow * KP + qseg * 16]     = a;
        *(uint4*)&Qh[qrow * KP + qseg * 16 + 8] = b;
        *(uint4*)&Ql[qrow * KP + qseg * 16]     = c;
        *(uint4*)&Ql[qrow * KP + qseg * 16 + 8] = d;
    }

    uint4 rk, rl, rv;                     // staging registers
    auto load_tile = [&](int kt_ld) {
        const int key0 = kt_ld * KB;
        rk = *(const uint4*)(khi + (size_t)(key0 + lrow) * DIM + gq8);
        rl = *(const uint4*)(klo + (size_t)(key0 + lrow) * DIM + gq8);
        rv = *(const uint4*)(vT + (size_t)(h * DH + lrow) * NN + key0 + lseg * 8);
    };
    load_tile(kt0);
    __syncthreads();                              // Q staged

    half8 qf[2][2];                               // [kc][hi/lo]
    #pragma unroll
    for (int kc = 0; kc < 2; ++kc) {
        const int r = w * 16 + l15;
        const int dc = kc * 32 + h4 * 8;
        qf[kc][0] = *(const half8*)&Qh[r * KP + dc];
        qf[kc][1] = *(const half8*)&Ql[r * KP + dc];
    }
    __syncthreads();                              // hoist done; overlay safe

    auto stage_to = [&](u16* Kh, u16* Kl, u16* Vt) {
        *(uint4*)&Kh[lrow * KP + lseg * 8] = rk;
        *(uint4*)&Kl[lrow * KP + lseg * 8] = rl;
        *(uint4*)&Vt[lrow * KP + lseg * 8] = rv;
    };

    stage_to(Kh0, Kl0, Vt0);                      // tile kt0 -> buf0
    load_tile(kt0 + 1);                           // tile kt0+1 -> regs
    __syncthreads();                              // buf0 ready

    const f32x4 z4 = {0.f, 0.f, 0.f, 0.f};
    f32x4 oacc[4] = {z4, z4, z4, z4};             // d-blocks 0..3 for own q
    float m_run = -3.0e38f, l_run = 0.f;          // lane-local: q = w*16+l15
    const int sl0 = (h4 & 1) * 32 + l15;          // P-shuffle source lanes
    const int sl1 = sl0 + 16;

    auto tile_body = [&](int t, u16* Kc, u16* Lc, u16* Vc,
                         u16* Kn, u16* Ln, u16* Vn) {
        if (t + 1 < kt1) stage_to(Kn, Ln, Vn);    // writes to the idle buffer
        if (t + 2 < kt1) load_tile(t + 2);        // early-issue global loads

        // ---- S^T = K Q^T (swapped operands): lane holds S[q][16 k-vals]
        // k = kcb*16 + h4*4 + i  for kcb=0..3, i=0..3; q = w*16 + l15.
        f32x4 sc[4] = {z4, z4, z4, z4};
        __builtin_amdgcn_s_setprio(1);
        #pragma unroll
        for (int kc = 0; kc < 2; ++kc) {
            const int dc = kc * 32 + h4 * 8;
            half8 kfh[4], kfl[4];
            #pragma unroll
            for (int kcb = 0; kcb < 4; ++kcb) {
                const int r = kcb * 16 + l15;
                kfh[kcb] = *(const half8*)&Kc[r * KP + dc];
                kfl[kcb] = *(const half8*)&Lc[r * KP + dc];
            }
            #pragma unroll
            for (int kcb = 0; kcb < 4; ++kcb) {
                sc[kcb] = MFMA16(kfh[kcb], qf[kc][0], sc[kcb]);
                sc[kcb] = MFMA16(kfl[kcb], qf[kc][0], sc[kcb]);
                sc[kcb] = MFMA16(kfh[kcb], qf[kc][1], sc[kcb]);
            }
        }
        __builtin_amdgcn_s_setprio(0);

        // ---- lane-local softmax: tree max over 16, 2-shfl all-reduce ----
        float c0 = fmaxf(fmaxf(sc[0][0], sc[0][1]), fmaxf(sc[0][2], sc[0][3]));
        float c1 = fmaxf(fmaxf(sc[1][0], sc[1][1]), fmaxf(sc[1][2], sc[1][3]));
        float c2 = fmaxf(fmaxf(sc[2][0], sc[2][1]), fmaxf(sc[2][2], sc[2][3]));
        float c3 = fmaxf(fmaxf(sc[3][0], sc[3][1]), fmaxf(sc[3][2], sc[3][3]));
        float pm = fmaxf(fmaxf(c0, c1), fmaxf(c2, c3));
        pm = fmaxf(pm, __shfl_xor(pm, 16));
        pm = fmaxf(pm, __shfl_xor(pm, 32));

        float p[4][4];
        float base, fr = 1.f;
        int resc;
        if (__all(pm - m_run <= 8.f)) {           // defer-max (THR=8)
            base = m_run;
            resc = 0;
        } else {
            const float mnew = fmaxf(m_run, pm);
            fr = __expf(m_run - mnew);
            m_run = mnew;
            base = mnew;
            resc = 1;
        }
        #pragma unroll
        for (int kcb = 0; kcb < 4; ++kcb)
            #pragma unroll
            for (int i = 0; i < 4; ++i)
                p[kcb][i] = __expf(sc[kcb][i] - base);
        float s0s = (p[0][0] + p[0][1]) + (p[0][2] + p[0][3]);
        float s1s = (p[1][0] + p[1][1]) + (p[1][2] + p[1][3]);
        float s2s = (p[2][0] + p[2][1]) + (p[2][2] + p[2][3]);
        float s3s = (p[3][0] + p[3][1]) + (p[3][2] + p[3][3]);
        float ls = (s0s + s1s) + (s2s + s3s);
        ls += __shfl_xor(ls, 16);
        ls += __shfl_xor(ls, 32);
        if (resc) {
            l_run = l_run * fr + ls;
            #pragma unroll
            for (int db = 0; db < 4; ++db) oacc[db] *= fr;
        } else {
            l_run += ls;
        }

        // ---- pack P to fp16 pairs (per kcb: [i0|i1], [i2|i3]) ----
        u32 pk01[4], pk23[4];
        #pragma unroll
        for (int kcb = 0; kcb < 4; ++kcb) {
            pk01[kcb] = (u32)f2h(p[kcb][0]) | ((u32)f2h(p[kcb][1]) << 16);
            pk23[kcb] = (u32)f2h(p[kcb][2]) | ((u32)f2h(p[kcb][3]) << 16);
        }

        // ---- PV: B-fragment built by shuffles among lanes sharing l15 ----
        // consumer (h4, kc) needs P[q][k = kc*32 + h4*8 + j], j=0..7:
        // kcb_w = kc*2 + (h4>>1); j<4 from lane sl0 (i=j), j>=4 from sl1.
        const int hiSel = h4 >> 1;
        __builtin_amdgcn_s_setprio(1);
        #pragma unroll
        for (int kc = 0; kc < 2; ++kc) {
            const u32 a0 = (u32)__shfl((int)pk01[kc * 2], sl0);
            const u32 a1 = (u32)__shfl((int)pk23[kc * 2], sl0);
            const u32 a2 = (u32)__shfl((int)pk01[kc * 2], sl1);
            const u32 a3 = (u32)__shfl((int)pk23[kc * 2], sl1);
            const u32 b0 = (u32)__shfl((int)pk01[kc * 2 + 1], sl0);
            const u32 b1 = (u32)__shfl((int)pk23[kc * 2 + 1], sl0);
            const u32 b2 = (u32)__shfl((int)pk01[kc * 2 + 1], sl1);
            const u32 b3 = (u32)__shfl((int)pk23[kc * 2 + 1], sl1);
            union { half8 v; u32 u[4]; } pf;
            pf.u[0] = hiSel ? b0 : a0;
            pf.u[1] = hiSel ? b1 : a1;
            pf.u[2] = hiSel ? b2 : a2;
            pf.u[3] = hiSel ? b3 : a3;
            #pragma unroll
            for (int db = 0; db < 4; ++db) {
                const half8 vf = *(const half8*)&Vc[(db * 16 + l15) * KP + kc * 32 + h4 * 8];
                oacc[db] = MFMA16(vf, pf.v, oacc[db]);
            }
        }
        __builtin_amdgcn_s_setprio(0);
        __syncthreads();   // single per-tile barrier: buf^1 staged + reads done
    };

    for (int t = kt0; t < kt1; t += 2) {
        tile_body(t,     Kh0, Kl0, Vt0, Kh1, Kl1, Vt1);
        tile_body(t + 1, Kh1, Kl1, Vt1, Kh0, Kl0, Vt0);
    }

    float* ob = (sp == 0) ? op0 : ((sp == 1) ? op1 : ((sp == 2) ? op2 : op3));
    #pragma unroll
    for (int db = 0; db < 4; ++db)
        *(f32x4*)&ob[(size_t)(q0 + w * 16 + l15) * DIM + h * DH + db * 16 + h4 * 4] = oacc[db];
    if (h4 == 0) {
        const int r = w * 16 + l15;
        mpart[((size_t)sp * NN + q0 + r) * NH + h] = m_run;
        lpart[((size_t)sp * NN + q0 + r) * NH + h] = l_run;
    }
}

// merge the 4 partials -> fp16 hi/lo planes (feeds the MFMA Wo GEMM)
__global__ __launch_bounds__(256) void attn_combine(
    const float* __restrict__ o0, const float* __restrict__ o1,
    const float* __restrict__ o2, const float* __restrict__ o3,
    const float* __restrict__ mp, const float* __restrict__ lp,
    u16* __restrict__ ohi, u16* __restrict__ olo)
{
    const int gid = blockIdx.x * 256 + threadIdx.x;
    const int row = gid >> 6;
    const int c4  = (gid & 63) * 4;
    const int h   = c4 >> 6;
    float m[4], wgt[4];
    #pragma unroll
    for (int z = 0; z < 4; ++z) m[z] = mp[((size_t)z * NN + row) * NH + h];
    const float M = fmaxf(fmaxf(m[0], m[1]), fmaxf(m[2], m[3]));
    float den = 0.f;
    #pragma unroll
    for (int z = 0; z < 4; ++z) {
        wgt[z] = __expf(m[z] - M);
        den += lp[((size_t)z * NN + row) * NH + h] * wgt[z];
    }
    const float inv = 1.f / den;
    const float4 a = *(const float4*)&o0[(size_t)row * DIM + c4];
    const float4 b = *(const float4*)&o1[(size_t)row * DIM + c4];
    const float4 c = *(const float4*)&o2[(size_t)row * DIM + c4];
    const float4 d = *(const float4*)&o3[(size_t)row * DIM + c4];
    float r[4];
    r[0] = (a.x * wgt[0] + b.x * wgt[1] + c.x * wgt[2] + d.x * wgt[3]) * inv;
    r[1] = (a.y * wgt[0] + b.y * wgt[1] + c.y * wgt[2] + d.y * wgt[3]) * inv;
    r[2] = (a.z * wgt[0] + b.z * wgt[1] + c.z * wgt[2] + d.z * wgt[3]) * inv;
    r[3] = (a.w * wgt[0] + b.w * wgt[1] + c.w * wgt[2] + d.w * wgt[3]) * inv;
    u16 hh[4], ll[4];
    #pragma unroll
    for (int j = 0; j < 4; ++j) split16(r[j], hh[j], ll[j]);
    *(uint2*)&ohi[(size_t)row * DIM + c4] =
        make_uint2((u32)hh[0] | ((u32)hh[1] << 16), (u32)hh[2] | ((u32)hh[3] << 16));
    *(uint2*)&olo[(size_t)row * DIM + c4] =
        make_uint2((u32)ll[0] | ((u32)ll[1] << 16), (u32)ll[2] | ((u32)ll[3] << 16));
}

// ---------------- per-node group adapter: 4 nodes per 256-thr block -------
__global__ __launch_bounds__(256) void adapter_kernel(
    const float* __restrict__ feats, const int* __restrict__ grp,
    const float* __restrict__ AW1, const float* __restrict__ Ab1,
    const float* __restrict__ AW2, const float* __restrict__ Ab2,
    float* __restrict__ out)
{
    const int wv = threadIdx.x >> 6;
    const int n = blockIdx.x * 4 + wv;
    const int lane = threadIdx.x & 63;
    __shared__ float f[4][F1D];
    f[wv][lane]      = feats[(size_t)n * F1D + lane];
    f[wv][lane + 64] = feats[(size_t)n * F1D + 64 + lane];
    // wave-local LDS: compiler waitcnt orders reads (no barrier needed)
    const int g = grp[n];
    const float* W1 = AW1 + (size_t)g * F1D * AD;
    const int a = lane & 31;
    const int half = lane >> 5;
    float hsum = 0.f;
    for (int d = 0; d < 64; ++d)
        hsum = fmaf(f[wv][half * 64 + d], W1[(half * 64 + d) * AD + a], hsum);
    hsum += __shfl_xor(hsum, 32);
    hsum = fmaxf(hsum + Ab1[g * AD + a], 0.f);
    float p = hsum * AW2[g * AD + a];
    #pragma unroll
    for (int mm = 1; mm < 32; mm <<= 1) p += __shfl_xor(p, mm);
    if (lane == 0) out[n] = p + Ab2[g];
}

// ---------------- host-side orchestration ----------------
extern "C" void kernel_launch(void* const* d_in, const int* in_sizes, int n_in,
                              void* d_out, int out_size, void* d_ws, size_t ws_size,
                              hipStream_t stream)
{
    const float* x_in   = (const float*)d_in[0];
    const float* eattr  = (const float*)d_in[1];
    const float* Wself  = (const float*)d_in[2];
    const float* Wnbr   = (const float*)d_in[3];
    const float* convb  = (const float*)d_in[4];
    const float* gamma  = (const float*)d_in[5];
    const float* beta   = (const float*)d_in[6];
    const float* bnmean = (const float*)d_in[7];
    const float* bnvar  = (const float*)d_in[8];
    const float* Wqkv   = (const float*)d_in[9];
    const float* bqkv   = (const float*)d_in[10];
    const float* Wo     = (const float*)d_in[11];
    const float* bo     = (const float*)d_in[12];
    const float* fc1W   = (const float*)d_in[13];
    const float* fc1b   = (const float*)d_in[14];
    const float* AW1    = (const float*)d_in[15];
    const float* Ab1    = (const float*)d_in[16];
    const float* AW2    = (const float*)d_in[17];
    const float* Ab2    = (const float*)d_in[18];
    const int*   eidx   = (const int*)d_in[19];
    const int*   grp    = (const int*)d_in[20];
    const int* srcArr = eidx;
    const int* dstArr = eidx + NE;

    float* fws = (float*)d_ws;
    const size_t NM = (size_t)NN * DIM;
    float* bufA  = fws;                  // x L0 / x L2 (residual)
    float* bufB  = fws + NM;             // attn op0
    float* bufC  = fws + 2 * NM;         // x L1 / attn op1
    float* feats = fws + 3 * NM;         // NN x F1D
    float* mpart = fws + 3 * NM + NM / 2;         // [4][NN][NH]
    float* lpart = mpart + 4 * NN * NH;
    u16* up = (u16*)(lpart + 4 * NN * NH);
    u16* xpAh = up;             u16* xpAl = xpAh + NM;   // x planes ping
    u16* xpBh = xpAl + NM;      u16* xpBl = xpBh + NM;   // x planes pong
    u16* aggh = xpBl + NM;      u16* aggl = aggh + NM;   // agg planes
    u16* qh = aggl + NM;        u16* ql = qh + NM;       // Q planes / combine out
    u16* kh = ql + NM;          u16* kl = kh + NM;       // K planes / Wo out
    u16* vt = kl + NM;                                   // V^T fp16 [256][NN]
    u16* wcath = vt + NM;                                // [3][256][512]
    u16* wcatl = wcath + 3 * 131072;
    u16* wt4h  = wcatl + 3 * 131072;                     // [4][256][256] qkv+wo
    u16* wt4l  = wt4h + 4 * 65536;
    u16* fc1h  = wt4l + 4 * 65536;                       // [128][256]
    u16* fc1l  = fc1h + 32768;
    int*   esrc = (int*)(fc1l + 32768);                  // NE
    float* ewt  = (float*)(esrc + NE);                   // NE
    int* off    = (int*)(ewt + NE);                      // NN+1
    int* cur    = off + NN + 1;                          // NN
    float* outp = (float*)d_out;

    float* op2 = (float*)xpAh;           // attn partial overlays
    float* op3 = (float*)xpBh;

    // fused prep: all converts + zero(cur)
    prep_kernel<<<1700, 256, 0, stream>>>(
        x_in, Wself, Wnbr, Wqkv, Wo, fc1W,
        xpAh, xpAl, wcath, wcatl, wt4h, wt4l, fc1h, fc1l, cur);

    // CSR build (csr_scan zeroes cur for csr_fill)
    csr_count<<<NE / 256, 256, 0, stream>>>(dstArr, cur);
    csr_scan<<<1, 1024, 0, stream>>>(cur, off);
    csr_fill<<<NE / 256, 256, 0, stream>>>(dstArr, srcArr, eattr, off, cur, esrc, ewt);

    const dim3 gc(DIM / 64, NN / 32);    // 32-row conv tiles: 512 blocks
    const int rgrid = NN * DIM / 4 / 256;

    // conv layer 0: x_in -> bufA (fp32) + xpB planes
    agg_kernel<false><<<NN / 4, 256, 0, stream>>>(x_in, esrc, ewt, off, aggh, aggl);
    conv_mfma<EPI_BNELU><<<gc, 256, 0, stream>>>(
        xpAh, xpAl, aggh, aggl, wcath, wcatl, convb,
        gamma, beta, bnmean, bnvar, bufA, xpBh, xpBl);
    // conv layer 1: bufA -> bufC + xpA planes
    agg_kernel<false><<<NN / 4, 256, 0, stream>>>(bufA, esrc, ewt, off, aggh, aggl);
    conv_mfma<EPI_BNELU><<<gc, 256, 0, stream>>>(
        xpBh, xpBl, aggh, aggl, wcath + 131072, wcatl + 131072, convb + DIM,
        gamma + DIM, beta + DIM, bnmean + DIM, bnvar + DIM, bufC, xpAh, xpAl);
    // conv layer 2 (edge-weighted, bias only): bufC -> bufA + xpB planes
    agg_kernel<true><<<NN / 4, 256, 0, stream>>>(bufC, esrc, ewt, off, aggh, aggl);
    conv_mfma<EPI_BIAS><<<gc, 256, 0, stream>>>(
        xpAh, xpAl, aggh, aggl, wcath + 262144, wcatl + 262144, convb + 2 * DIM,
        nullptr, nullptr, nullptr, nullptr, bufA, xpBh, xpBl);

    // QKV (fp16 3-pass MFMA) -> Q/K planes (Q/8) + V^T
    qkv_mfma<<<dim3(12, NN / 64), 256, 0, stream>>>(
        xpBh, xpBl, wt4h, wt4l, bqkv, qh, ql, kh, kl, vt);

    // flash attention (8-wave QB=128, dbuf, swapped QK^T) -> combine
    attn_kernel<<<dim3(NN / QB, NH, NSPLIT), 512, 0, stream>>>(
        qh, ql, kh, kl, vt, bufB, bufC, op2, op3, mpart, lpart);
    attn_combine<<<rgrid, 256, 0, stream>>>(
        bufB, bufC, op2, op3, mpart, lpart, qh, ql);

    // Wo + residual (fp16 3-pass MFMA, 32x64 tiles): kh/kl = planes(...)
    mfma_gemm32<MEPI_WO><<<dim3(DIM / 64, NN / 32), 256, 0, stream>>>(
        qh, ql, wt4h + 3 * 65536, wt4l + 3 * 65536, bo, bufA,
        nullptr, kh, kl, DIM, DIM);

    // fc1 + ELU (fp16 3-pass MFMA, 32x64 tiles): feats = elu(x' @ fc1W + fc1b)
    mfma_gemm32<MEPI_FC1><<<dim3(F1D / 64, NN / 32), 256, 0, stream>>>(
        kh, kl, fc1h, fc1l, fc1b, nullptr, feats, nullptr, nullptr, DIM, F1D);

    // adapter routing -> out
    adapter_kernel<<<NN / 4, 256, 0, stream>>>(feats, grp, AW1, Ab1, AW2, Ab2, outp);
}

// Round 18
// 211.493 us; speedup vs baseline: 1.1743x; 1.0007x over previous
//
#include <hip/hip_runtime.h>
#include <math.h>

#define NN   4096
#define DIM  256
#define NE   131072
#define NH   4
#define DH   64
#define F1D  128
#define NG   16
#define AD   32

typedef unsigned short u16;
typedef unsigned int   u32;
typedef _Float16 f16;
typedef __attribute__((ext_vector_type(8))) _Float16 half8;
typedef __attribute__((ext_vector_type(4))) float f32x4;

enum { EPI_BIAS = 0, EPI_BNELU = 1 };
enum { MEPI_WO = 0, MEPI_FC1 = 1 };

#define MFMA16(a, b, c) __builtin_amdgcn_mfma_f32_16x16x32_f16(a, b, c, 0, 0, 0)

__device__ inline u16 f2h(float x) { union { f16 f; u16 u; } c; c.f = (f16)x; return c.u; }
__device__ inline float h2f(u16 h) { union { f16 f; u16 u; } c; c.u = h; return (float)c.f; }
// fp16 hi/lo split: x = hi + lo + eps, |eps| <= 2^-24 |x|  (fp32-grade)
__device__ inline void split16(float x, u16& h, u16& l) {
    union { f16 f; u16 u; } ch, cl;
    ch.f = (f16)x;
    cl.f = (f16)(x - (float)ch.f);
    h = ch.u; l = cl.u;
}
// XOR-swizzled index into a [64|128][64]-u16 LDS tile (128 B rows).
// colByte is 16B-aligned; XOR of (row&7)<<4 keeps 16B alignment and spreads
// the 128B-stride row accesses across 8 bank groups (2-way = free).
__device__ inline int swz64(int row, int colByte) {
    return row * 64 + ((colByte ^ ((row & 7) << 4)) >> 1);
}

// ---------------- CSR build ----------------
__global__ void csr_count(const int* __restrict__ dst, int* __restrict__ cnt) {
    int e = blockIdx.x * 256 + threadIdx.x;
    atomicAdd(&cnt[dst[e]], 1);
}

__global__ __launch_bounds__(1024) void csr_scan(
    int* __restrict__ cnt, int* __restrict__ off)
{
    __shared__ int wsum[16];
    const int t = threadIdx.x;
    const int lane = t & 63;
    int4 v = *(const int4*)&cnt[t * 4];
    const int s = v.x + v.y + v.z + v.w;
    int acc = s;
    #pragma unroll
    for (int o = 1; o < 64; o <<= 1) {
        int u = __shfl_up(acc, o);
        if (lane >= o) acc += u;
    }
    if (lane == 63) wsum[t >> 6] = acc;
    __syncthreads();
    if (t < 16) {
        int w0 = wsum[t];
        int a2 = w0;
        #pragma unroll
        for (int o = 1; o < 16; o <<= 1) {
            int u = __shfl_up(a2, o);
            if (t >= o) a2 += u;
        }
        wsum[t] = a2 - w0;
    }
    __syncthreads();
    const int base = wsum[t >> 6] + (acc - s);
    off[t * 4 + 0] = base;
    off[t * 4 + 1] = base + v.x;
    off[t * 4 + 2] = base + v.x + v.y;
    off[t * 4 + 3] = base + v.x + v.y + v.z;
    *(int4*)&cnt[t * 4] = make_int4(0, 0, 0, 0);
    if (t == 1023) off[NN] = base + s;
}

__global__ void csr_fill(const int* __restrict__ dst, const int* __restrict__ src,
                         const float* __restrict__ eattr, const int* __restrict__ off,
                         int* __restrict__ cur, int* __restrict__ esrc,
                         float* __restrict__ ewt) {
    int e = blockIdx.x * 256 + threadIdx.x;
    int d = dst[e];
    int pos = off[d] + atomicAdd(&cur[d], 1);
    esrc[pos] = src[e];
    ewt[pos]  = eattr[e];
}

// ---------------- fused one-time prep: all weight/x converts + zero cur ----
__global__ __launch_bounds__(256) void prep_kernel(
    const float* __restrict__ x,
    const float* __restrict__ Ws, const float* __restrict__ Wn,
    const float* __restrict__ Wqkv, const float* __restrict__ Wo,
    const float* __restrict__ fc1W,
    u16* __restrict__ xh, u16* __restrict__ xl,
    u16* __restrict__ wch, u16* __restrict__ wcl,
    u16* __restrict__ w4h, u16* __restrict__ w4l,
    u16* __restrict__ f1h, u16* __restrict__ f1l,
    int* __restrict__ cur)
{
    const int b = blockIdx.x;
    const int t = threadIdx.x;
    if (b < 1024) {
        const int gid = b * 256 + t;
        const float4 v = *(const float4*)&x[(size_t)gid * 4];
        u16 h[4], l[4];
        split16(v.x, h[0], l[0]); split16(v.y, h[1], l[1]);
        split16(v.z, h[2], l[2]); split16(v.w, h[3], l[3]);
        *(uint2*)&xh[(size_t)gid * 4] =
            make_uint2((u32)h[0] | ((u32)h[1] << 16), (u32)h[2] | ((u32)h[3] << 16));
        *(uint2*)&xl[(size_t)gid * 4] =
            make_uint2((u32)l[0] | ((u32)l[1] << 16), (u32)l[2] | ((u32)l[3] << 16));
    } else if (b < 1408) {
        const int gid = (b - 1024) * 256 + t;
        const int L = gid / 32768;
        const int rem = gid % 32768;
        const int m = rem / 128;
        const int k4 = (rem % 128) * 4;
        const float* S = Ws + (size_t)L * 65536;
        const float* Nb = Wn + (size_t)L * 65536;
        u16 h[4], l[4];
        #pragma unroll
        for (int j = 0; j < 4; ++j) {
            const int k = k4 + j;
            const float v = (k < 256) ? S[(size_t)k * 256 + m]
                                      : Nb[(size_t)(k - 256) * 256 + m];
            split16(v, h[j], l[j]);
        }
        const size_t o = (size_t)L * 131072 + (size_t)m * 512 + k4;
        *(uint2*)&wch[o] = make_uint2((u32)h[0] | ((u32)h[1] << 16), (u32)h[2] | ((u32)h[3] << 16));
        *(uint2*)&wcl[o] = make_uint2((u32)l[0] | ((u32)l[1] << 16), (u32)l[2] | ((u32)l[3] << 16));
    } else if (b < 1664) {
        const int gid = (b - 1408) * 256 + t;
        const int mat = gid / 16384;
        const int rem = gid % 16384;
        const int m = rem / 64;
        const int k4 = (rem % 64) * 4;
        const float* W = (mat < 3) ? Wqkv + (size_t)mat * 65536 : Wo;
        u16 h[4], l[4];
        #pragma unroll
        for (int j = 0; j < 4; ++j)
            split16(W[(size_t)(k4 + j) * 256 + m], h[j], l[j]);
        const size_t o = (size_t)mat * 65536 + (size_t)m * 256 + k4;
        *(uint2*)&w4h[o] = make_uint2((u32)h[0] | ((u32)h[1] << 16), (u32)h[2] | ((u32)h[3] << 16));
        *(uint2*)&w4l[o] = make_uint2((u32)l[0] | ((u32)l[1] << 16), (u32)l[2] | ((u32)l[3] << 16));
    } else if (b < 1696) {
        const int gid = (b - 1664) * 256 + t;
        const int m = gid / 64;
        const int k4 = (gid % 64) * 4;
        u16 h[4], l[4];
        #pragma unroll
        for (int j = 0; j < 4; ++j)
            split16(fc1W[(size_t)(k4 + j) * F1D + m], h[j], l[j]);
        const size_t o = (size_t)m * 256 + k4;
        *(uint2*)&f1h[o] = make_uint2((u32)h[0] | ((u32)h[1] << 16), (u32)h[2] | ((u32)h[3] << 16));
        *(uint2*)&f1l[o] = make_uint2((u32)l[0] | ((u32)l[1] << 16), (u32)l[2] | ((u32)l[3] << 16));
    } else {
        const int gid = (b - 1696) * 256 + t;
        if (gid < NN / 4) *(int4*)&cur[gid * 4] = make_int4(0, 0, 0, 0);
    }
}

// ---------------- neighbor aggregation: 1 wave per node, fp16-plane out ---
template<bool LAST>
__global__ __launch_bounds__(256) void agg_kernel(
    const float* __restrict__ x, const int* __restrict__ esrc,
    const float* __restrict__ ewt, const int* __restrict__ off,
    u16* __restrict__ aggh, u16* __restrict__ aggl)
{
    const int node = blockIdx.x * 4 + (threadIdx.x >> 6);
    const int lane = threadIdx.x & 63;
    const int d4 = lane * 4;
    int j = off[node];
    const int j1 = off[node + 1];
    float4 acc = make_float4(0.f, 0.f, 0.f, 0.f);
    for (; j + 4 <= j1; j += 4) {
        const int s0 = esrc[j], s1 = esrc[j + 1], s2 = esrc[j + 2], s3 = esrc[j + 3];
        const float4 x0 = *(const float4*)&x[(size_t)s0 * DIM + d4];
        const float4 x1 = *(const float4*)&x[(size_t)s1 * DIM + d4];
        const float4 x2 = *(const float4*)&x[(size_t)s2 * DIM + d4];
        const float4 x3 = *(const float4*)&x[(size_t)s3 * DIM + d4];
        const float w0 = LAST ? ewt[j]     : 1.f;
        const float w1 = LAST ? ewt[j + 1] : 1.f;
        const float w2 = LAST ? ewt[j + 2] : 1.f;
        const float w3 = LAST ? ewt[j + 3] : 1.f;
        acc.x = fmaf(x0.x, w0, acc.x); acc.y = fmaf(x0.y, w0, acc.y);
        acc.z = fmaf(x0.z, w0, acc.z); acc.w = fmaf(x0.w, w0, acc.w);
        acc.x = fmaf(x1.x, w1, acc.x); acc.y = fmaf(x1.y, w1, acc.y);
        acc.z = fmaf(x1.z, w1, acc.z); acc.w = fmaf(x1.w, w1, acc.w);
        acc.x = fmaf(x2.x, w2, acc.x); acc.y = fmaf(x2.y, w2, acc.y);
        acc.z = fmaf(x2.z, w2, acc.z); acc.w = fmaf(x2.w, w2, acc.w);
        acc.x = fmaf(x3.x, w3, acc.x); acc.y = fmaf(x3.y, w3, acc.y);
        acc.z = fmaf(x3.z, w3, acc.z); acc.w = fmaf(x3.w, w3, acc.w);
    }
    for (; j < j1; ++j) {
        const int s = esrc[j];
        const float w = LAST ? ewt[j] : 1.f;
        const float4 xv = *(const float4*)&x[(size_t)s * DIM + d4];
        acc.x = fmaf(xv.x, w, acc.x); acc.y = fmaf(xv.y, w, acc.y);
        acc.z = fmaf(xv.z, w, acc.z); acc.w = fmaf(xv.w, w, acc.w);
    }
    u16 h[4], l[4];
    split16(acc.x, h[0], l[0]); split16(acc.y, h[1], l[1]);
    split16(acc.z, h[2], l[2]); split16(acc.w, h[3], l[3]);
    *(uint2*)&aggh[(size_t)node * DIM + d4] =
        make_uint2((u32)h[0] | ((u32)h[1] << 16), (u32)h[2] | ((u32)h[3] << 16));
    *(uint2*)&aggl[(size_t)node * DIM + d4] =
        make_uint2((u32)l[0] | ((u32)l[1] << 16), (u32)l[2] | ((u32)l[3] << 16));
}

// ---------------- conv MFMA GEMM: 32x64 tile (2 blocks/CU) ----------------
template<int EPI>
__global__ __launch_bounds__(256) void conv_mfma(
    const u16* __restrict__ xh, const u16* __restrict__ xl,
    const u16* __restrict__ gh, const u16* __restrict__ gl,
    const u16* __restrict__ bth, const u16* __restrict__ btl,
    const float* __restrict__ bias,
    const float* __restrict__ gamma, const float* __restrict__ beta,
    const float* __restrict__ bnmean, const float* __restrict__ bnvar,
    float* __restrict__ outf, u16* __restrict__ oh, u16* __restrict__ ol)
{
    __shared__ u16 lds[13824];           // 27648 B
    u16* As_h = lds;                     // [32][72]
    u16* As_l = lds + 2304;
    u16* Bs_h = lds + 4608;              // [64][72]
    u16* Bs_l = lds + 9216;
    #define TKP 72

    const int tid  = threadIdx.x;
    const int row0 = blockIdx.y * 32;
    const int col0 = blockIdx.x * 64;

    const int w   = tid >> 6;
    const int l15 = tid & 15, h4 = (tid & 63) >> 4;
    const int rh  = w & 1, ch = w >> 1;
    const int arow = tid >> 3, acs = (tid & 7) * 8;
    const int brow = tid & 63, bseg = tid >> 6;
    const int bc = bseg * 16;

    uint4 sah, sal, sbh0, sbh1, sbl0, sbl1;
    {
        sah = *((const uint4*)&xh[(size_t)(row0 + arow) * DIM + acs]);
        sal = *((const uint4*)&xl[(size_t)(row0 + arow) * DIM + acs]);
        const u16* pbh = bth + (size_t)(col0 + brow) * 512 + bc;
        const u16* pbl = btl + (size_t)(col0 + brow) * 512 + bc;
        sbh0 = ((const uint4*)pbh)[0]; sbh1 = ((const uint4*)pbh)[1];
        sbl0 = ((const uint4*)pbl)[0]; sbl1 = ((const uint4*)pbl)[1];
    }

    const f32x4 z4 = {0.f, 0.f, 0.f, 0.f};
    f32x4 acc[2] = {z4, z4};

    for (int kt = 0; kt < 8; ++kt) {
        *(uint4*)&As_h[arow * TKP + acs] = sah;
        *(uint4*)&As_l[arow * TKP + acs] = sal;
        *(uint4*)&Bs_h[brow * TKP + bc]     = sbh0;
        *(uint4*)&Bs_h[brow * TKP + bc + 8] = sbh1;
        *(uint4*)&Bs_l[brow * TKP + bc]     = sbl0;
        *(uint4*)&Bs_l[brow * TKP + bc + 8] = sbl1;
        if (kt + 1 < 8) {                 // early-issue prefetch
            const int kn = kt + 1;
            const u16 *pah, *pal;
            if (kn < 4) {
                pah = xh + (size_t)(row0 + arow) * DIM + kn * 64 + acs;
                pal = xl + (size_t)(row0 + arow) * DIM + kn * 64 + acs;
            } else {
                pah = gh + (size_t)(row0 + arow) * DIM + (kn - 4) * 64 + acs;
                pal = gl + (size_t)(row0 + arow) * DIM + (kn - 4) * 64 + acs;
            }
            sah = *((const uint4*)pah);
            sal = *((const uint4*)pal);
            const u16* pbh = bth + (size_t)(col0 + brow) * 512 + kn * 64 + bc;
            const u16* pbl = btl + (size_t)(col0 + brow) * 512 + kn * 64 + bc;
            sbh0 = ((const uint4*)pbh)[0]; sbh1 = ((const uint4*)pbh)[1];
            sbl0 = ((const uint4*)pbl)[0]; sbl1 = ((const uint4*)pbl)[1];
        }
        __syncthreads();

        __builtin_amdgcn_s_setprio(1);
        #pragma unroll
        for (int kc = 0; kc < 2; ++kc) {
            const int dc = kc * 32 + h4 * 8;
            half8 afh, afl, bfh[2], bfl[2];
            afh = *(const half8*)&As_h[(rh * 16 + l15) * TKP + dc];
            afl = *(const half8*)&As_l[(rh * 16 + l15) * TKP + dc];
            #pragma unroll
            for (int bb = 0; bb < 2; ++bb) {
                const int r = ch * 32 + bb * 16 + l15;
                bfh[bb] = *(const half8*)&Bs_h[r * TKP + dc];
                bfl[bb] = *(const half8*)&Bs_l[r * TKP + dc];
            }
            #pragma unroll
            for (int bb = 0; bb < 2; ++bb) {
                acc[bb] = MFMA16(afh, bfh[bb], acc[bb]);
                acc[bb] = MFMA16(afh, bfl[bb], acc[bb]);
                acc[bb] = MFMA16(afl, bfh[bb], acc[bb]);
            }
        }
        __builtin_amdgcn_s_setprio(0);
        __syncthreads();
    }

    #pragma unroll
    for (int bb = 0; bb < 2; ++bb) {
        const int c  = col0 + ch * 32 + bb * 16 + l15;
        const int r0 = row0 + rh * 16 + h4 * 4;
        #pragma unroll
        for (int i = 0; i < 4; ++i) {
            const int r = r0 + i;
            float t = acc[bb][i] + bias[c];
            if (EPI == EPI_BNELU) {
                t = gamma[c] * (t - bnmean[c]) * rsqrtf(bnvar[c] + 1e-5f) + beta[c];
                t = t > 0.f ? t : expm1f(t);
            }
            outf[(size_t)r * DIM + c] = t;
            u16 hh, ll;
            split16(t, hh, ll);
            oh[(size_t)r * DIM + c] = hh;
            ol[(size_t)r * DIM + c] = ll;
        }
    }
    #undef TKP
}

// ---------------- QKV MFMA GEMM (fp16 3-pass, early prefetch) -------------
__global__ __launch_bounds__(256) void qkv_mfma(
    const u16* __restrict__ xh, const u16* __restrict__ xl,
    const u16* __restrict__ wth, const u16* __restrict__ wtl,
    const float* __restrict__ bias,
    u16* __restrict__ qh_o, u16* __restrict__ ql_o,
    u16* __restrict__ kh_o, u16* __restrict__ kl_o,
    u16* __restrict__ vt_o)
{
    __shared__ u16 lds[4 * 4608];
    u16* As_h = lds;
    u16* As_l = lds + 4608;
    u16* Bs_h = lds + 9216;
    u16* Bs_l = lds + 13824;
    #define TKP 72

    const int tid  = threadIdx.x;
    const int row0 = blockIdx.y * 64;
    const int mat  = blockIdx.x >> 2;
    const int col0 = (blockIdx.x & 3) * 64;
    const float* biasp = bias + mat * DIM;

    const int w   = tid >> 6;
    const int l15 = tid & 15, h4 = (tid & 63) >> 4;
    const int rh  = w & 1, ch = w >> 1;
    const int lrow = tid & 63, lseg = tid >> 6;
    const int lc = lseg * 16;

    const size_t brow = (size_t)(mat * 256 + col0 + lrow) * 256;
    uint4 sah0, sah1, sal0, sal1, sbh0, sbh1, sbl0, sbl1;
    {
        const u16* pah = xh + (size_t)(row0 + lrow) * DIM + lc;
        const u16* pal = xl + (size_t)(row0 + lrow) * DIM + lc;
        sah0 = ((const uint4*)pah)[0]; sah1 = ((const uint4*)pah)[1];
        sal0 = ((const uint4*)pal)[0]; sal1 = ((const uint4*)pal)[1];
        sbh0 = ((const uint4*)(wth + brow + lc))[0]; sbh1 = ((const uint4*)(wth + brow + lc))[1];
        sbl0 = ((const uint4*)(wtl + brow + lc))[0]; sbl1 = ((const uint4*)(wtl + brow + lc))[1];
    }

    const f32x4 z4 = {0.f, 0.f, 0.f, 0.f};
    f32x4 acc[2][2] = {{z4, z4}, {z4, z4}};

    for (int kt = 0; kt < 4; ++kt) {
        *(uint4*)&As_h[lrow * TKP + lc]     = sah0;
        *(uint4*)&As_h[lrow * TKP + lc + 8] = sah1;
        *(uint4*)&As_l[lrow * TKP + lc]     = sal0;
        *(uint4*)&As_l[lrow * TKP + lc + 8] = sal1;
        *(uint4*)&Bs_h[lrow * TKP + lc]     = sbh0;
        *(uint4*)&Bs_h[lrow * TKP + lc + 8] = sbh1;
        *(uint4*)&Bs_l[lrow * TKP + lc]     = sbl0;
        *(uint4*)&Bs_l[lrow * TKP + lc + 8] = sbl1;
        if (kt + 1 < 4) {
            const int kb = (kt + 1) * 64 + lc;
            const u16* pah = xh + (size_t)(row0 + lrow) * DIM + kb;
            const u16* pal = xl + (size_t)(row0 + lrow) * DIM + kb;
            sah0 = ((const uint4*)pah)[0]; sah1 = ((const uint4*)pah)[1];
            sal0 = ((const uint4*)pal)[0]; sal1 = ((const uint4*)pal)[1];
            sbh0 = ((const uint4*)(wth + brow + kb))[0]; sbh1 = ((const uint4*)(wth + brow + kb))[1];
            sbl0 = ((const uint4*)(wtl + brow + kb))[0]; sbl1 = ((const uint4*)(wtl + brow + kb))[1];
        }
        __syncthreads();

        __builtin_amdgcn_s_setprio(1);
        #pragma unroll
        for (int kc = 0; kc < 2; ++kc) {
            const int dc = kc * 32 + h4 * 8;
            half8 afh[2], afl[2], bfh[2], bfl[2];
            #pragma unroll
            for (int ab = 0; ab < 2; ++ab) {
                const int r = rh * 32 + ab * 16 + l15;
                afh[ab] = *(const half8*)&As_h[r * TKP + dc];
                afl[ab] = *(const half8*)&As_l[r * TKP + dc];
            }
            #pragma unroll
            for (int bb = 0; bb < 2; ++bb) {
                const int r = ch * 32 + bb * 16 + l15;
                bfh[bb] = *(const half8*)&Bs_h[r * TKP + dc];
                bfl[bb] = *(const half8*)&Bs_l[r * TKP + dc];
            }
            #pragma unroll
            for (int ab = 0; ab < 2; ++ab)
                #pragma unroll
                for (int bb = 0; bb < 2; ++bb) {
                    acc[ab][bb] = MFMA16(afh[ab], bfh[bb], acc[ab][bb]);
                    acc[ab][bb] = MFMA16(afh[ab], bfl[bb], acc[ab][bb]);
                    acc[ab][bb] = MFMA16(afl[ab], bfh[bb], acc[ab][bb]);
                }
        }
        __builtin_amdgcn_s_setprio(0);
        __syncthreads();
    }

    const float s = (mat == 0) ? 0.125f : 1.0f;
    u16* oph = (mat == 0) ? qh_o : kh_o;
    u16* opl = (mat == 0) ? ql_o : kl_o;
    #pragma unroll
    for (int ab = 0; ab < 2; ++ab)
        #pragma unroll
        for (int bb = 0; bb < 2; ++bb) {
            const int c  = col0 + ch * 32 + bb * 16 + l15;
            const int r0 = row0 + rh * 32 + ab * 16 + h4 * 4;
            if (mat < 2) {
                #pragma unroll
                for (int i = 0; i < 4; ++i) {
                    const int r = r0 + i;
                    const float t = (acc[ab][bb][i] + biasp[c]) * s;
                    u16 hh, ll;
                    split16(t, hh, ll);
                    oph[(size_t)r * DIM + c] = hh;
                    opl[(size_t)r * DIM + c] = ll;
                }
            } else {
                u16 v[4];
                #pragma unroll
                for (int i = 0; i < 4; ++i)
                    v[i] = f2h(acc[ab][bb][i] + biasp[c]);
                *(uint2*)&vt_o[(size_t)c * NN + r0] =
                    make_uint2((u32)v[0] | ((u32)v[1] << 16), (u32)v[2] | ((u32)v[3] << 16));
            }
        }
    #undef TKP
}

// ---------------- MFMA fp16 GEMM, 32x64 tile (Wo / fc1) -------------------
template<int MEPI>
__global__ __launch_bounds__(256) void mfma_gemm32(
    const u16* __restrict__ Ah, const u16* __restrict__ Al,
    const u16* __restrict__ Bth, const u16* __restrict__ Btl,
    const float* __restrict__ bias, const float* __restrict__ resid,
    float* __restrict__ outf, u16* __restrict__ outh, u16* __restrict__ outl,
    int K, int M)
{
    __shared__ u16 lds[13824];           // 27648 B
    u16* As_h = lds;                     // [32][72]
    u16* As_l = lds + 2304;
    u16* Bs_h = lds + 4608;              // [64][72]
    u16* Bs_l = lds + 9216;
    #define TKP 72

    const int tid  = threadIdx.x;
    const int row0 = blockIdx.y * 32;
    const int col0 = blockIdx.x * 64;

    const int w   = tid >> 6;
    const int l15 = tid & 15, h4 = (tid & 63) >> 4;
    const int rh  = w & 1, ch = w >> 1;
    const int arow = tid >> 3, acs = (tid & 7) * 8;
    const int brow = tid & 63, bseg = tid >> 6;
    const int bc = bseg * 16;

    uint4 sah, sal, sbh0, sbh1, sbl0, sbl1;
    {
        sah = *((const uint4*)&Ah[(size_t)(row0 + arow) * K + acs]);
        sal = *((const uint4*)&Al[(size_t)(row0 + arow) * K + acs]);
        const u16* pbh = Bth + (size_t)(col0 + brow) * K + bc;
        const u16* pbl = Btl + (size_t)(col0 + brow) * K + bc;
        sbh0 = ((const uint4*)pbh)[0]; sbh1 = ((const uint4*)pbh)[1];
        sbl0 = ((const uint4*)pbl)[0]; sbl1 = ((const uint4*)pbl)[1];
    }

    const f32x4 z4 = {0.f, 0.f, 0.f, 0.f};
    f32x4 acc[2] = {z4, z4};
    const int NKT2 = K / 64;

    for (int kt = 0; kt < NKT2; ++kt) {
        *(uint4*)&As_h[arow * TKP + acs] = sah;
        *(uint4*)&As_l[arow * TKP + acs] = sal;
        *(uint4*)&Bs_h[brow * TKP + bc]     = sbh0;
        *(uint4*)&Bs_h[brow * TKP + bc + 8] = sbh1;
        *(uint4*)&Bs_l[brow * TKP + bc]     = sbl0;
        *(uint4*)&Bs_l[brow * TKP + bc + 8] = sbl1;
        if (kt + 1 < NKT2) {              // early-issue prefetch
            const int kb = (kt + 1) * 64;
            sah = *((const uint4*)&Ah[(size_t)(row0 + arow) * K + kb + acs]);
            sal = *((const uint4*)&Al[(size_t)(row0 + arow) * K + kb + acs]);
            const u16* pbh = Bth + (size_t)(col0 + brow) * K + kb + bc;
            const u16* pbl = Btl + (size_t)(col0 + brow) * K + kb + bc;
            sbh0 = ((const uint4*)pbh)[0]; sbh1 = ((const uint4*)pbh)[1];
            sbl0 = ((const uint4*)pbl)[0]; sbl1 = ((const uint4*)pbl)[1];
        }
        __syncthreads();

        __builtin_amdgcn_s_setprio(1);
        #pragma unroll
        for (int kc = 0; kc < 2; ++kc) {
            const int dc = kc * 32 + h4 * 8;
            half8 afh, afl, bfh[2], bfl[2];
            afh = *(const half8*)&As_h[(rh * 16 + l15) * TKP + dc];
            afl = *(const half8*)&As_l[(rh * 16 + l15) * TKP + dc];
            #pragma unroll
            for (int bb = 0; bb < 2; ++bb) {
                const int r = ch * 32 + bb * 16 + l15;
                bfh[bb] = *(const half8*)&Bs_h[r * TKP + dc];
                bfl[bb] = *(const half8*)&Bs_l[r * TKP + dc];
            }
            #pragma unroll
            for (int bb = 0; bb < 2; ++bb) {
                acc[bb] = MFMA16(afh, bfh[bb], acc[bb]);
                acc[bb] = MFMA16(afh, bfl[bb], acc[bb]);
                acc[bb] = MFMA16(afl, bfh[bb], acc[bb]);
            }
        }
        __builtin_amdgcn_s_setprio(0);
        __syncthreads();
    }

    #pragma unroll
    for (int bb = 0; bb < 2; ++bb) {
        const int c  = col0 + ch * 32 + bb * 16 + l15;
        const int r0 = row0 + rh * 16 + h4 * 4;
        #pragma unroll
        for (int i = 0; i < 4; ++i) {
            const int r = r0 + i;
            float t = acc[bb][i] + bias[c];
            if (MEPI == MEPI_WO) {
                t += resid[(size_t)r * M + c];
                u16 hh, ll;
                split16(t, hh, ll);
                outh[(size_t)r * M + c] = hh;
                outl[(size_t)r * M + c] = ll;
            } else {    // FC1: bias + ELU -> fp32 feats
                t = t > 0.f ? t : expm1f(t);
                outf[(size_t)r * M + c] = t;
            }
        }
    }
    #undef TKP
}

// ---------------- MFMA flash attention (round-18) -------------------------
// Round-17 swapped-QK^T structure + XOR-swizzled [64][64] K/Kl/V tiles
// (LDS 49152 B -> 3 blocks/CU) + NSPLIT=6 (grid 768 = 3/CU) + normalized
// fp16 o-partials (6 splits fit in dead workspace buffers).
#define QB 128
#define KB 64
#define NSPLIT 6
#define NKT (NN / KB)

__global__ __launch_bounds__(512, 2) void attn_kernel(
    const u16* __restrict__ qhi, const u16* __restrict__ qlo,
    const u16* __restrict__ khi, const u16* __restrict__ klo,
    const u16* __restrict__ vT,
    u16* __restrict__ op0, u16* __restrict__ op1, u16* __restrict__ op2,
    u16* __restrict__ op3, u16* __restrict__ op4, u16* __restrict__ op5,
    float* __restrict__ mpart, float* __restrict__ lpart)
{
    __shared__ u16 lds[24576];            // 49152 B -> 3 blocks/CU
    u16* Kh0 = lds;                       // [64][64] swizzled, 4096 u16 each
    u16* Kl0 = lds + 4096;
    u16* Vt0 = lds + 8192;
    u16* Kh1 = lds + 12288;
    u16* Kl1 = lds + 16384;
    u16* Vt1 = lds + 20480;
    u16* Qh  = lds;                       // overlay (init): [128][64] swizzled
    u16* Ql  = lds + 8192;                // overlay (init)

    const int tid = threadIdx.x;
    const int h   = blockIdx.y;
    const int q0  = blockIdx.x * QB;
    const int sp  = blockIdx.z;
    const int kt0 = (sp * NKT) / NSPLIT;
    const int kt1 = ((sp + 1) * NKT) / NSPLIT;

    const int w   = tid >> 6;             // wave 0..7 -> q rows w*16..+15
    const int l15 = tid & 15, h4 = (tid & 63) >> 4;
    const int lrow = tid & 63, lseg = tid >> 6;   // staging: 8 segs x 8 u16
    const int gq8 = h * DH + lseg * 8;

    {   // stage Q (once, into overlay region): 128 rows x 64 d, swizzled
        const int qrow = tid >> 2, qseg = tid & 3;
        const u16* s0 = qhi + (size_t)(q0 + qrow) * DIM + h * DH + qseg * 16;
        const u16* s1 = qlo + (size_t)(q0 + qrow) * DIM + h * DH + qseg * 16;
        uint4 a = ((const uint4*)s0)[0], b = ((const uint4*)s0)[1];
        uint4 c = ((const uint4*)s1)[0], d = ((const uint4*)s1)[1];
        *(uint4*)&Qh[swz64(qrow, qseg * 32)]      = a;
        *(uint4*)&Qh[swz64(qrow, qseg * 32 + 16)] = b;
        *(uint4*)&Ql[swz64(qrow, qseg * 32)]      = c;
        *(uint4*)&Ql[swz64(qrow, qseg * 32 + 16)] = d;
    }

    uint4 rk, rl, rv;                     // staging registers
    auto load_tile = [&](int kt_ld) {
        const int key0 = kt_ld * KB;
        rk = *(const uint4*)(khi + (size_t)(key0 + lrow) * DIM + gq8);
        rl = *(const uint4*)(klo + (size_t)(key0 + lrow) * DIM + gq8);
        rv = *(const uint4*)(vT + (size_t)(h * DH + lrow) * NN + key0 + lseg * 8);
    };
    load_tile(kt0);
    __syncthreads();                              // Q staged

    half8 qf[2][2];                               // [kc][hi/lo]
    #pragma unroll
    for (int kc = 0; kc < 2; ++kc) {
        const int r = w * 16 + l15;
        const int cb = kc * 64 + h4 * 16;         // byte col
        qf[kc][0] = *(const half8*)&Qh[swz64(r, cb)];
        qf[kc][1] = *(const half8*)&Ql[swz64(r, cb)];
    }
    __syncthreads();                              // hoist done; overlay safe

    auto stage_to = [&](u16* Kh, u16* Kl, u16* Vt) {
        const int idx = swz64(lrow, lseg * 16);
        *(uint4*)&Kh[idx] = rk;
        *(uint4*)&Kl[idx] = rl;
        *(uint4*)&Vt[idx] = rv;
    };

    stage_to(Kh0, Kl0, Vt0);                      // tile kt0 -> buf0
    load_tile(kt0 + 1);                           // tile kt0+1 -> regs
    __syncthreads();                              // buf0 ready

    const f32x4 z4 = {0.f, 0.f, 0.f, 0.f};
    f32x4 oacc[4] = {z4, z4, z4, z4};             // d-blocks 0..3 for own q
    float m_run = -3.0e38f, l_run = 0.f;          // lane-local: q = w*16+l15
    const int sl0 = (h4 & 1) * 32 + l15;          // P-shuffle source lanes
    const int sl1 = sl0 + 16;

    auto tile_body = [&](int t, u16* Kc, u16* Lc, u16* Vc,
                         u16* Kn, u16* Ln, u16* Vn) {
        if (t + 1 < kt1) stage_to(Kn, Ln, Vn);    // writes to the idle buffer
        if (t + 2 < kt1) load_tile(t + 2);        // early-issue global loads

        // ---- S^T = K Q^T (swapped operands): lane holds S[q][16 k-vals]
        f32x4 sc[4] = {z4, z4, z4, z4};
        __builtin_amdgcn_s_setprio(1);
        #pragma unroll
        for (int kc = 0; kc < 2; ++kc) {
            const int cb = kc * 64 + h4 * 16;     // byte col
            half8 kfh[4], kfl[4];
            #pragma unroll
            for (int kcb = 0; kcb < 4; ++kcb) {
                const int r = kcb * 16 + l15;
                const int idx = swz64(r, cb);
                kfh[kcb] = *(const half8*)&Kc[idx];
                kfl[kcb] = *(const half8*)&Lc[idx];
            }
            #pragma unroll
            for (int kcb = 0; kcb < 4; ++kcb) {
                sc[kcb] = MFMA16(kfh[kcb], qf[kc][0], sc[kcb]);
                sc[kcb] = MFMA16(kfl[kcb], qf[kc][0], sc[kcb]);
                sc[kcb] = MFMA16(kfh[kcb], qf[kc][1], sc[kcb]);
            }
        }
        __builtin_amdgcn_s_setprio(0);

        // ---- lane-local softmax: tree max over 16, 2-shfl all-reduce ----
        float c0 = fmaxf(fmaxf(sc[0][0], sc[0][1]), fmaxf(sc[0][2], sc[0][3]));
        float c1 = fmaxf(fmaxf(sc[1][0], sc[1][1]), fmaxf(sc[1][2], sc[1][3]));
        float c2 = fmaxf(fmaxf(sc[2][0], sc[2][1]), fmaxf(sc[2][2], sc[2][3]));
        float c3 = fmaxf(fmaxf(sc[3][0], sc[3][1]), fmaxf(sc[3][2], sc[3][3]));
        float pm = fmaxf(fmaxf(c0, c1), fmaxf(c2, c3));
        pm = fmaxf(pm, __shfl_xor(pm, 16));
        pm = fmaxf(pm, __shfl_xor(pm, 32));

        float p[4][4];
        float base, fr = 1.f;
        int resc;
        if (__all(pm - m_run <= 8.f)) {           // defer-max (THR=8)
            base = m_run;
            resc = 0;
        } else {
            const float mnew = fmaxf(m_run, pm);
            fr = __expf(m_run - mnew);
            m_run = mnew;
            base = mnew;
            resc = 1;
        }
        #pragma unroll
        for (int kcb = 0; kcb < 4; ++kcb)
            #pragma unroll
            for (int i = 0; i < 4; ++i)
                p[kcb][i] = __expf(sc[kcb][i] - base);
        float s0s = (p[0][0] + p[0][1]) + (p[0][2] + p[0][3]);
        float s1s = (p[1][0] + p[1][1]) + (p[1][2] + p[1][3]);
        float s2s = (p[2][0] + p[2][1]) + (p[2][2] + p[2][3]);
        float s3s = (p[3][0] + p[3][1]) + (p[3][2] + p[3][3]);
        float ls = (s0s + s1s) + (s2s + s3s);
        ls += __shfl_xor(ls, 16);
        ls += __shfl_xor(ls, 32);
        if (resc) {
            l_run = l_run * fr + ls;
            #pragma unroll
            for (int db = 0; db < 4; ++db) oacc[db] *= fr;
        } else {
            l_run += ls;
        }

        // ---- pack P to fp16 pairs (per kcb: [i0|i1], [i2|i3]) ----
        u32 pk01[4], pk23[4];
        #pragma unroll
        for (int kcb = 0; kcb < 4; ++kcb) {
            pk01[kcb] = (u32)f2h(p[kcb][0]) | ((u32)f2h(p[kcb][1]) << 16);
            pk23[kcb] = (u32)f2h(p[kcb][2]) | ((u32)f2h(p[kcb][3]) << 16);
        }

        // ---- PV: B-fragment built by shuffles among lanes sharing l15 ----
        const int hiSel = h4 >> 1;
        __builtin_amdgcn_s_setprio(1);
        #pragma unroll
        for (int kc = 0; kc < 2; ++kc) {
            const u32 a0 = (u32)__shfl((int)pk01[kc * 2], sl0);
            const u32 a1 = (u32)__shfl((int)pk23[kc * 2], sl0);
            const u32 a2 = (u32)__shfl((int)pk01[kc * 2], sl1);
            const u32 a3 = (u32)__shfl((int)pk23[kc * 2], sl1);
            const u32 b0 = (u32)__shfl((int)pk01[kc * 2 + 1], sl0);
            const u32 b1 = (u32)__shfl((int)pk23[kc * 2 + 1], sl0);
            const u32 b2 = (u32)__shfl((int)pk01[kc * 2 + 1], sl1);
            const u32 b3 = (u32)__shfl((int)pk23[kc * 2 + 1], sl1);
            union { half8 v; u32 u[4]; } pf;
            pf.u[0] = hiSel ? b0 : a0;
            pf.u[1] = hiSel ? b1 : a1;
            pf.u[2] = hiSel ? b2 : a2;
            pf.u[3] = hiSel ? b3 : a3;
            const int cb = kc * 64 + h4 * 16;     // byte col
            #pragma unroll
            for (int db = 0; db < 4; ++db) {
                const half8 vf = *(const half8*)&Vc[swz64(db * 16 + l15, cb)];
                oacc[db] = MFMA16(vf, pf.v, oacc[db]);
            }
        }
        __builtin_amdgcn_s_setprio(0);
        __syncthreads();   // single per-tile barrier: buf^1 staged + reads done
    };

    {   // pointer-swap loop (handles odd tile counts: 10 or 11 per split)
        u16 *Kc = Kh0, *Lc = Kl0, *Vc = Vt0;
        u16 *Kn = Kh1, *Ln = Kl1, *Vn = Vt1;
        for (int t = kt0; t < kt1; ++t) {
            tile_body(t, Kc, Lc, Vc, Kn, Ln, Vn);
            u16* tmp;
            tmp = Kc; Kc = Kn; Kn = tmp;
            tmp = Lc; Lc = Ln; Ln = tmp;
            tmp = Vc; Vc = Vn; Vn = tmp;
        }
    }

    // epilogue: NORMALIZED fp16 partial (o/l_run, values ~ |V| <= few hundred)
    u16* ob = (sp == 0) ? op0 : ((sp == 1) ? op1 : ((sp == 2) ? op2 :
              ((sp == 3) ? op3 : ((sp == 4) ? op4 : op5))));
    const float inv = 1.f / l_run;
    #pragma unroll
    for (int db = 0; db < 4; ++db) {
        u32 w0 = (u32)f2h(oacc[db][0] * inv) | ((u32)f2h(oacc[db][1] * inv) << 16);
        u32 w1 = (u32)f2h(oacc[db][2] * inv) | ((u32)f2h(oacc[db][3] * inv) << 16);
        *(uint2*)&ob[(size_t)(q0 + w * 16 + l15) * DIM + h * DH + db * 16 + h4 * 4] =
            make_uint2(w0, w1);
    }
    if (h4 == 0) {
        const int r = w * 16 + l15;
        mpart[((size_t)sp * NN + q0 + r) * NH + h] = m_run;
        lpart[((size_t)sp * NN + q0 + r) * NH + h] = l_run;
    }
}

// merge 6 normalized fp16 partials -> fp16 hi/lo planes (feeds Wo GEMM)
__global__ __launch_bounds__(256) void attn_combine(
    const u16* __restrict__ o0, const u16* __restrict__ o1,
    const u16* __restrict__ o2, const u16* __restrict__ o3,
    const u16* __restrict__ o4, const u16* __restrict__ o5,
    const float* __restrict__ mp, const float* __restrict__ lp,
    u16* __restrict__ ohi, u16* __restrict__ olo)
{
    const int gid = blockIdx.x * 256 + threadIdx.x;
    const int row = gid >> 6;
    const int c4  = (gid & 63) * 4;
    const int h   = c4 >> 6;
    float m[6], wgt[6];
    #pragma unroll
    for (int z = 0; z < 6; ++z) m[z] = mp[((size_t)z * NN + row) * NH + h];
    float M = m[0];
    #pragma unroll
    for (int z = 1; z < 6; ++z) M = fmaxf(M, m[z]);
    float den = 0.f;
    #pragma unroll
    for (int z = 0; z < 6; ++z) {
        wgt[z] = lp[((size_t)z * NN + row) * NH + h] * __expf(m[z] - M);
        den += wgt[z];
    }
    const float inv = 1.f / den;
    const u16* ps[6] = {o0, o1, o2, o3, o4, o5};
    float r[4] = {0.f, 0.f, 0.f, 0.f};
    #pragma unroll
    for (int z = 0; z < 6; ++z) {
        const uint2 v = *(const uint2*)&ps[z][(size_t)row * DIM + c4];
        r[0] += wgt[z] * h2f((u16)(v.x & 0xffff));
        r[1] += wgt[z] * h2f((u16)(v.x >> 16));
        r[2] += wgt[z] * h2f((u16)(v.y & 0xffff));
        r[3] += wgt[z] * h2f((u16)(v.y >> 16));
    }
    u16 hh[4], ll[4];
    #pragma unroll
    for (int j = 0; j < 4; ++j) split16(r[j] * inv, hh[j], ll[j]);
    *(uint2*)&ohi[(size_t)row * DIM + c4] =
        make_uint2((u32)hh[0] | ((u32)hh[1] << 16), (u32)hh[2] | ((u32)hh[3] << 16));
    *(uint2*)&olo[(size_t)row * DIM + c4] =
        make_uint2((u32)ll[0] | ((u32)ll[1] << 16), (u32)ll[2] | ((u32)ll[3] << 16));
}

// ---------------- per-node group adapter: 4 nodes per 256-thr block -------
__global__ __launch_bounds__(256) void adapter_kernel(
    const float* __restrict__ feats, const int* __restrict__ grp,
    const float* __restrict__ AW1, const float* __restrict__ Ab1,
    const float* __restrict__ AW2, const float* __restrict__ Ab2,
    float* __restrict__ out)
{
    const int wv = threadIdx.x >> 6;
    const int n = blockIdx.x * 4 + wv;
    const int lane = threadIdx.x & 63;
    __shared__ float f[4][F1D];
    f[wv][lane]      = feats[(size_t)n * F1D + lane];
    f[wv][lane + 64] = feats[(size_t)n * F1D + 64 + lane];
    // wave-local LDS: compiler waitcnt orders reads (no barrier needed)
    const int g = grp[n];
    const float* W1 = AW1 + (size_t)g * F1D * AD;
    const int a = lane & 31;
    const int half = lane >> 5;
    float hsum = 0.f;
    for (int d = 0; d < 64; ++d)
        hsum = fmaf(f[wv][half * 64 + d], W1[(half * 64 + d) * AD + a], hsum);
    hsum += __shfl_xor(hsum, 32);
    hsum = fmaxf(hsum + Ab1[g * AD + a], 0.f);
    float p = hsum * AW2[g * AD + a];
    #pragma unroll
    for (int mm = 1; mm < 32; mm <<= 1) p += __shfl_xor(p, mm);
    if (lane == 0) out[n] = p + Ab2[g];
}

// ---------------- host-side orchestration ----------------
extern "C" void kernel_launch(void* const* d_in, const int* in_sizes, int n_in,
                              void* d_out, int out_size, void* d_ws, size_t ws_size,
                              hipStream_t stream)
{
    const float* x_in   = (const float*)d_in[0];
    const float* eattr  = (const float*)d_in[1];
    const float* Wself  = (const float*)d_in[2];
    const float* Wnbr   = (const float*)d_in[3];
    const float* convb  = (const float*)d_in[4];
    const float* gamma  = (const float*)d_in[5];
    const float* beta   = (const float*)d_in[6];
    const float* bnmean = (const float*)d_in[7];
    const float* bnvar  = (const float*)d_in[8];
    const float* Wqkv   = (const float*)d_in[9];
    const float* bqkv   = (const float*)d_in[10];
    const float* Wo     = (const float*)d_in[11];
    const float* bo     = (const float*)d_in[12];
    const float* fc1W   = (const float*)d_in[13];
    const float* fc1b   = (const float*)d_in[14];
    const float* AW1    = (const float*)d_in[15];
    const float* Ab1    = (const float*)d_in[16];
    const float* AW2    = (const float*)d_in[17];
    const float* Ab2    = (const float*)d_in[18];
    const int*   eidx   = (const int*)d_in[19];
    const int*   grp    = (const int*)d_in[20];
    const int* srcArr = eidx;
    const int* dstArr = eidx + NE;

    float* fws = (float*)d_ws;
    const size_t NM = (size_t)NN * DIM;
    float* bufA  = fws;                  // x L0 / x L2 (residual)
    float* bufB  = fws + NM;             // attn op0 (fp16) scratch
    float* bufC  = fws + 2 * NM;         // x L1 / attn op1 scratch
    float* feats = fws + 3 * NM;         // NN x F1D (attn op5 scratch first)
    float* mpart = fws + 3 * NM + NM / 2;         // [6][NN][NH]
    float* lpart = mpart + 6 * NN * NH;
    u16* up = (u16*)(lpart + 6 * NN * NH);
    u16* xpAh = up;             u16* xpAl = xpAh + NM;   // x planes ping
    u16* xpBh = xpAl + NM;      u16* xpBl = xpBh + NM;   // x planes pong
    u16* aggh = xpBl + NM;      u16* aggl = aggh + NM;   // agg planes
    u16* qh = aggl + NM;        u16* ql = qh + NM;       // Q planes / combine out
    u16* kh = ql + NM;          u16* kl = kh + NM;       // K planes / Wo out
    u16* vt = kl + NM;                                   // V^T fp16 [256][NN]
    u16* wcath = vt + NM;                                // [3][256][512]
    u16* wcatl = wcath + 3 * 131072;
    u16* wt4h  = wcatl + 3 * 131072;                     // [4][256][256] qkv+wo
    u16* wt4l  = wt4h + 4 * 65536;
    u16* fc1h  = wt4l + 4 * 65536;                       // [128][256]
    u16* fc1l  = fc1h + 32768;
    int*   esrc = (int*)(fc1l + 32768);                  // NE
    float* ewt  = (float*)(esrc + NE);                   // NE
    int* off    = (int*)(ewt + NE);                      // NN+1
    int* cur    = off + NN + 1;                          // NN
    float* outp = (float*)d_out;

    // 6 normalized-fp16 attn partials in buffers dead during attention:
    u16* o0 = (u16*)bufB;
    u16* o1 = (u16*)bufC;
    u16* o2 = xpAh;                      // xpA region (dead after qkv)
    u16* o3 = xpBh;                      // xpB region (dead after qkv)
    u16* o4 = aggh;                      // agg region (dead after conv2)
    u16* o5 = (u16*)feats;               // feats written later by fc1

    // fused prep: all converts + zero(cur)
    prep_kernel<<<1700, 256, 0, stream>>>(
        x_in, Wself, Wnbr, Wqkv, Wo, fc1W,
        xpAh, xpAl, wcath, wcatl, wt4h, wt4l, fc1h, fc1l, cur);

    // CSR build (csr_scan zeroes cur for csr_fill)
    csr_count<<<NE / 256, 256, 0, stream>>>(dstArr, cur);
    csr_scan<<<1, 1024, 0, stream>>>(cur, off);
    csr_fill<<<NE / 256, 256, 0, stream>>>(dstArr, srcArr, eattr, off, cur, esrc, ewt);

    const dim3 gc(DIM / 64, NN / 32);    // 32-row conv tiles: 512 blocks
    const int rgrid = NN * DIM / 4 / 256;

    // conv layer 0: x_in -> bufA (fp32) + xpB planes
    agg_kernel<false><<<NN / 4, 256, 0, stream>>>(x_in, esrc, ewt, off, aggh, aggl);
    conv_mfma<EPI_BNELU><<<gc, 256, 0, stream>>>(
        xpAh, xpAl, aggh, aggl, wcath, wcatl, convb,
        gamma, beta, bnmean, bnvar, bufA, xpBh, xpBl);
    // conv layer 1: bufA -> bufC + xpA planes
    agg_kernel<false><<<NN / 4, 256, 0, stream>>>(bufA, esrc, ewt, off, aggh, aggl);
    conv_mfma<EPI_BNELU><<<gc, 256, 0, stream>>>(
        xpBh, xpBl, aggh, aggl, wcath + 131072, wcatl + 131072, convb + DIM,
        gamma + DIM, beta + DIM, bnmean + DIM, bnvar + DIM, bufC, xpAh, xpAl);
    // conv layer 2 (edge-weighted, bias only): bufC -> bufA + xpB planes
    agg_kernel<true><<<NN / 4, 256, 0, stream>>>(bufC, esrc, ewt, off, aggh, aggl);
    conv_mfma<EPI_BIAS><<<gc, 256, 0, stream>>>(
        xpAh, xpAl, aggh, aggl, wcath + 262144, wcatl + 262144, convb + 2 * DIM,
        nullptr, nullptr, nullptr, nullptr, bufA, xpBh, xpBl);

    // QKV (fp16 3-pass MFMA) -> Q/K planes (Q/8) + V^T
    qkv_mfma<<<dim3(12, NN / 64), 256, 0, stream>>>(
        xpBh, xpBl, wt4h, wt4l, bqkv, qh, ql, kh, kl, vt);

    // flash attention (8-wave QB=128, swizzled dbuf, 6-way key split)
    attn_kernel<<<dim3(NN / QB, NH, NSPLIT), 512, 0, stream>>>(
        qh, ql, kh, kl, vt, o0, o1, o2, o3, o4, o5, mpart, lpart);
    attn_combine<<<rgrid, 256, 0, stream>>>(
        o0, o1, o2, o3, o4, o5, mpart, lpart, qh, ql);

    // Wo + residual (fp16 3-pass MFMA, 32x64 tiles): kh/kl = planes(...)
    mfma_gemm32<MEPI_WO><<<dim3(DIM / 64, NN / 32), 256, 0, stream>>>(
        qh, ql, wt4h + 3 * 65536, wt4l + 3 * 65536, bo, bufA,
        nullptr, kh, kl, DIM, DIM);

    // fc1 + ELU (fp16 3-pass MFMA, 32x64 tiles): feats = elu(x' @ fc1W + fc1b)
    mfma_gemm32<MEPI_FC1><<<dim3(F1D / 64, NN / 32), 256, 0, stream>>>(
        kh, kl, fc1h, fc1l, fc1b, nullptr, feats, nullptr, nullptr, DIM, F1D);

    // adapter routing -> out
    adapter_kernel<<<NN / 4, 256, 0, stream>>>(feats, grp, AW1, Ab1, AW2, Ab2, outp);
}

// Round 19
// 206.476 us; speedup vs baseline: 1.2028x; 1.0243x over previous
//
#include <hip/hip_runtime.h>
#include <math.h>

#define NN   4096
#define DIM  256
#define NE   131072
#define NH   4
#define DH   64
#define F1D  128
#define NG   16
#define AD   32

typedef unsigned short u16;
typedef unsigned int   u32;
typedef _Float16 f16;
typedef __attribute__((ext_vector_type(8))) _Float16 half8;
typedef __attribute__((ext_vector_type(4))) float f32x4;

#define MFMA16(a, b, c) __builtin_amdgcn_mfma_f32_16x16x32_f16(a, b, c, 0, 0, 0)

__device__ inline u16 f2h(float x) { union { f16 f; u16 u; } c; c.f = (f16)x; return c.u; }
__device__ inline float h2f(u16 h) { union { f16 f; u16 u; } c; c.u = h; return (float)c.f; }
// fp16 hi/lo split: x = hi + lo + eps, |eps| <= 2^-24 |x|  (fp32-grade)
__device__ inline void split16(float x, u16& h, u16& l) {
    union { f16 f; u16 u; } ch, cl;
    ch.f = (f16)x;
    cl.f = (f16)(x - (float)ch.f);
    h = ch.u; l = cl.u;
}
// XOR-swizzled index into a [64|128][64]-u16 LDS tile (128 B rows).
__device__ inline int swz64(int row, int colByte) {
    return row * 64 + ((colByte ^ ((row & 7) << 4)) >> 1);
}

// ---------------- CSR build ----------------
__global__ void csr_count(const int* __restrict__ dst, int* __restrict__ cnt) {
    int e = blockIdx.x * 256 + threadIdx.x;
    atomicAdd(&cnt[dst[e]], 1);
}

__global__ __launch_bounds__(1024) void csr_scan(
    int* __restrict__ cnt, int* __restrict__ off)
{
    __shared__ int wsum[16];
    const int t = threadIdx.x;
    const int lane = t & 63;
    int4 v = *(const int4*)&cnt[t * 4];
    const int s = v.x + v.y + v.z + v.w;
    int acc = s;
    #pragma unroll
    for (int o = 1; o < 64; o <<= 1) {
        int u = __shfl_up(acc, o);
        if (lane >= o) acc += u;
    }
    if (lane == 63) wsum[t >> 6] = acc;
    __syncthreads();
    if (t < 16) {
        int w0 = wsum[t];
        int a2 = w0;
        #pragma unroll
        for (int o = 1; o < 16; o <<= 1) {
            int u = __shfl_up(a2, o);
            if (t >= o) a2 += u;
        }
        wsum[t] = a2 - w0;
    }
    __syncthreads();
    const int base = wsum[t >> 6] + (acc - s);
    off[t * 4 + 0] = base;
    off[t * 4 + 1] = base + v.x;
    off[t * 4 + 2] = base + v.x + v.y;
    off[t * 4 + 3] = base + v.x + v.y + v.z;
    *(int4*)&cnt[t * 4] = make_int4(0, 0, 0, 0);
    if (t == 1023) off[NN] = base + s;
}

__global__ void csr_fill(const int* __restrict__ dst, const int* __restrict__ src,
                         const float* __restrict__ eattr, const int* __restrict__ off,
                         int* __restrict__ cur, int* __restrict__ esrc,
                         float* __restrict__ ewt) {
    int e = blockIdx.x * 256 + threadIdx.x;
    int d = dst[e];
    int pos = off[d] + atomicAdd(&cur[d], 1);
    esrc[pos] = src[e];
    ewt[pos]  = eattr[e];
}

// ---------------- fused one-time prep: all weight/x converts + zero cur ----
__global__ __launch_bounds__(256) void prep_kernel(
    const float* __restrict__ x,
    const float* __restrict__ Ws, const float* __restrict__ Wn,
    const float* __restrict__ Wqkv, const float* __restrict__ Wo,
    const float* __restrict__ fc1W,
    u16* __restrict__ xh, u16* __restrict__ xl,
    u16* __restrict__ wch, u16* __restrict__ wcl,
    u16* __restrict__ w4h, u16* __restrict__ w4l,
    u16* __restrict__ f1h, u16* __restrict__ f1l,
    int* __restrict__ cur)
{
    const int b = blockIdx.x;
    const int t = threadIdx.x;
    if (b < 1024) {
        const int gid = b * 256 + t;
        const float4 v = *(const float4*)&x[(size_t)gid * 4];
        u16 h[4], l[4];
        split16(v.x, h[0], l[0]); split16(v.y, h[1], l[1]);
        split16(v.z, h[2], l[2]); split16(v.w, h[3], l[3]);
        *(uint2*)&xh[(size_t)gid * 4] =
            make_uint2((u32)h[0] | ((u32)h[1] << 16), (u32)h[2] | ((u32)h[3] << 16));
        *(uint2*)&xl[(size_t)gid * 4] =
            make_uint2((u32)l[0] | ((u32)l[1] << 16), (u32)l[2] | ((u32)l[3] << 16));
    } else if (b < 1408) {
        const int gid = (b - 1024) * 256 + t;
        const int L = gid / 32768;
        const int rem = gid % 32768;
        const int m = rem / 128;
        const int k4 = (rem % 128) * 4;
        const float* S = Ws + (size_t)L * 65536;
        const float* Nb = Wn + (size_t)L * 65536;
        u16 h[4], l[4];
        #pragma unroll
        for (int j = 0; j < 4; ++j) {
            const int k = k4 + j;
            const float v = (k < 256) ? S[(size_t)k * 256 + m]
                                      : Nb[(size_t)(k - 256) * 256 + m];
            split16(v, h[j], l[j]);
        }
        const size_t o = (size_t)L * 131072 + (size_t)m * 512 + k4;
        *(uint2*)&wch[o] = make_uint2((u32)h[0] | ((u32)h[1] << 16), (u32)h[2] | ((u32)h[3] << 16));
        *(uint2*)&wcl[o] = make_uint2((u32)l[0] | ((u32)l[1] << 16), (u32)l[2] | ((u32)l[3] << 16));
    } else if (b < 1664) {
        const int gid = (b - 1408) * 256 + t;
        const int mat = gid / 16384;
        const int rem = gid % 16384;
        const int m = rem / 64;
        const int k4 = (rem % 64) * 4;
        const float* W = (mat < 3) ? Wqkv + (size_t)mat * 65536 : Wo;
        u16 h[4], l[4];
        #pragma unroll
        for (int j = 0; j < 4; ++j)
            split16(W[(size_t)(k4 + j) * 256 + m], h[j], l[j]);
        const size_t o = (size_t)mat * 65536 + (size_t)m * 256 + k4;
        *(uint2*)&w4h[o] = make_uint2((u32)h[0] | ((u32)h[1] << 16), (u32)h[2] | ((u32)h[3] << 16));
        *(uint2*)&w4l[o] = make_uint2((u32)l[0] | ((u32)l[1] << 16), (u32)l[2] | ((u32)l[3] << 16));
    } else if (b < 1696) {
        const int gid = (b - 1664) * 256 + t;
        const int m = gid / 64;
        const int k4 = (gid % 64) * 4;
        u16 h[4], l[4];
        #pragma unroll
        for (int j = 0; j < 4; ++j)
            split16(fc1W[(size_t)(k4 + j) * F1D + m], h[j], l[j]);
        const size_t o = (size_t)m * 256 + k4;
        *(uint2*)&f1h[o] = make_uint2((u32)h[0] | ((u32)h[1] << 16), (u32)h[2] | ((u32)h[3] << 16));
        *(uint2*)&f1l[o] = make_uint2((u32)l[0] | ((u32)l[1] << 16), (u32)l[2] | ((u32)l[3] << 16));
    } else {
        const int gid = (b - 1696) * 256 + t;
        if (gid < NN / 4) *(int4*)&cur[gid * 4] = make_int4(0, 0, 0, 0);
    }
}

// ---------------- neighbor aggregation: 1 wave per node, fp16-plane out ---
template<bool LAST>
__global__ __launch_bounds__(256) void agg_kernel(
    const float* __restrict__ x, const int* __restrict__ esrc,
    const float* __restrict__ ewt, const int* __restrict__ off,
    u16* __restrict__ aggh, u16* __restrict__ aggl)
{
    const int node = blockIdx.x * 4 + (threadIdx.x >> 6);
    const int lane = threadIdx.x & 63;
    const int d4 = lane * 4;
    int j = off[node];
    const int j1 = off[node + 1];
    float4 acc = make_float4(0.f, 0.f, 0.f, 0.f);
    for (; j + 4 <= j1; j += 4) {
        const int s0 = esrc[j], s1 = esrc[j + 1], s2 = esrc[j + 2], s3 = esrc[j + 3];
        const float4 x0 = *(const float4*)&x[(size_t)s0 * DIM + d4];
        const float4 x1 = *(const float4*)&x[(size_t)s1 * DIM + d4];
        const float4 x2 = *(const float4*)&x[(size_t)s2 * DIM + d4];
        const float4 x3 = *(const float4*)&x[(size_t)s3 * DIM + d4];
        const float w0 = LAST ? ewt[j]     : 1.f;
        const float w1 = LAST ? ewt[j + 1] : 1.f;
        const float w2 = LAST ? ewt[j + 2] : 1.f;
        const float w3 = LAST ? ewt[j + 3] : 1.f;
        acc.x = fmaf(x0.x, w0, acc.x); acc.y = fmaf(x0.y, w0, acc.y);
        acc.z = fmaf(x0.z, w0, acc.z); acc.w = fmaf(x0.w, w0, acc.w);
        acc.x = fmaf(x1.x, w1, acc.x); acc.y = fmaf(x1.y, w1, acc.y);
        acc.z = fmaf(x1.z, w1, acc.z); acc.w = fmaf(x1.w, w1, acc.w);
        acc.x = fmaf(x2.x, w2, acc.x); acc.y = fmaf(x2.y, w2, acc.y);
        acc.z = fmaf(x2.z, w2, acc.z); acc.w = fmaf(x2.w, w2, acc.w);
        acc.x = fmaf(x3.x, w3, acc.x); acc.y = fmaf(x3.y, w3, acc.y);
        acc.z = fmaf(x3.z, w3, acc.z); acc.w = fmaf(x3.w, w3, acc.w);
    }
    for (; j < j1; ++j) {
        const int s = esrc[j];
        const float w = LAST ? ewt[j] : 1.f;
        const float4 xv = *(const float4*)&x[(size_t)s * DIM + d4];
        acc.x = fmaf(xv.x, w, acc.x); acc.y = fmaf(xv.y, w, acc.y);
        acc.z = fmaf(xv.z, w, acc.z); acc.w = fmaf(xv.w, w, acc.w);
    }
    u16 h[4], l[4];
    split16(acc.x, h[0], l[0]); split16(acc.y, h[1], l[1]);
    split16(acc.z, h[2], l[2]); split16(acc.w, h[3], l[3]);
    *(uint2*)&aggh[(size_t)node * DIM + d4] =
        make_uint2((u32)h[0] | ((u32)h[1] << 16), (u32)h[2] | ((u32)h[3] << 16));
    *(uint2*)&aggl[(size_t)node * DIM + d4] =
        make_uint2((u32)l[0] | ((u32)l[1] << 16), (u32)l[2] | ((u32)l[3] << 16));
}

// ---------------- conv MFMA GEMM: 32x64 tile (2 blocks/CU) ----------------
template<int EPI>   // 0 = bias only, 1 = bias+BN+ELU
__global__ __launch_bounds__(256) void conv_mfma(
    const u16* __restrict__ xh, const u16* __restrict__ xl,
    const u16* __restrict__ gh, const u16* __restrict__ gl,
    const u16* __restrict__ bth, const u16* __restrict__ btl,
    const float* __restrict__ bias,
    const float* __restrict__ gamma, const float* __restrict__ beta,
    const float* __restrict__ bnmean, const float* __restrict__ bnvar,
    float* __restrict__ outf, u16* __restrict__ oh, u16* __restrict__ ol)
{
    __shared__ u16 lds[13824];           // 27648 B
    u16* As_h = lds;                     // [32][72]
    u16* As_l = lds + 2304;
    u16* Bs_h = lds + 4608;              // [64][72]
    u16* Bs_l = lds + 9216;
    #define TKP 72

    const int tid  = threadIdx.x;
    const int row0 = blockIdx.y * 32;
    const int col0 = blockIdx.x * 64;

    const int w   = tid >> 6;
    const int l15 = tid & 15, h4 = (tid & 63) >> 4;
    const int rh  = w & 1, ch = w >> 1;
    const int arow = tid >> 3, acs = (tid & 7) * 8;
    const int brow = tid & 63, bseg = tid >> 6;
    const int bc = bseg * 16;

    uint4 sah, sal, sbh0, sbh1, sbl0, sbl1;
    {
        sah = *((const uint4*)&xh[(size_t)(row0 + arow) * DIM + acs]);
        sal = *((const uint4*)&xl[(size_t)(row0 + arow) * DIM + acs]);
        const u16* pbh = bth + (size_t)(col0 + brow) * 512 + bc;
        const u16* pbl = btl + (size_t)(col0 + brow) * 512 + bc;
        sbh0 = ((const uint4*)pbh)[0]; sbh1 = ((const uint4*)pbh)[1];
        sbl0 = ((const uint4*)pbl)[0]; sbl1 = ((const uint4*)pbl)[1];
    }

    const f32x4 z4 = {0.f, 0.f, 0.f, 0.f};
    f32x4 acc[2] = {z4, z4};

    for (int kt = 0; kt < 8; ++kt) {
        *(uint4*)&As_h[arow * TKP + acs] = sah;
        *(uint4*)&As_l[arow * TKP + acs] = sal;
        *(uint4*)&Bs_h[brow * TKP + bc]     = sbh0;
        *(uint4*)&Bs_h[brow * TKP + bc + 8] = sbh1;
        *(uint4*)&Bs_l[brow * TKP + bc]     = sbl0;
        *(uint4*)&Bs_l[brow * TKP + bc + 8] = sbl1;
        if (kt + 1 < 8) {                 // early-issue prefetch
            const int kn = kt + 1;
            const u16 *pah, *pal;
            if (kn < 4) {
                pah = xh + (size_t)(row0 + arow) * DIM + kn * 64 + acs;
                pal = xl + (size_t)(row0 + arow) * DIM + kn * 64 + acs;
            } else {
                pah = gh + (size_t)(row0 + arow) * DIM + (kn - 4) * 64 + acs;
                pal = gl + (size_t)(row0 + arow) * DIM + (kn - 4) * 64 + acs;
            }
            sah = *((const uint4*)pah);
            sal = *((const uint4*)pal);
            const u16* pbh = bth + (size_t)(col0 + brow) * 512 + kn * 64 + bc;
            const u16* pbl = btl + (size_t)(col0 + brow) * 512 + kn * 64 + bc;
            sbh0 = ((const uint4*)pbh)[0]; sbh1 = ((const uint4*)pbh)[1];
            sbl0 = ((const uint4*)pbl)[0]; sbl1 = ((const uint4*)pbl)[1];
        }
        __syncthreads();

        __builtin_amdgcn_s_setprio(1);
        #pragma unroll
        for (int kc = 0; kc < 2; ++kc) {
            const int dc = kc * 32 + h4 * 8;
            half8 afh, afl, bfh[2], bfl[2];
            afh = *(const half8*)&As_h[(rh * 16 + l15) * TKP + dc];
            afl = *(const half8*)&As_l[(rh * 16 + l15) * TKP + dc];
            #pragma unroll
            for (int bb = 0; bb < 2; ++bb) {
                const int r = ch * 32 + bb * 16 + l15;
                bfh[bb] = *(const half8*)&Bs_h[r * TKP + dc];
                bfl[bb] = *(const half8*)&Bs_l[r * TKP + dc];
            }
            #pragma unroll
            for (int bb = 0; bb < 2; ++bb) {
                acc[bb] = MFMA16(afh, bfh[bb], acc[bb]);
                acc[bb] = MFMA16(afh, bfl[bb], acc[bb]);
                acc[bb] = MFMA16(afl, bfh[bb], acc[bb]);
            }
        }
        __builtin_amdgcn_s_setprio(0);
        __syncthreads();
    }

    #pragma unroll
    for (int bb = 0; bb < 2; ++bb) {
        const int c  = col0 + ch * 32 + bb * 16 + l15;
        const int r0 = row0 + rh * 16 + h4 * 4;
        #pragma unroll
        for (int i = 0; i < 4; ++i) {
            const int r = r0 + i;
            float t = acc[bb][i] + bias[c];
            if (EPI == 1) {
                t = gamma[c] * (t - bnmean[c]) * rsqrtf(bnvar[c] + 1e-5f) + beta[c];
                t = t > 0.f ? t : expm1f(t);
            }
            outf[(size_t)r * DIM + c] = t;
            u16 hh, ll;
            split16(t, hh, ll);
            oh[(size_t)r * DIM + c] = hh;
            ol[(size_t)r * DIM + c] = ll;
        }
    }
    #undef TKP
}

// ---------------- QKV MFMA GEMM (fp16 3-pass, early prefetch) -------------
__global__ __launch_bounds__(256) void qkv_mfma(
    const u16* __restrict__ xh, const u16* __restrict__ xl,
    const u16* __restrict__ wth, const u16* __restrict__ wtl,
    const float* __restrict__ bias,
    u16* __restrict__ qh_o, u16* __restrict__ ql_o,
    u16* __restrict__ kh_o, u16* __restrict__ kl_o,
    u16* __restrict__ vt_o)
{
    __shared__ u16 lds[4 * 4608];
    u16* As_h = lds;
    u16* As_l = lds + 4608;
    u16* Bs_h = lds + 9216;
    u16* Bs_l = lds + 13824;
    #define TKP 72

    const int tid  = threadIdx.x;
    const int row0 = blockIdx.y * 64;
    const int mat  = blockIdx.x >> 2;
    const int col0 = (blockIdx.x & 3) * 64;
    const float* biasp = bias + mat * DIM;

    const int w   = tid >> 6;
    const int l15 = tid & 15, h4 = (tid & 63) >> 4;
    const int rh  = w & 1, ch = w >> 1;
    const int lrow = tid & 63, lseg = tid >> 6;
    const int lc = lseg * 16;

    const size_t brow = (size_t)(mat * 256 + col0 + lrow) * 256;
    uint4 sah0, sah1, sal0, sal1, sbh0, sbh1, sbl0, sbl1;
    {
        const u16* pah = xh + (size_t)(row0 + lrow) * DIM + lc;
        const u16* pal = xl + (size_t)(row0 + lrow) * DIM + lc;
        sah0 = ((const uint4*)pah)[0]; sah1 = ((const uint4*)pah)[1];
        sal0 = ((const uint4*)pal)[0]; sal1 = ((const uint4*)pal)[1];
        sbh0 = ((const uint4*)(wth + brow + lc))[0]; sbh1 = ((const uint4*)(wth + brow + lc))[1];
        sbl0 = ((const uint4*)(wtl + brow + lc))[0]; sbl1 = ((const uint4*)(wtl + brow + lc))[1];
    }

    const f32x4 z4 = {0.f, 0.f, 0.f, 0.f};
    f32x4 acc[2][2] = {{z4, z4}, {z4, z4}};

    for (int kt = 0; kt < 4; ++kt) {
        *(uint4*)&As_h[lrow * TKP + lc]     = sah0;
        *(uint4*)&As_h[lrow * TKP + lc + 8] = sah1;
        *(uint4*)&As_l[lrow * TKP + lc]     = sal0;
        *(uint4*)&As_l[lrow * TKP + lc + 8] = sal1;
        *(uint4*)&Bs_h[lrow * TKP + lc]     = sbh0;
        *(uint4*)&Bs_h[lrow * TKP + lc + 8] = sbh1;
        *(uint4*)&Bs_l[lrow * TKP + lc]     = sbl0;
        *(uint4*)&Bs_l[lrow * TKP + lc + 8] = sbl1;
        if (kt + 1 < 4) {
            const int kb = (kt + 1) * 64 + lc;
            const u16* pah = xh + (size_t)(row0 + lrow) * DIM + kb;
            const u16* pal = xl + (size_t)(row0 + lrow) * DIM + kb;
            sah0 = ((const uint4*)pah)[0]; sah1 = ((const uint4*)pah)[1];
            sal0 = ((const uint4*)pal)[0]; sal1 = ((const uint4*)pal)[1];
            sbh0 = ((const uint4*)(wth + brow + kb))[0]; sbh1 = ((const uint4*)(wth + brow + kb))[1];
            sbl0 = ((const uint4*)(wtl + brow + kb))[0]; sbl1 = ((const uint4*)(wtl + brow + kb))[1];
        }
        __syncthreads();

        __builtin_amdgcn_s_setprio(1);
        #pragma unroll
        for (int kc = 0; kc < 2; ++kc) {
            const int dc = kc * 32 + h4 * 8;
            half8 afh[2], afl[2], bfh[2], bfl[2];
            #pragma unroll
            for (int ab = 0; ab < 2; ++ab) {
                const int r = rh * 32 + ab * 16 + l15;
                afh[ab] = *(const half8*)&As_h[r * TKP + dc];
                afl[ab] = *(const half8*)&As_l[r * TKP + dc];
            }
            #pragma unroll
            for (int bb = 0; bb < 2; ++bb) {
                const int r = ch * 32 + bb * 16 + l15;
                bfh[bb] = *(const half8*)&Bs_h[r * TKP + dc];
                bfl[bb] = *(const half8*)&Bs_l[r * TKP + dc];
            }
            #pragma unroll
            for (int ab = 0; ab < 2; ++ab)
                #pragma unroll
                for (int bb = 0; bb < 2; ++bb) {
                    acc[ab][bb] = MFMA16(afh[ab], bfh[bb], acc[ab][bb]);
                    acc[ab][bb] = MFMA16(afh[ab], bfl[bb], acc[ab][bb]);
                    acc[ab][bb] = MFMA16(afl[ab], bfh[bb], acc[ab][bb]);
                }
        }
        __builtin_amdgcn_s_setprio(0);
        __syncthreads();
    }

    const float s = (mat == 0) ? 0.125f : 1.0f;
    u16* oph = (mat == 0) ? qh_o : kh_o;
    u16* opl = (mat == 0) ? ql_o : kl_o;
    #pragma unroll
    for (int ab = 0; ab < 2; ++ab)
        #pragma unroll
        for (int bb = 0; bb < 2; ++bb) {
            const int c  = col0 + ch * 32 + bb * 16 + l15;
            const int r0 = row0 + rh * 32 + ab * 16 + h4 * 4;
            if (mat < 2) {
                #pragma unroll
                for (int i = 0; i < 4; ++i) {
                    const int r = r0 + i;
                    const float t = (acc[ab][bb][i] + biasp[c]) * s;
                    u16 hh, ll;
                    split16(t, hh, ll);
                    oph[(size_t)r * DIM + c] = hh;
                    opl[(size_t)r * DIM + c] = ll;
                }
            } else {
                u16 v[4];
                #pragma unroll
                for (int i = 0; i < 4; ++i)
                    v[i] = f2h(acc[ab][bb][i] + biasp[c]);
                *(uint2*)&vt_o[(size_t)c * NN + r0] =
                    make_uint2((u32)v[0] | ((u32)v[1] << 16), (u32)v[2] | ((u32)v[3] << 16));
            }
        }
    #undef TKP
}

// ---------------- Wo GEMM with FUSED 4-partial combine (round-19) ---------
// A[r][d] = (sum_z l_z*exp(m_z-M) * part_z[r][d]) / den  merged during the
// A-stage (head = kt since K=256). Epilogue: + resid + bias -> hi/lo planes.
__global__ __launch_bounds__(256) void wo_fused(
    const u16* __restrict__ p0, const u16* __restrict__ p1,
    const u16* __restrict__ p2, const u16* __restrict__ p3,
    const float* __restrict__ mp, const float* __restrict__ lp,
    const u16* __restrict__ Bth, const u16* __restrict__ Btl,
    const float* __restrict__ bias, const float* __restrict__ resid,
    u16* __restrict__ outh, u16* __restrict__ outl)
{
    __shared__ u16 lds[13824];           // 27648 B
    u16* As_h = lds;                     // [32][72]
    u16* As_l = lds + 2304;
    u16* Bs_h = lds + 4608;              // [64][72]
    u16* Bs_l = lds + 9216;
    #define TKP 72
    const int K = DIM, M = DIM;

    const int tid  = threadIdx.x;
    const int row0 = blockIdx.y * 32;
    const int col0 = blockIdx.x * 64;

    const int w   = tid >> 6;
    const int l15 = tid & 15, h4 = (tid & 63) >> 4;
    const int rh  = w & 1, ch = w >> 1;
    const int arow = tid >> 3, acs = (tid & 7) * 8;
    const int brow = tid & 63, bseg = tid >> 6;
    const int bc = bseg * 16;
    const int r = row0 + arow;           // A row this thread stages

    uint4 pa0, pa1, pa2, pa3, sbh0, sbh1, sbl0, sbl1;
    {
        const size_t ao = (size_t)r * DIM + acs;       // kt=0 segment
        pa0 = *(const uint4*)&p0[ao];
        pa1 = *(const uint4*)&p1[ao];
        pa2 = *(const uint4*)&p2[ao];
        pa3 = *(const uint4*)&p3[ao];
        const u16* pbh = Bth + (size_t)(col0 + brow) * K + bc;
        const u16* pbl = Btl + (size_t)(col0 + brow) * K + bc;
        sbh0 = ((const uint4*)pbh)[0]; sbh1 = ((const uint4*)pbh)[1];
        sbl0 = ((const uint4*)pbl)[0]; sbl1 = ((const uint4*)pbl)[1];
    }

    const f32x4 z4 = {0.f, 0.f, 0.f, 0.f};
    f32x4 acc[2] = {z4, z4};

    for (int kt = 0; kt < 4; ++kt) {
        {   // merge 4 partials for head = kt (same math/order as old combine)
            const int hd = kt;
            const float m0 = mp[((size_t)0 * NN + r) * NH + hd];
            const float m1 = mp[((size_t)1 * NN + r) * NH + hd];
            const float m2 = mp[((size_t)2 * NN + r) * NH + hd];
            const float m3 = mp[((size_t)3 * NN + r) * NH + hd];
            const float M2 = fmaxf(fmaxf(m0, m1), fmaxf(m2, m3));
            const float w0 = lp[((size_t)0 * NN + r) * NH + hd] * __expf(m0 - M2);
            const float w1 = lp[((size_t)1 * NN + r) * NH + hd] * __expf(m1 - M2);
            const float w2 = lp[((size_t)2 * NN + r) * NH + hd] * __expf(m2 - M2);
            const float w3 = lp[((size_t)3 * NN + r) * NH + hd] * __expf(m3 - M2);
            const float inv = 1.f / (((w0 + w1) + (w2 + w3)));
            union { uint4 v; u16 u[8]; } a0, a1, a2, a3, oh_, ol_;
            a0.v = pa0; a1.v = pa1; a2.v = pa2; a3.v = pa3;
            #pragma unroll
            for (int j = 0; j < 8; ++j) {
                const float mv = (w0 * h2f(a0.u[j]) + w1 * h2f(a1.u[j]) +
                                  w2 * h2f(a2.u[j]) + w3 * h2f(a3.u[j])) * inv;
                split16(mv, oh_.u[j], ol_.u[j]);
            }
            *(uint4*)&As_h[arow * TKP + acs] = oh_.v;
            *(uint4*)&As_l[arow * TKP + acs] = ol_.v;
        }
        *(uint4*)&Bs_h[brow * TKP + bc]     = sbh0;
        *(uint4*)&Bs_h[brow * TKP + bc + 8] = sbh1;
        *(uint4*)&Bs_l[brow * TKP + bc]     = sbl0;
        *(uint4*)&Bs_l[brow * TKP + bc + 8] = sbl1;
        if (kt + 1 < 4) {                 // early-issue prefetch
            const size_t ao = (size_t)r * DIM + (kt + 1) * 64 + acs;
            pa0 = *(const uint4*)&p0[ao];
            pa1 = *(const uint4*)&p1[ao];
            pa2 = *(const uint4*)&p2[ao];
            pa3 = *(const uint4*)&p3[ao];
            const int kb = (kt + 1) * 64;
            const u16* pbh = Bth + (size_t)(col0 + brow) * K + kb + bc;
            const u16* pbl = Btl + (size_t)(col0 + brow) * K + kb + bc;
            sbh0 = ((const uint4*)pbh)[0]; sbh1 = ((const uint4*)pbh)[1];
            sbl0 = ((const uint4*)pbl)[0]; sbl1 = ((const uint4*)pbl)[1];
        }
        __syncthreads();

        __builtin_amdgcn_s_setprio(1);
        #pragma unroll
        for (int kc = 0; kc < 2; ++kc) {
            const int dc = kc * 32 + h4 * 8;
            half8 afh, afl, bfh[2], bfl[2];
            afh = *(const half8*)&As_h[(rh * 16 + l15) * TKP + dc];
            afl = *(const half8*)&As_l[(rh * 16 + l15) * TKP + dc];
            #pragma unroll
            for (int bb = 0; bb < 2; ++bb) {
                const int rr = ch * 32 + bb * 16 + l15;
                bfh[bb] = *(const half8*)&Bs_h[rr * TKP + dc];
                bfl[bb] = *(const half8*)&Bs_l[rr * TKP + dc];
            }
            #pragma unroll
            for (int bb = 0; bb < 2; ++bb) {
                acc[bb] = MFMA16(afh, bfh[bb], acc[bb]);
                acc[bb] = MFMA16(afh, bfl[bb], acc[bb]);
                acc[bb] = MFMA16(afl, bfh[bb], acc[bb]);
            }
        }
        __builtin_amdgcn_s_setprio(0);
        __syncthreads();
    }

    #pragma unroll
    for (int bb = 0; bb < 2; ++bb) {
        const int c  = col0 + ch * 32 + bb * 16 + l15;
        const int r0 = row0 + rh * 16 + h4 * 4;
        #pragma unroll
        for (int i = 0; i < 4; ++i) {
            const int rr = r0 + i;
            float t = acc[bb][i] + bias[c] + resid[(size_t)rr * M + c];
            u16 hh, ll;
            split16(t, hh, ll);
            outh[(size_t)rr * M + c] = hh;
            outl[(size_t)rr * M + c] = ll;
        }
    }
    #undef TKP
}

// ---------------- fc1 MFMA GEMM, 32x64 tile -------------------------------
__global__ __launch_bounds__(256) void fc1_mfma(
    const u16* __restrict__ Ah, const u16* __restrict__ Al,
    const u16* __restrict__ Bth, const u16* __restrict__ Btl,
    const float* __restrict__ bias, float* __restrict__ outf)
{
    __shared__ u16 lds[13824];
    u16* As_h = lds;
    u16* As_l = lds + 2304;
    u16* Bs_h = lds + 4608;
    u16* Bs_l = lds + 9216;
    #define TKP 72
    const int K = DIM, M = F1D;

    const int tid  = threadIdx.x;
    const int row0 = blockIdx.y * 32;
    const int col0 = blockIdx.x * 64;

    const int w   = tid >> 6;
    const int l15 = tid & 15, h4 = (tid & 63) >> 4;
    const int rh  = w & 1, ch = w >> 1;
    const int arow = tid >> 3, acs = (tid & 7) * 8;
    const int brow = tid & 63, bseg = tid >> 6;
    const int bc = bseg * 16;

    uint4 sah, sal, sbh0, sbh1, sbl0, sbl1;
    {
        sah = *((const uint4*)&Ah[(size_t)(row0 + arow) * K + acs]);
        sal = *((const uint4*)&Al[(size_t)(row0 + arow) * K + acs]);
        const u16* pbh = Bth + (size_t)(col0 + brow) * K + bc;
        const u16* pbl = Btl + (size_t)(col0 + brow) * K + bc;
        sbh0 = ((const uint4*)pbh)[0]; sbh1 = ((const uint4*)pbh)[1];
        sbl0 = ((const uint4*)pbl)[0]; sbl1 = ((const uint4*)pbl)[1];
    }

    const f32x4 z4 = {0.f, 0.f, 0.f, 0.f};
    f32x4 acc[2] = {z4, z4};

    for (int kt = 0; kt < 4; ++kt) {
        *(uint4*)&As_h[arow * TKP + acs] = sah;
        *(uint4*)&As_l[arow * TKP + acs] = sal;
        *(uint4*)&Bs_h[brow * TKP + bc]     = sbh0;
        *(uint4*)&Bs_h[brow * TKP + bc + 8] = sbh1;
        *(uint4*)&Bs_l[brow * TKP + bc]     = sbl0;
        *(uint4*)&Bs_l[brow * TKP + bc + 8] = sbl1;
        if (kt + 1 < 4) {
            const int kb = (kt + 1) * 64;
            sah = *((const uint4*)&Ah[(size_t)(row0 + arow) * K + kb + acs]);
            sal = *((const uint4*)&Al[(size_t)(row0 + arow) * K + kb + acs]);
            const u16* pbh = Bth + (size_t)(col0 + brow) * K + kb + bc;
            const u16* pbl = Btl + (size_t)(col0 + brow) * K + kb + bc;
            sbh0 = ((const uint4*)pbh)[0]; sbh1 = ((const uint4*)pbh)[1];
            sbl0 = ((const uint4*)pbl)[0]; sbl1 = ((const uint4*)pbl)[1];
        }
        __syncthreads();

        __builtin_amdgcn_s_setprio(1);
        #pragma unroll
        for (int kc = 0; kc < 2; ++kc) {
            const int dc = kc * 32 + h4 * 8;
            half8 afh, afl, bfh[2], bfl[2];
            afh = *(const half8*)&As_h[(rh * 16 + l15) * TKP + dc];
            afl = *(const half8*)&As_l[(rh * 16 + l15) * TKP + dc];
            #pragma unroll
            for (int bb = 0; bb < 2; ++bb) {
                const int rr = ch * 32 + bb * 16 + l15;
                bfh[bb] = *(const half8*)&Bs_h[rr * TKP + dc];
                bfl[bb] = *(const half8*)&Bs_l[rr * TKP + dc];
            }
            #pragma unroll
            for (int bb = 0; bb < 2; ++bb) {
                acc[bb] = MFMA16(afh, bfh[bb], acc[bb]);
                acc[bb] = MFMA16(afh, bfl[bb], acc[bb]);
                acc[bb] = MFMA16(afl, bfh[bb], acc[bb]);
            }
        }
        __builtin_amdgcn_s_setprio(0);
        __syncthreads();
    }

    #pragma unroll
    for (int bb = 0; bb < 2; ++bb) {
        const int c  = col0 + ch * 32 + bb * 16 + l15;
        const int r0 = row0 + rh * 16 + h4 * 4;
        #pragma unroll
        for (int i = 0; i < 4; ++i) {
            const int rr = r0 + i;
            float t = acc[bb][i] + bias[c];
            t = t > 0.f ? t : expm1f(t);
            outf[(size_t)rr * M + c] = t;
        }
    }
    #undef TKP
}

// ---------------- MFMA flash attention (round-19: NSPLIT=4 + swizzle) -----
#define QB 128
#define KB 64
#define NSPLIT 4
#define NKT (NN / KB)

__global__ __launch_bounds__(512, 2) void attn_kernel(
    const u16* __restrict__ qhi, const u16* __restrict__ qlo,
    const u16* __restrict__ khi, const u16* __restrict__ klo,
    const u16* __restrict__ vT,
    u16* __restrict__ op0, u16* __restrict__ op1,
    u16* __restrict__ op2, u16* __restrict__ op3,
    float* __restrict__ mpart, float* __restrict__ lpart)
{
    __shared__ u16 lds[24576];            // 49152 B -> 3 blocks/CU capable
    u16* Kh0 = lds;                       // [64][64] swizzled
    u16* Kl0 = lds + 4096;
    u16* Vt0 = lds + 8192;
    u16* Kh1 = lds + 12288;
    u16* Kl1 = lds + 16384;
    u16* Vt1 = lds + 20480;
    u16* Qh  = lds;                       // overlay (init): [128][64] swizzled
    u16* Ql  = lds + 8192;                // overlay (init)

    const int tid = threadIdx.x;
    const int h   = blockIdx.y;
    const int q0  = blockIdx.x * QB;
    const int sp  = blockIdx.z;
    const int kt0 = (sp * NKT) / NSPLIT;
    const int kt1 = ((sp + 1) * NKT) / NSPLIT;

    const int w   = tid >> 6;             // wave 0..7 -> q rows w*16..+15
    const int l15 = tid & 15, h4 = (tid & 63) >> 4;
    const int lrow = tid & 63, lseg = tid >> 6;   // staging: 8 segs x 8 u16
    const int gq8 = h * DH + lseg * 8;

    {   // stage Q (once, into overlay region): 128 rows x 64 d, swizzled
        const int qrow = tid >> 2, qseg = tid & 3;
        const u16* s0 = qhi + (size_t)(q0 + qrow) * DIM + h * DH + qseg * 16;
        const u16* s1 = qlo + (size_t)(q0 + qrow) * DIM + h * DH + qseg * 16;
        uint4 a = ((const uint4*)s0)[0], b = ((const uint4*)s0)[1];
        uint4 c = ((const uint4*)s1)[0], d = ((const uint4*)s1)[1];
        *(uint4*)&Qh[swz64(qrow, qseg * 32)]      = a;
        *(uint4*)&Qh[swz64(qrow, qseg * 32 + 16)] = b;
        *(uint4*)&Ql[swz64(qrow, qseg * 32)]      = c;
        *(uint4*)&Ql[swz64(qrow, qseg * 32 + 16)] = d;
    }

    uint4 rk, rl, rv;                     // staging registers
    auto load_tile = [&](int kt_ld) {
        const int key0 = kt_ld * KB;
        rk = *(const uint4*)(khi + (size_t)(key0 + lrow) * DIM + gq8);
        rl = *(const uint4*)(klo + (size_t)(key0 + lrow) * DIM + gq8);
        rv = *(const uint4*)(vT + (size_t)(h * DH + lrow) * NN + key0 + lseg * 8);
    };
    load_tile(kt0);
    __syncthreads();                              // Q staged

    half8 qf[2][2];                               // [kc][hi/lo]
    #pragma unroll
    for (int kc = 0; kc < 2; ++kc) {
        const int r = w * 16 + l15;
        const int cb = kc * 64 + h4 * 16;         // byte col
        qf[kc][0] = *(const half8*)&Qh[swz64(r, cb)];
        qf[kc][1] = *(const half8*)&Ql[swz64(r, cb)];
    }
    __syncthreads();                              // hoist done; overlay safe

    auto stage_to = [&](u16* Kh, u16* Kl, u16* Vt) {
        const int idx = swz64(lrow, lseg * 16);
        *(uint4*)&Kh[idx] = rk;
        *(uint4*)&Kl[idx] = rl;
        *(uint4*)&Vt[idx] = rv;
    };

    stage_to(Kh0, Kl0, Vt0);                      // tile kt0 -> buf0
    load_tile(kt0 + 1);                           // tile kt0+1 -> regs
    __syncthreads();                              // buf0 ready

    const f32x4 z4 = {0.f, 0.f, 0.f, 0.f};
    f32x4 oacc[4] = {z4, z4, z4, z4};             // d-blocks 0..3 for own q
    float m_run = -3.0e38f, l_run = 0.f;          // lane-local: q = w*16+l15
    const int sl0 = (h4 & 1) * 32 + l15;          // P-shuffle source lanes
    const int sl1 = sl0 + 16;

    auto tile_body = [&](int t, u16* Kc, u16* Lc, u16* Vc,
                         u16* Kn, u16* Ln, u16* Vn) {
        if (t + 1 < kt1) stage_to(Kn, Ln, Vn);    // writes to the idle buffer
        if (t + 2 < kt1) load_tile(t + 2);        // early-issue global loads

        // ---- S^T = K Q^T (swapped operands): lane holds S[q][16 k-vals]
        f32x4 sc[4] = {z4, z4, z4, z4};
        __builtin_amdgcn_s_setprio(1);
        #pragma unroll
        for (int kc = 0; kc < 2; ++kc) {
            const int cb = kc * 64 + h4 * 16;     // byte col
            half8 kfh[4], kfl[4];
            #pragma unroll
            for (int kcb = 0; kcb < 4; ++kcb) {
                const int r = kcb * 16 + l15;
                const int idx = swz64(r, cb);
                kfh[kcb] = *(const half8*)&Kc[idx];
                kfl[kcb] = *(const half8*)&Lc[idx];
            }
            #pragma unroll
            for (int kcb = 0; kcb < 4; ++kcb) {
                sc[kcb] = MFMA16(kfh[kcb], qf[kc][0], sc[kcb]);
                sc[kcb] = MFMA16(kfl[kcb], qf[kc][0], sc[kcb]);
                sc[kcb] = MFMA16(kfh[kcb], qf[kc][1], sc[kcb]);
            }
        }
        __builtin_amdgcn_s_setprio(0);

        // ---- lane-local softmax: tree max over 16, 2-shfl all-reduce ----
        float c0 = fmaxf(fmaxf(sc[0][0], sc[0][1]), fmaxf(sc[0][2], sc[0][3]));
        float c1 = fmaxf(fmaxf(sc[1][0], sc[1][1]), fmaxf(sc[1][2], sc[1][3]));
        float c2 = fmaxf(fmaxf(sc[2][0], sc[2][1]), fmaxf(sc[2][2], sc[2][3]));
        float c3 = fmaxf(fmaxf(sc[3][0], sc[3][1]), fmaxf(sc[3][2], sc[3][3]));
        float pm = fmaxf(fmaxf(c0, c1), fmaxf(c2, c3));
        pm = fmaxf(pm, __shfl_xor(pm, 16));
        pm = fmaxf(pm, __shfl_xor(pm, 32));

        float p[4][4];
        float base, fr = 1.f;
        int resc;
        if (__all(pm - m_run <= 8.f)) {           // defer-max (THR=8)
            base = m_run;
            resc = 0;
        } else {
            const float mnew = fmaxf(m_run, pm);
            fr = __expf(m_run - mnew);
            m_run = mnew;
            base = mnew;
            resc = 1;
        }
        #pragma unroll
        for (int kcb = 0; kcb < 4; ++kcb)
            #pragma unroll
            for (int i = 0; i < 4; ++i)
                p[kcb][i] = __expf(sc[kcb][i] - base);
        float s0s = (p[0][0] + p[0][1]) + (p[0][2] + p[0][3]);
        float s1s = (p[1][0] + p[1][1]) + (p[1][2] + p[1][3]);
        float s2s = (p[2][0] + p[2][1]) + (p[2][2] + p[2][3]);
        float s3s = (p[3][0] + p[3][1]) + (p[3][2] + p[3][3]);
        float ls = (s0s + s1s) + (s2s + s3s);
        ls += __shfl_xor(ls, 16);
        ls += __shfl_xor(ls, 32);
        if (resc) {
            l_run = l_run * fr + ls;
            #pragma unroll
            for (int db = 0; db < 4; ++db) oacc[db] *= fr;
        } else {
            l_run += ls;
        }

        // ---- pack P to fp16 pairs (per kcb: [i0|i1], [i2|i3]) ----
        u32 pk01[4], pk23[4];
        #pragma unroll
        for (int kcb = 0; kcb < 4; ++kcb) {
            pk01[kcb] = (u32)f2h(p[kcb][0]) | ((u32)f2h(p[kcb][1]) << 16);
            pk23[kcb] = (u32)f2h(p[kcb][2]) | ((u32)f2h(p[kcb][3]) << 16);
        }

        // ---- PV: B-fragment built by shuffles among lanes sharing l15 ----
        const int hiSel = h4 >> 1;
        __builtin_amdgcn_s_setprio(1);
        #pragma unroll
        for (int kc = 0; kc < 2; ++kc) {
            const u32 a0 = (u32)__shfl((int)pk01[kc * 2], sl0);
            const u32 a1 = (u32)__shfl((int)pk23[kc * 2], sl0);
            const u32 a2 = (u32)__shfl((int)pk01[kc * 2], sl1);
            const u32 a3 = (u32)__shfl((int)pk23[kc * 2], sl1);
            const u32 b0 = (u32)__shfl((int)pk01[kc * 2 + 1], sl0);
            const u32 b1 = (u32)__shfl((int)pk23[kc * 2 + 1], sl0);
            const u32 b2 = (u32)__shfl((int)pk01[kc * 2 + 1], sl1);
            const u32 b3 = (u32)__shfl((int)pk23[kc * 2 + 1], sl1);
            union { half8 v; u32 u[4]; } pf;
            pf.u[0] = hiSel ? b0 : a0;
            pf.u[1] = hiSel ? b1 : a1;
            pf.u[2] = hiSel ? b2 : a2;
            pf.u[3] = hiSel ? b3 : a3;
            const int cb = kc * 64 + h4 * 16;     // byte col
            #pragma unroll
            for (int db = 0; db < 4; ++db) {
                const half8 vf = *(const half8*)&Vc[swz64(db * 16 + l15, cb)];
                oacc[db] = MFMA16(vf, pf.v, oacc[db]);
            }
        }
        __builtin_amdgcn_s_setprio(0);
        __syncthreads();   // single per-tile barrier: buf^1 staged + reads done
    };

    {   // pointer-swap loop
        u16 *Kc = Kh0, *Lc = Kl0, *Vc = Vt0;
        u16 *Kn = Kh1, *Ln = Kl1, *Vn = Vt1;
        for (int t = kt0; t < kt1; ++t) {
            tile_body(t, Kc, Lc, Vc, Kn, Ln, Vn);
            u16* tmp;
            tmp = Kc; Kc = Kn; Kn = tmp;
            tmp = Lc; Lc = Ln; Ln = tmp;
            tmp = Vc; Vc = Vn; Vn = tmp;
        }
    }

    // epilogue: NORMALIZED fp16 partial (o/l_run)
    u16* ob = (sp == 0) ? op0 : ((sp == 1) ? op1 : ((sp == 2) ? op2 : op3));
    const float inv = 1.f / l_run;
    #pragma unroll
    for (int db = 0; db < 4; ++db) {
        u32 w0 = (u32)f2h(oacc[db][0] * inv) | ((u32)f2h(oacc[db][1] * inv) << 16);
        u32 w1 = (u32)f2h(oacc[db][2] * inv) | ((u32)f2h(oacc[db][3] * inv) << 16);
        *(uint2*)&ob[(size_t)(q0 + w * 16 + l15) * DIM + h * DH + db * 16 + h4 * 4] =
            make_uint2(w0, w1);
    }
    if (h4 == 0) {
        const int r = w * 16 + l15;
        mpart[((size_t)sp * NN + q0 + r) * NH + h] = m_run;
        lpart[((size_t)sp * NN + q0 + r) * NH + h] = l_run;
    }
}

// ---------------- per-node group adapter: 4 nodes per 256-thr block -------
__global__ __launch_bounds__(256) void adapter_kernel(
    const float* __restrict__ feats, const int* __restrict__ grp,
    const float* __restrict__ AW1, const float* __restrict__ Ab1,
    const float* __restrict__ AW2, const float* __restrict__ Ab2,
    float* __restrict__ out)
{
    const int wv = threadIdx.x >> 6;
    const int n = blockIdx.x * 4 + wv;
    const int lane = threadIdx.x & 63;
    __shared__ float f[4][F1D];
    f[wv][lane]      = feats[(size_t)n * F1D + lane];
    f[wv][lane + 64] = feats[(size_t)n * F1D + 64 + lane];
    // wave-local LDS: compiler waitcnt orders reads (no barrier needed)
    const int g = grp[n];
    const float* W1 = AW1 + (size_t)g * F1D * AD;
    const int a = lane & 31;
    const int half = lane >> 5;
    float hsum = 0.f;
    for (int d = 0; d < 64; ++d)
        hsum = fmaf(f[wv][half * 64 + d], W1[(half * 64 + d) * AD + a], hsum);
    hsum += __shfl_xor(hsum, 32);
    hsum = fmaxf(hsum + Ab1[g * AD + a], 0.f);
    float p = hsum * AW2[g * AD + a];
    #pragma unroll
    for (int mm = 1; mm < 32; mm <<= 1) p += __shfl_xor(p, mm);
    if (lane == 0) out[n] = p + Ab2[g];
}

// ---------------- host-side orchestration ----------------
extern "C" void kernel_launch(void* const* d_in, const int* in_sizes, int n_in,
                              void* d_out, int out_size, void* d_ws, size_t ws_size,
                              hipStream_t stream)
{
    const float* x_in   = (const float*)d_in[0];
    const float* eattr  = (const float*)d_in[1];
    const float* Wself  = (const float*)d_in[2];
    const float* Wnbr   = (const float*)d_in[3];
    const float* convb  = (const float*)d_in[4];
    const float* gamma  = (const float*)d_in[5];
    const float* beta   = (const float*)d_in[6];
    const float* bnmean = (const float*)d_in[7];
    const float* bnvar  = (const float*)d_in[8];
    const float* Wqkv   = (const float*)d_in[9];
    const float* bqkv   = (const float*)d_in[10];
    const float* Wo     = (const float*)d_in[11];
    const float* bo     = (const float*)d_in[12];
    const float* fc1W   = (const float*)d_in[13];
    const float* fc1b   = (const float*)d_in[14];
    const float* AW1    = (const float*)d_in[15];
    const float* Ab1    = (const float*)d_in[16];
    const float* AW2    = (const float*)d_in[17];
    const float* Ab2    = (const float*)d_in[18];
    const int*   eidx   = (const int*)d_in[19];
    const int*   grp    = (const int*)d_in[20];
    const int* srcArr = eidx;
    const int* dstArr = eidx + NE;

    float* fws = (float*)d_ws;
    const size_t NM = (size_t)NN * DIM;
    float* bufA  = fws;                  // x L0 / x L2 (residual)
    float* bufB  = fws + NM;             // attn op0 scratch
    float* bufC  = fws + 2 * NM;         // x L1 / attn op1 scratch
    float* feats = fws + 3 * NM;         // NN x F1D
    float* mpart = fws + 3 * NM + NM / 2;         // [4][NN][NH]
    float* lpart = mpart + 4 * NN * NH;
    u16* up = (u16*)(lpart + 4 * NN * NH);
    u16* xpAh = up;             u16* xpAl = xpAh + NM;   // x planes ping
    u16* xpBh = xpAl + NM;      u16* xpBl = xpBh + NM;   // x planes pong
    u16* aggh = xpBl + NM;      u16* aggl = aggh + NM;   // agg planes
    u16* qh = aggl + NM;        u16* ql = qh + NM;       // Q planes
    u16* kh = ql + NM;          u16* kl = kh + NM;       // K planes / Wo out
    u16* vt = kl + NM;                                   // V^T fp16 [256][NN]
    u16* wcath = vt + NM;                                // [3][256][512]
    u16* wcatl = wcath + 3 * 131072;
    u16* wt4h  = wcatl + 3 * 131072;                     // [4][256][256] qkv+wo
    u16* wt4l  = wt4h + 4 * 65536;
    u16* fc1h  = wt4l + 4 * 65536;                       // [128][256]
    u16* fc1l  = fc1h + 32768;
    int*   esrc = (int*)(fc1l + 32768);                  // NE
    float* ewt  = (float*)(esrc + NE);                   // NE
    int* off    = (int*)(ewt + NE);                      // NN+1
    int* cur    = off + NN + 1;                          // NN
    float* outp = (float*)d_out;

    // 4 normalized-fp16 attn partials in buffers dead during attention:
    u16* o0 = (u16*)bufB;
    u16* o1 = (u16*)bufC;
    u16* o2 = xpAh;                      // xpA region (dead after qkv)
    u16* o3 = xpBh;                      // xpB region (dead after qkv)

    // fused prep: all converts + zero(cur)
    prep_kernel<<<1700, 256, 0, stream>>>(
        x_in, Wself, Wnbr, Wqkv, Wo, fc1W,
        xpAh, xpAl, wcath, wcatl, wt4h, wt4l, fc1h, fc1l, cur);

    // CSR build (csr_scan zeroes cur for csr_fill)
    csr_count<<<NE / 256, 256, 0, stream>>>(dstArr, cur);
    csr_scan<<<1, 1024, 0, stream>>>(cur, off);
    csr_fill<<<NE / 256, 256, 0, stream>>>(dstArr, srcArr, eattr, off, cur, esrc, ewt);

    const dim3 gc(DIM / 64, NN / 32);    // 32-row conv tiles: 512 blocks
    // conv layer 0: x_in -> bufA (fp32) + xpB planes
    agg_kernel<false><<<NN / 4, 256, 0, stream>>>(x_in, esrc, ewt, off, aggh, aggl);
    conv_mfma<1><<<gc, 256, 0, stream>>>(
        xpAh, xpAl, aggh, aggl, wcath, wcatl, convb,
        gamma, beta, bnmean, bnvar, bufA, xpBh, xpBl);
    // conv layer 1: bufA -> bufC + xpA planes
    agg_kernel<false><<<NN / 4, 256, 0, stream>>>(bufA, esrc, ewt, off, aggh, aggl);
    conv_mfma<1><<<gc, 256, 0, stream>>>(
        xpBh, xpBl, aggh, aggl, wcath + 131072, wcatl + 131072, convb + DIM,
        gamma + DIM, beta + DIM, bnmean + DIM, bnvar + DIM, bufC, xpAh, xpAl);
    // conv layer 2 (edge-weighted, bias only): bufC -> bufA + xpB planes
    agg_kernel<true><<<NN / 4, 256, 0, stream>>>(bufC, esrc, ewt, off, aggh, aggl);
    conv_mfma<0><<<gc, 256, 0, stream>>>(
        xpAh, xpAl, aggh, aggl, wcath + 262144, wcatl + 262144, convb + 2 * DIM,
        nullptr, nullptr, nullptr, nullptr, bufA, xpBh, xpBl);

    // QKV (fp16 3-pass MFMA) -> Q/K planes (Q/8) + V^T
    qkv_mfma<<<dim3(12, NN / 64), 256, 0, stream>>>(
        xpBh, xpBl, wt4h, wt4l, bqkv, qh, ql, kh, kl, vt);

    // flash attention (8-wave QB=128, swizzled dbuf, 4-way key split)
    attn_kernel<<<dim3(NN / QB, NH, NSPLIT), 512, 0, stream>>>(
        qh, ql, kh, kl, vt, o0, o1, o2, o3, mpart, lpart);

    // Wo + residual with FUSED 4-partial combine: kh/kl = planes(...)
    wo_fused<<<dim3(DIM / 64, NN / 32), 256, 0, stream>>>(
        o0, o1, o2, o3, mpart, lpart,
        wt4h + 3 * 65536, wt4l + 3 * 65536, bo, bufA, kh, kl);

    // fc1 + ELU (fp16 3-pass MFMA): feats = elu(x' @ fc1W + fc1b)
    fc1_mfma<<<dim3(F1D / 64, NN / 32), 256, 0, stream>>>(
        kh, kl, fc1h, fc1l, fc1b, feats);

    // adapter routing -> out
    adapter_kernel<<<NN / 4, 256, 0, stream>>>(feats, grp, AW1, Ab1, AW2, Ab2, outp);
}

// Round 20
// 206.210 us; speedup vs baseline: 1.2044x; 1.0013x over previous
//
#include <hip/hip_runtime.h>
#include <math.h>

#define NN   4096
#define DIM  256
#define NE   131072
#define NH   4
#define DH   64
#define F1D  128
#define NG   16
#define AD   32

typedef unsigned short u16;
typedef unsigned int   u32;
typedef _Float16 f16;
typedef __attribute__((ext_vector_type(8))) _Float16 half8;
typedef __attribute__((ext_vector_type(4))) float f32x4;

#define MFMA16(a, b, c) __builtin_amdgcn_mfma_f32_16x16x32_f16(a, b, c, 0, 0, 0)

__device__ inline u16 f2h(float x) { union { f16 f; u16 u; } c; c.f = (f16)x; return c.u; }
__device__ inline float h2f(u16 h) { union { f16 f; u16 u; } c; c.u = h; return (float)c.f; }
// fp16 hi/lo split: x = hi + lo + eps, |eps| <= 2^-24 |x|  (fp32-grade)
__device__ inline void split16(float x, u16& h, u16& l) {
    union { f16 f; u16 u; } ch, cl;
    ch.f = (f16)x;
    cl.f = (f16)(x - (float)ch.f);
    h = ch.u; l = cl.u;
}
// XOR-swizzled index into a [64|128][64]-u16 LDS tile (128 B rows).
__device__ inline int swz64(int row, int colByte) {
    return row * 64 + ((colByte ^ ((row & 7) << 4)) >> 1);
}

// ---------------- CSR build ----------------
__global__ void csr_count(const int* __restrict__ dst, int* __restrict__ cnt) {
    int e = blockIdx.x * 256 + threadIdx.x;
    atomicAdd(&cnt[dst[e]], 1);
}

__global__ __launch_bounds__(1024) void csr_scan(
    int* __restrict__ cnt, int* __restrict__ off)
{
    __shared__ int wsum[16];
    const int t = threadIdx.x;
    const int lane = t & 63;
    int4 v = *(const int4*)&cnt[t * 4];
    const int s = v.x + v.y + v.z + v.w;
    int acc = s;
    #pragma unroll
    for (int o = 1; o < 64; o <<= 1) {
        int u = __shfl_up(acc, o);
        if (lane >= o) acc += u;
    }
    if (lane == 63) wsum[t >> 6] = acc;
    __syncthreads();
    if (t < 16) {
        int w0 = wsum[t];
        int a2 = w0;
        #pragma unroll
        for (int o = 1; o < 16; o <<= 1) {
            int u = __shfl_up(a2, o);
            if (t >= o) a2 += u;
        }
        wsum[t] = a2 - w0;
    }
    __syncthreads();
    const int base = wsum[t >> 6] + (acc - s);
    off[t * 4 + 0] = base;
    off[t * 4 + 1] = base + v.x;
    off[t * 4 + 2] = base + v.x + v.y;
    off[t * 4 + 3] = base + v.x + v.y + v.z;
    *(int4*)&cnt[t * 4] = make_int4(0, 0, 0, 0);
    if (t == 1023) off[NN] = base + s;
}

__global__ void csr_fill(const int* __restrict__ dst, const int* __restrict__ src,
                         const float* __restrict__ eattr, const int* __restrict__ off,
                         int* __restrict__ cur, int* __restrict__ esrc,
                         float* __restrict__ ewt) {
    int e = blockIdx.x * 256 + threadIdx.x;
    int d = dst[e];
    int pos = off[d] + atomicAdd(&cur[d], 1);
    esrc[pos] = src[e];
    ewt[pos]  = eattr[e];
}

// ---------------- fused one-time prep: all weight/x converts + zero cur ----
__global__ __launch_bounds__(256) void prep_kernel(
    const float* __restrict__ x,
    const float* __restrict__ Ws, const float* __restrict__ Wn,
    const float* __restrict__ Wqkv, const float* __restrict__ Wo,
    const float* __restrict__ fc1W,
    u16* __restrict__ xh, u16* __restrict__ xl,
    u16* __restrict__ wch, u16* __restrict__ wcl,
    u16* __restrict__ w4h, u16* __restrict__ w4l,
    u16* __restrict__ f1h, u16* __restrict__ f1l,
    int* __restrict__ cur)
{
    const int b = blockIdx.x;
    const int t = threadIdx.x;
    if (b < 1024) {
        const int gid = b * 256 + t;
        const float4 v = *(const float4*)&x[(size_t)gid * 4];
        u16 h[4], l[4];
        split16(v.x, h[0], l[0]); split16(v.y, h[1], l[1]);
        split16(v.z, h[2], l[2]); split16(v.w, h[3], l[3]);
        *(uint2*)&xh[(size_t)gid * 4] =
            make_uint2((u32)h[0] | ((u32)h[1] << 16), (u32)h[2] | ((u32)h[3] << 16));
        *(uint2*)&xl[(size_t)gid * 4] =
            make_uint2((u32)l[0] | ((u32)l[1] << 16), (u32)l[2] | ((u32)l[3] << 16));
    } else if (b < 1408) {
        const int gid = (b - 1024) * 256 + t;
        const int L = gid / 32768;
        const int rem = gid % 32768;
        const int m = rem / 128;
        const int k4 = (rem % 128) * 4;
        const float* S = Ws + (size_t)L * 65536;
        const float* Nb = Wn + (size_t)L * 65536;
        u16 h[4], l[4];
        #pragma unroll
        for (int j = 0; j < 4; ++j) {
            const int k = k4 + j;
            const float v = (k < 256) ? S[(size_t)k * 256 + m]
                                      : Nb[(size_t)(k - 256) * 256 + m];
            split16(v, h[j], l[j]);
        }
        const size_t o = (size_t)L * 131072 + (size_t)m * 512 + k4;
        *(uint2*)&wch[o] = make_uint2((u32)h[0] | ((u32)h[1] << 16), (u32)h[2] | ((u32)h[3] << 16));
        *(uint2*)&wcl[o] = make_uint2((u32)l[0] | ((u32)l[1] << 16), (u32)l[2] | ((u32)l[3] << 16));
    } else if (b < 1664) {
        const int gid = (b - 1408) * 256 + t;
        const int mat = gid / 16384;
        const int rem = gid % 16384;
        const int m = rem / 64;
        const int k4 = (rem % 64) * 4;
        const float* W = (mat < 3) ? Wqkv + (size_t)mat * 65536 : Wo;
        u16 h[4], l[4];
        #pragma unroll
        for (int j = 0; j < 4; ++j)
            split16(W[(size_t)(k4 + j) * 256 + m], h[j], l[j]);
        const size_t o = (size_t)mat * 65536 + (size_t)m * 256 + k4;
        *(uint2*)&w4h[o] = make_uint2((u32)h[0] | ((u32)h[1] << 16), (u32)h[2] | ((u32)h[3] << 16));
        *(uint2*)&w4l[o] = make_uint2((u32)l[0] | ((u32)l[1] << 16), (u32)l[2] | ((u32)l[3] << 16));
    } else if (b < 1696) {
        const int gid = (b - 1664) * 256 + t;
        const int m = gid / 64;
        const int k4 = (gid % 64) * 4;
        u16 h[4], l[4];
        #pragma unroll
        for (int j = 0; j < 4; ++j)
            split16(fc1W[(size_t)(k4 + j) * F1D + m], h[j], l[j]);
        const size_t o = (size_t)m * 256 + k4;
        *(uint2*)&f1h[o] = make_uint2((u32)h[0] | ((u32)h[1] << 16), (u32)h[2] | ((u32)h[3] << 16));
        *(uint2*)&f1l[o] = make_uint2((u32)l[0] | ((u32)l[1] << 16), (u32)l[2] | ((u32)l[3] << 16));
    } else {
        const int gid = (b - 1696) * 256 + t;
        if (gid < NN / 4) *(int4*)&cur[gid * 4] = make_int4(0, 0, 0, 0);
    }
}

// ---------------- neighbor aggregation: 1 wave per node, unroll-8 ---------
template<bool LAST>
__global__ __launch_bounds__(256) void agg_kernel(
    const float* __restrict__ x, const int* __restrict__ esrc,
    const float* __restrict__ ewt, const int* __restrict__ off,
    u16* __restrict__ aggh, u16* __restrict__ aggl)
{
    const int node = blockIdx.x * 4 + (threadIdx.x >> 6);
    const int lane = threadIdx.x & 63;
    const int d4 = lane * 4;
    int j = off[node];
    const int j1 = off[node + 1];
    float4 acc = make_float4(0.f, 0.f, 0.f, 0.f);
    for (; j + 8 <= j1; j += 8) {
        int s[8];
        #pragma unroll
        for (int u = 0; u < 8; ++u) s[u] = esrc[j + u];
        float4 xv[8];
        #pragma unroll
        for (int u = 0; u < 8; ++u)
            xv[u] = *(const float4*)&x[(size_t)s[u] * DIM + d4];
        float wv[8];
        #pragma unroll
        for (int u = 0; u < 8; ++u) wv[u] = LAST ? ewt[j + u] : 1.f;
        #pragma unroll
        for (int u = 0; u < 8; ++u) {   // sequential order: bit-identical
            acc.x = fmaf(xv[u].x, wv[u], acc.x);
            acc.y = fmaf(xv[u].y, wv[u], acc.y);
            acc.z = fmaf(xv[u].z, wv[u], acc.z);
            acc.w = fmaf(xv[u].w, wv[u], acc.w);
        }
    }
    for (; j < j1; ++j) {
        const int s = esrc[j];
        const float w = LAST ? ewt[j] : 1.f;
        const float4 xv = *(const float4*)&x[(size_t)s * DIM + d4];
        acc.x = fmaf(xv.x, w, acc.x); acc.y = fmaf(xv.y, w, acc.y);
        acc.z = fmaf(xv.z, w, acc.z); acc.w = fmaf(xv.w, w, acc.w);
    }
    u16 h[4], l[4];
    split16(acc.x, h[0], l[0]); split16(acc.y, h[1], l[1]);
    split16(acc.z, h[2], l[2]); split16(acc.w, h[3], l[3]);
    *(uint2*)&aggh[(size_t)node * DIM + d4] =
        make_uint2((u32)h[0] | ((u32)h[1] << 16), (u32)h[2] | ((u32)h[3] << 16));
    *(uint2*)&aggl[(size_t)node * DIM + d4] =
        make_uint2((u32)l[0] | ((u32)l[1] << 16), (u32)l[2] | ((u32)l[3] << 16));
}

// ---------------- conv MFMA GEMM: 32x64 tile, LDS dbuf 1-barrier ----------
template<int EPI>   // 0 = bias only, 1 = bias+BN+ELU
__global__ __launch_bounds__(256) void conv_mfma(
    const u16* __restrict__ xh, const u16* __restrict__ xl,
    const u16* __restrict__ gh, const u16* __restrict__ gl,
    const u16* __restrict__ bth, const u16* __restrict__ btl,
    const float* __restrict__ bias,
    const float* __restrict__ gamma, const float* __restrict__ beta,
    const float* __restrict__ bnmean, const float* __restrict__ bnvar,
    float* __restrict__ outf, u16* __restrict__ oh, u16* __restrict__ ol)
{
    __shared__ u16 lds[27648];           // 2 sets x 13824 u16 (55296 B)
    #define TKP 72

    const int tid  = threadIdx.x;
    const int row0 = blockIdx.y * 32;
    const int col0 = blockIdx.x * 64;

    const int w   = tid >> 6;
    const int l15 = tid & 15, h4 = (tid & 63) >> 4;
    const int rh  = w & 1, ch = w >> 1;
    const int arow = tid >> 3, acs = (tid & 7) * 8;
    const int brow = tid & 63, bseg = tid >> 6;
    const int bc = bseg * 16;

    uint4 sah, sal, sbh0, sbh1, sbl0, sbl1;
    auto load_kt = [&](int kn) {
        const u16 *pah, *pal;
        if (kn < 4) {
            pah = xh + (size_t)(row0 + arow) * DIM + kn * 64 + acs;
            pal = xl + (size_t)(row0 + arow) * DIM + kn * 64 + acs;
        } else {
            pah = gh + (size_t)(row0 + arow) * DIM + (kn - 4) * 64 + acs;
            pal = gl + (size_t)(row0 + arow) * DIM + (kn - 4) * 64 + acs;
        }
        sah = *((const uint4*)pah);
        sal = *((const uint4*)pal);
        const u16* pbh = bth + (size_t)(col0 + brow) * 512 + kn * 64 + bc;
        const u16* pbl = btl + (size_t)(col0 + brow) * 512 + kn * 64 + bc;
        sbh0 = ((const uint4*)pbh)[0]; sbh1 = ((const uint4*)pbh)[1];
        sbl0 = ((const uint4*)pbl)[0]; sbl1 = ((const uint4*)pbl)[1];
    };
    auto stage_to = [&](u16* base) {
        *(uint4*)&base[arow * TKP + acs]          = sah;   // A_h
        *(uint4*)&base[2304 + arow * TKP + acs]   = sal;   // A_l
        *(uint4*)&base[4608 + brow * TKP + bc]      = sbh0; // B_h
        *(uint4*)&base[4608 + brow * TKP + bc + 8]  = sbh1;
        *(uint4*)&base[9216 + brow * TKP + bc]      = sbl0; // B_l
        *(uint4*)&base[9216 + brow * TKP + bc + 8]  = sbl1;
    };

    load_kt(0);
    stage_to(lds);
    load_kt(1);
    __syncthreads();                     // set0 ready

    const f32x4 z4 = {0.f, 0.f, 0.f, 0.f};
    f32x4 acc[2] = {z4, z4};

    u16* cur = lds;
    u16* nxt = lds + 13824;
    for (int kt = 0; kt < 8; ++kt) {
        if (kt + 1 < 8) stage_to(nxt);   // regs(kt+1) -> idle buffer
        if (kt + 2 < 8) load_kt(kt + 2); // early-issue global loads
        const u16* Ah_ = cur;
        const u16* Al_ = cur + 2304;
        const u16* Bh_ = cur + 4608;
        const u16* Bl_ = cur + 9216;
        __builtin_amdgcn_s_setprio(1);
        #pragma unroll
        for (int kc = 0; kc < 2; ++kc) {
            const int dc = kc * 32 + h4 * 8;
            half8 afh, afl, bfh[2], bfl[2];
            afh = *(const half8*)&Ah_[(rh * 16 + l15) * TKP + dc];
            afl = *(const half8*)&Al_[(rh * 16 + l15) * TKP + dc];
            #pragma unroll
            for (int bb = 0; bb < 2; ++bb) {
                const int r = ch * 32 + bb * 16 + l15;
                bfh[bb] = *(const half8*)&Bh_[r * TKP + dc];
                bfl[bb] = *(const half8*)&Bl_[r * TKP + dc];
            }
            #pragma unroll
            for (int bb = 0; bb < 2; ++bb) {
                acc[bb] = MFMA16(afh, bfh[bb], acc[bb]);
                acc[bb] = MFMA16(afh, bfl[bb], acc[bb]);
                acc[bb] = MFMA16(afl, bfh[bb], acc[bb]);
            }
        }
        __builtin_amdgcn_s_setprio(0);
        __syncthreads();                 // nxt staged + cur reads done
        u16* t2 = cur; cur = nxt; nxt = t2;
    }

    #pragma unroll
    for (int bb = 0; bb < 2; ++bb) {
        const int c  = col0 + ch * 32 + bb * 16 + l15;
        const int r0 = row0 + rh * 16 + h4 * 4;
        #pragma unroll
        for (int i = 0; i < 4; ++i) {
            const int r = r0 + i;
            float t = acc[bb][i] + bias[c];
            if (EPI == 1) {
                t = gamma[c] * (t - bnmean[c]) * rsqrtf(bnvar[c] + 1e-5f) + beta[c];
                t = t > 0.f ? t : expm1f(t);
            }
            outf[(size_t)r * DIM + c] = t;
            u16 hh, ll;
            split16(t, hh, ll);
            oh[(size_t)r * DIM + c] = hh;
            ol[(size_t)r * DIM + c] = ll;
        }
    }
    #undef TKP
}

// ---------------- QKV MFMA GEMM (fp16 3-pass, early prefetch) -------------
__global__ __launch_bounds__(256) void qkv_mfma(
    const u16* __restrict__ xh, const u16* __restrict__ xl,
    const u16* __restrict__ wth, const u16* __restrict__ wtl,
    const float* __restrict__ bias,
    u16* __restrict__ qh_o, u16* __restrict__ ql_o,
    u16* __restrict__ kh_o, u16* __restrict__ kl_o,
    u16* __restrict__ vt_o)
{
    __shared__ u16 lds[4 * 4608];
    u16* As_h = lds;
    u16* As_l = lds + 4608;
    u16* Bs_h = lds + 9216;
    u16* Bs_l = lds + 13824;
    #define TKP 72

    const int tid  = threadIdx.x;
    const int row0 = blockIdx.y * 64;
    const int mat  = blockIdx.x >> 2;
    const int col0 = (blockIdx.x & 3) * 64;
    const float* biasp = bias + mat * DIM;

    const int w   = tid >> 6;
    const int l15 = tid & 15, h4 = (tid & 63) >> 4;
    const int rh  = w & 1, ch = w >> 1;
    const int lrow = tid & 63, lseg = tid >> 6;
    const int lc = lseg * 16;

    const size_t brow = (size_t)(mat * 256 + col0 + lrow) * 256;
    uint4 sah0, sah1, sal0, sal1, sbh0, sbh1, sbl0, sbl1;
    {
        const u16* pah = xh + (size_t)(row0 + lrow) * DIM + lc;
        const u16* pal = xl + (size_t)(row0 + lrow) * DIM + lc;
        sah0 = ((const uint4*)pah)[0]; sah1 = ((const uint4*)pah)[1];
        sal0 = ((const uint4*)pal)[0]; sal1 = ((const uint4*)pal)[1];
        sbh0 = ((const uint4*)(wth + brow + lc))[0]; sbh1 = ((const uint4*)(wth + brow + lc))[1];
        sbl0 = ((const uint4*)(wtl + brow + lc))[0]; sbl1 = ((const uint4*)(wtl + brow + lc))[1];
    }

    const f32x4 z4 = {0.f, 0.f, 0.f, 0.f};
    f32x4 acc[2][2] = {{z4, z4}, {z4, z4}};

    for (int kt = 0; kt < 4; ++kt) {
        *(uint4*)&As_h[lrow * TKP + lc]     = sah0;
        *(uint4*)&As_h[lrow * TKP + lc + 8] = sah1;
        *(uint4*)&As_l[lrow * TKP + lc]     = sal0;
        *(uint4*)&As_l[lrow * TKP + lc + 8] = sal1;
        *(uint4*)&Bs_h[lrow * TKP + lc]     = sbh0;
        *(uint4*)&Bs_h[lrow * TKP + lc + 8] = sbh1;
        *(uint4*)&Bs_l[lrow * TKP + lc]     = sbl0;
        *(uint4*)&Bs_l[lrow * TKP + lc + 8] = sbl1;
        if (kt + 1 < 4) {
            const int kb = (kt + 1) * 64 + lc;
            const u16* pah = xh + (size_t)(row0 + lrow) * DIM + kb;
            const u16* pal = xl + (size_t)(row0 + lrow) * DIM + kb;
            sah0 = ((const uint4*)pah)[0]; sah1 = ((const uint4*)pah)[1];
            sal0 = ((const uint4*)pal)[0]; sal1 = ((const uint4*)pal)[1];
            sbh0 = ((const uint4*)(wth + brow + kb))[0]; sbh1 = ((const uint4*)(wth + brow + kb))[1];
            sbl0 = ((const uint4*)(wtl + brow + kb))[0]; sbl1 = ((const uint4*)(wtl + brow + kb))[1];
        }
        __syncthreads();

        __builtin_amdgcn_s_setprio(1);
        #pragma unroll
        for (int kc = 0; kc < 2; ++kc) {
            const int dc = kc * 32 + h4 * 8;
            half8 afh[2], afl[2], bfh[2], bfl[2];
            #pragma unroll
            for (int ab = 0; ab < 2; ++ab) {
                const int r = rh * 32 + ab * 16 + l15;
                afh[ab] = *(const half8*)&As_h[r * TKP + dc];
                afl[ab] = *(const half8*)&As_l[r * TKP + dc];
            }
            #pragma unroll
            for (int bb = 0; bb < 2; ++bb) {
                const int r = ch * 32 + bb * 16 + l15;
                bfh[bb] = *(const half8*)&Bs_h[r * TKP + dc];
                bfl[bb] = *(const half8*)&Bs_l[r * TKP + dc];
            }
            #pragma unroll
            for (int ab = 0; ab < 2; ++ab)
                #pragma unroll
                for (int bb = 0; bb < 2; ++bb) {
                    acc[ab][bb] = MFMA16(afh[ab], bfh[bb], acc[ab][bb]);
                    acc[ab][bb] = MFMA16(afh[ab], bfl[bb], acc[ab][bb]);
                    acc[ab][bb] = MFMA16(afl[ab], bfh[bb], acc[ab][bb]);
                }
        }
        __builtin_amdgcn_s_setprio(0);
        __syncthreads();
    }

    const float s = (mat == 0) ? 0.125f : 1.0f;
    u16* oph = (mat == 0) ? qh_o : kh_o;
    u16* opl = (mat == 0) ? ql_o : kl_o;
    #pragma unroll
    for (int ab = 0; ab < 2; ++ab)
        #pragma unroll
        for (int bb = 0; bb < 2; ++bb) {
            const int c  = col0 + ch * 32 + bb * 16 + l15;
            const int r0 = row0 + rh * 32 + ab * 16 + h4 * 4;
            if (mat < 2) {
                #pragma unroll
                for (int i = 0; i < 4; ++i) {
                    const int r = r0 + i;
                    const float t = (acc[ab][bb][i] + biasp[c]) * s;
                    u16 hh, ll;
                    split16(t, hh, ll);
                    oph[(size_t)r * DIM + c] = hh;
                    opl[(size_t)r * DIM + c] = ll;
                }
            } else {
                u16 v[4];
                #pragma unroll
                for (int i = 0; i < 4; ++i)
                    v[i] = f2h(acc[ab][bb][i] + biasp[c]);
                *(uint2*)&vt_o[(size_t)c * NN + r0] =
                    make_uint2((u32)v[0] | ((u32)v[1] << 16), (u32)v[2] | ((u32)v[3] << 16));
            }
        }
    #undef TKP
}

// ---------------- Wo GEMM, FUSED combine, LDS dbuf 1-barrier --------------
__global__ __launch_bounds__(256) void wo_fused(
    const u16* __restrict__ p0, const u16* __restrict__ p1,
    const u16* __restrict__ p2, const u16* __restrict__ p3,
    const float* __restrict__ mp, const float* __restrict__ lp,
    const u16* __restrict__ Bth, const u16* __restrict__ Btl,
    const float* __restrict__ bias, const float* __restrict__ resid,
    u16* __restrict__ outh, u16* __restrict__ outl)
{
    __shared__ u16 lds[27648];           // 2 sets x 13824 u16
    #define TKP 72
    const int K = DIM, M = DIM;

    const int tid  = threadIdx.x;
    const int row0 = blockIdx.y * 32;
    const int col0 = blockIdx.x * 64;

    const int w   = tid >> 6;
    const int l15 = tid & 15, h4 = (tid & 63) >> 4;
    const int rh  = w & 1, ch = w >> 1;
    const int arow = tid >> 3, acs = (tid & 7) * 8;
    const int brow = tid & 63, bseg = tid >> 6;
    const int bc = bseg * 16;
    const int r = row0 + arow;           // A row this thread stages

    uint4 pa0, pa1, pa2, pa3, sbh0, sbh1, sbl0, sbl1;
    auto load_kt = [&](int kn) {
        const size_t ao = (size_t)r * DIM + kn * 64 + acs;
        pa0 = *(const uint4*)&p0[ao];
        pa1 = *(const uint4*)&p1[ao];
        pa2 = *(const uint4*)&p2[ao];
        pa3 = *(const uint4*)&p3[ao];
        const u16* pbh = Bth + (size_t)(col0 + brow) * K + kn * 64 + bc;
        const u16* pbl = Btl + (size_t)(col0 + brow) * K + kn * 64 + bc;
        sbh0 = ((const uint4*)pbh)[0]; sbh1 = ((const uint4*)pbh)[1];
        sbl0 = ((const uint4*)pbl)[0]; sbl1 = ((const uint4*)pbl)[1];
    };
    auto stage_to = [&](u16* base, int hd) {
        // merge 4 partials for head = hd (same math/order as r19)
        const float m0 = mp[((size_t)0 * NN + r) * NH + hd];
        const float m1 = mp[((size_t)1 * NN + r) * NH + hd];
        const float m2 = mp[((size_t)2 * NN + r) * NH + hd];
        const float m3 = mp[((size_t)3 * NN + r) * NH + hd];
        const float M2 = fmaxf(fmaxf(m0, m1), fmaxf(m2, m3));
        const float w0 = lp[((size_t)0 * NN + r) * NH + hd] * __expf(m0 - M2);
        const float w1 = lp[((size_t)1 * NN + r) * NH + hd] * __expf(m1 - M2);
        const float w2 = lp[((size_t)2 * NN + r) * NH + hd] * __expf(m2 - M2);
        const float w3 = lp[((size_t)3 * NN + r) * NH + hd] * __expf(m3 - M2);
        const float inv = 1.f / (((w0 + w1) + (w2 + w3)));
        union { uint4 v; u16 u[8]; } a0, a1, a2, a3, oh_, ol_;
        a0.v = pa0; a1.v = pa1; a2.v = pa2; a3.v = pa3;
        #pragma unroll
        for (int j = 0; j < 8; ++j) {
            const float mv = (w0 * h2f(a0.u[j]) + w1 * h2f(a1.u[j]) +
                              w2 * h2f(a2.u[j]) + w3 * h2f(a3.u[j])) * inv;
            split16(mv, oh_.u[j], ol_.u[j]);
        }
        *(uint4*)&base[arow * TKP + acs]        = oh_.v;   // A_h
        *(uint4*)&base[2304 + arow * TKP + acs] = ol_.v;   // A_l
        *(uint4*)&base[4608 + brow * TKP + bc]     = sbh0; // B_h
        *(uint4*)&base[4608 + brow * TKP + bc + 8] = sbh1;
        *(uint4*)&base[9216 + brow * TKP + bc]     = sbl0; // B_l
        *(uint4*)&base[9216 + brow * TKP + bc + 8] = sbl1;
    };

    load_kt(0);
    stage_to(lds, 0);
    load_kt(1);
    __syncthreads();

    const f32x4 z4 = {0.f, 0.f, 0.f, 0.f};
    f32x4 acc[2] = {z4, z4};

    u16* cur = lds;
    u16* nxt = lds + 13824;
    for (int kt = 0; kt < 4; ++kt) {
        if (kt + 1 < 4) stage_to(nxt, kt + 1);
        if (kt + 2 < 4) load_kt(kt + 2);
        const u16* Ah_ = cur;
        const u16* Al_ = cur + 2304;
        const u16* Bh_ = cur + 4608;
        const u16* Bl_ = cur + 9216;
        __builtin_amdgcn_s_setprio(1);
        #pragma unroll
        for (int kc = 0; kc < 2; ++kc) {
            const int dc = kc * 32 + h4 * 8;
            half8 afh, afl, bfh[2], bfl[2];
            afh = *(const half8*)&Ah_[(rh * 16 + l15) * TKP + dc];
            afl = *(const half8*)&Al_[(rh * 16 + l15) * TKP + dc];
            #pragma unroll
            for (int bb = 0; bb < 2; ++bb) {
                const int rr = ch * 32 + bb * 16 + l15;
                bfh[bb] = *(const half8*)&Bh_[rr * TKP + dc];
                bfl[bb] = *(const half8*)&Bl_[rr * TKP + dc];
            }
            #pragma unroll
            for (int bb = 0; bb < 2; ++bb) {
                acc[bb] = MFMA16(afh, bfh[bb], acc[bb]);
                acc[bb] = MFMA16(afh, bfl[bb], acc[bb]);
                acc[bb] = MFMA16(afl, bfh[bb], acc[bb]);
            }
        }
        __builtin_amdgcn_s_setprio(0);
        __syncthreads();
        u16* t2 = cur; cur = nxt; nxt = t2;
    }

    #pragma unroll
    for (int bb = 0; bb < 2; ++bb) {
        const int c  = col0 + ch * 32 + bb * 16 + l15;
        const int r0 = row0 + rh * 16 + h4 * 4;
        #pragma unroll
        for (int i = 0; i < 4; ++i) {
            const int rr = r0 + i;
            float t = acc[bb][i] + bias[c] + resid[(size_t)rr * M + c];
            u16 hh, ll;
            split16(t, hh, ll);
            outh[(size_t)rr * M + c] = hh;
            outl[(size_t)rr * M + c] = ll;
        }
    }
    #undef TKP
}

// ---------------- fc1 MFMA GEMM, 32x64 tile, LDS dbuf 1-barrier -----------
__global__ __launch_bounds__(256) void fc1_mfma(
    const u16* __restrict__ Ah, const u16* __restrict__ Al,
    const u16* __restrict__ Bth, const u16* __restrict__ Btl,
    const float* __restrict__ bias, float* __restrict__ outf)
{
    __shared__ u16 lds[27648];
    #define TKP 72
    const int K = DIM, M = F1D;

    const int tid  = threadIdx.x;
    const int row0 = blockIdx.y * 32;
    const int col0 = blockIdx.x * 64;

    const int w   = tid >> 6;
    const int l15 = tid & 15, h4 = (tid & 63) >> 4;
    const int rh  = w & 1, ch = w >> 1;
    const int arow = tid >> 3, acs = (tid & 7) * 8;
    const int brow = tid & 63, bseg = tid >> 6;
    const int bc = bseg * 16;

    uint4 sah, sal, sbh0, sbh1, sbl0, sbl1;
    auto load_kt = [&](int kn) {
        sah = *((const uint4*)&Ah[(size_t)(row0 + arow) * K + kn * 64 + acs]);
        sal = *((const uint4*)&Al[(size_t)(row0 + arow) * K + kn * 64 + acs]);
        const u16* pbh = Bth + (size_t)(col0 + brow) * K + kn * 64 + bc;
        const u16* pbl = Btl + (size_t)(col0 + brow) * K + kn * 64 + bc;
        sbh0 = ((const uint4*)pbh)[0]; sbh1 = ((const uint4*)pbh)[1];
        sbl0 = ((const uint4*)pbl)[0]; sbl1 = ((const uint4*)pbl)[1];
    };
    auto stage_to = [&](u16* base) {
        *(uint4*)&base[arow * TKP + acs]        = sah;
        *(uint4*)&base[2304 + arow * TKP + acs] = sal;
        *(uint4*)&base[4608 + brow * TKP + bc]     = sbh0;
        *(uint4*)&base[4608 + brow * TKP + bc + 8] = sbh1;
        *(uint4*)&base[9216 + brow * TKP + bc]     = sbl0;
        *(uint4*)&base[9216 + brow * TKP + bc + 8] = sbl1;
    };

    load_kt(0);
    stage_to(lds);
    load_kt(1);
    __syncthreads();

    const f32x4 z4 = {0.f, 0.f, 0.f, 0.f};
    f32x4 acc[2] = {z4, z4};

    u16* cur = lds;
    u16* nxt = lds + 13824;
    for (int kt = 0; kt < 4; ++kt) {
        if (kt + 1 < 4) stage_to(nxt);
        if (kt + 2 < 4) load_kt(kt + 2);
        const u16* Ah_ = cur;
        const u16* Al_ = cur + 2304;
        const u16* Bh_ = cur + 4608;
        const u16* Bl_ = cur + 9216;
        __builtin_amdgcn_s_setprio(1);
        #pragma unroll
        for (int kc = 0; kc < 2; ++kc) {
            const int dc = kc * 32 + h4 * 8;
            half8 afh, afl, bfh[2], bfl[2];
            afh = *(const half8*)&Ah_[(rh * 16 + l15) * TKP + dc];
            afl = *(const half8*)&Al_[(rh * 16 + l15) * TKP + dc];
            #pragma unroll
            for (int bb = 0; bb < 2; ++bb) {
                const int rr = ch * 32 + bb * 16 + l15;
                bfh[bb] = *(const half8*)&Bh_[rr * TKP + dc];
                bfl[bb] = *(const half8*)&Bl_[rr * TKP + dc];
            }
            #pragma unroll
            for (int bb = 0; bb < 2; ++bb) {
                acc[bb] = MFMA16(afh, bfh[bb], acc[bb]);
                acc[bb] = MFMA16(afh, bfl[bb], acc[bb]);
                acc[bb] = MFMA16(afl, bfh[bb], acc[bb]);
            }
        }
        __builtin_amdgcn_s_setprio(0);
        __syncthreads();
        u16* t2 = cur; cur = nxt; nxt = t2;
    }

    #pragma unroll
    for (int bb = 0; bb < 2; ++bb) {
        const int c  = col0 + ch * 32 + bb * 16 + l15;
        const int r0 = row0 + rh * 16 + h4 * 4;
        #pragma unroll
        for (int i = 0; i < 4; ++i) {
            const int rr = r0 + i;
            float t = acc[bb][i] + bias[c];
            t = t > 0.f ? t : expm1f(t);
            outf[(size_t)rr * M + c] = t;
        }
    }
    #undef TKP
}

// ---------------- MFMA flash attention (round-19 structure, unchanged) ----
#define QB 128
#define KB 64
#define NSPLIT 4
#define NKT (NN / KB)

__global__ __launch_bounds__(512, 2) void attn_kernel(
    const u16* __restrict__ qhi, const u16* __restrict__ qlo,
    const u16* __restrict__ khi, const u16* __restrict__ klo,
    const u16* __restrict__ vT,
    u16* __restrict__ op0, u16* __restrict__ op1,
    u16* __restrict__ op2, u16* __restrict__ op3,
    float* __restrict__ mpart, float* __restrict__ lpart)
{
    __shared__ u16 lds[24576];            // 49152 B
    u16* Kh0 = lds;                       // [64][64] swizzled
    u16* Kl0 = lds + 4096;
    u16* Vt0 = lds + 8192;
    u16* Kh1 = lds + 12288;
    u16* Kl1 = lds + 16384;
    u16* Vt1 = lds + 20480;
    u16* Qh  = lds;                       // overlay (init): [128][64] swizzled
    u16* Ql  = lds + 8192;                // overlay (init)

    const int tid = threadIdx.x;
    const int h   = blockIdx.y;
    const int q0  = blockIdx.x * QB;
    const int sp  = blockIdx.z;
    const int kt0 = (sp * NKT) / NSPLIT;
    const int kt1 = ((sp + 1) * NKT) / NSPLIT;

    const int w   = tid >> 6;             // wave 0..7 -> q rows w*16..+15
    const int l15 = tid & 15, h4 = (tid & 63) >> 4;
    const int lrow = tid & 63, lseg = tid >> 6;   // staging: 8 segs x 8 u16
    const int gq8 = h * DH + lseg * 8;

    {   // stage Q (once, into overlay region): 128 rows x 64 d, swizzled
        const int qrow = tid >> 2, qseg = tid & 3;
        const u16* s0 = qhi + (size_t)(q0 + qrow) * DIM + h * DH + qseg * 16;
        const u16* s1 = qlo + (size_t)(q0 + qrow) * DIM + h * DH + qseg * 16;
        uint4 a = ((const uint4*)s0)[0], b = ((const uint4*)s0)[1];
        uint4 c = ((const uint4*)s1)[0], d = ((const uint4*)s1)[1];
        *(uint4*)&Qh[swz64(qrow, qseg * 32)]      = a;
        *(uint4*)&Qh[swz64(qrow, qseg * 32 + 16)] = b;
        *(uint4*)&Ql[swz64(qrow, qseg * 32)]      = c;
        *(uint4*)&Ql[swz64(qrow, qseg * 32 + 16)] = d;
    }

    uint4 rk, rl, rv;                     // staging registers
    auto load_tile = [&](int kt_ld) {
        const int key0 = kt_ld * KB;
        rk = *(const uint4*)(khi + (size_t)(key0 + lrow) * DIM + gq8);
        rl = *(const uint4*)(klo + (size_t)(key0 + lrow) * DIM + gq8);
        rv = *(const uint4*)(vT + (size_t)(h * DH + lrow) * NN + key0 + lseg * 8);
    };
    load_tile(kt0);
    __syncthreads();                              // Q staged

    half8 qf[2][2];                               // [kc][hi/lo]
    #pragma unroll
    for (int kc = 0; kc < 2; ++kc) {
        const int r = w * 16 + l15;
        const int cb = kc * 64 + h4 * 16;         // byte col
        qf[kc][0] = *(const half8*)&Qh[swz64(r, cb)];
        qf[kc][1] = *(const half8*)&Ql[swz64(r, cb)];
    }
    __syncthreads();                              // hoist done; overlay safe

    auto stage_to = [&](u16* Kh, u16* Kl, u16* Vt) {
        const int idx = swz64(lrow, lseg * 16);
        *(uint4*)&Kh[idx] = rk;
        *(uint4*)&Kl[idx] = rl;
        *(uint4*)&Vt[idx] = rv;
    };

    stage_to(Kh0, Kl0, Vt0);                      // tile kt0 -> buf0
    load_tile(kt0 + 1);                           // tile kt0+1 -> regs
    __syncthreads();                              // buf0 ready

    const f32x4 z4 = {0.f, 0.f, 0.f, 0.f};
    f32x4 oacc[4] = {z4, z4, z4, z4};             // d-blocks 0..3 for own q
    float m_run = -3.0e38f, l_run = 0.f;          // lane-local: q = w*16+l15
    const int sl0 = (h4 & 1) * 32 + l15;          // P-shuffle source lanes
    const int sl1 = sl0 + 16;

    auto tile_body = [&](int t, u16* Kc, u16* Lc, u16* Vc,
                         u16* Kn, u16* Ln, u16* Vn) {
        if (t + 1 < kt1) stage_to(Kn, Ln, Vn);    // writes to the idle buffer
        if (t + 2 < kt1) load_tile(t + 2);        // early-issue global loads

        // ---- S^T = K Q^T (swapped operands): lane holds S[q][16 k-vals]
        f32x4 sc[4] = {z4, z4, z4, z4};
        __builtin_amdgcn_s_setprio(1);
        #pragma unroll
        for (int kc = 0; kc < 2; ++kc) {
            const int cb = kc * 64 + h4 * 16;     // byte col
            half8 kfh[4], kfl[4];
            #pragma unroll
            for (int kcb = 0; kcb < 4; ++kcb) {
                const int r = kcb * 16 + l15;
                const int idx = swz64(r, cb);
                kfh[kcb] = *(const half8*)&Kc[idx];
                kfl[kcb] = *(const half8*)&Lc[idx];
            }
            #pragma unroll
            for (int kcb = 0; kcb < 4; ++kcb) {
                sc[kcb] = MFMA16(kfh[kcb], qf[kc][0], sc[kcb]);
                sc[kcb] = MFMA16(kfl[kcb], qf[kc][0], sc[kcb]);
                sc[kcb] = MFMA16(kfh[kcb], qf[kc][1], sc[kcb]);
            }
        }
        __builtin_amdgcn_s_setprio(0);

        // ---- lane-local softmax: tree max over 16, 2-shfl all-reduce ----
        float c0 = fmaxf(fmaxf(sc[0][0], sc[0][1]), fmaxf(sc[0][2], sc[0][3]));
        float c1 = fmaxf(fmaxf(sc[1][0], sc[1][1]), fmaxf(sc[1][2], sc[1][3]));
        float c2 = fmaxf(fmaxf(sc[2][0], sc[2][1]), fmaxf(sc[2][2], sc[2][3]));
        float c3 = fmaxf(fmaxf(sc[3][0], sc[3][1]), fmaxf(sc[3][2], sc[3][3]));
        float pm = fmaxf(fmaxf(c0, c1), fmaxf(c2, c3));
        pm = fmaxf(pm, __shfl_xor(pm, 16));
        pm = fmaxf(pm, __shfl_xor(pm, 32));

        float p[4][4];
        float base, fr = 1.f;
        int resc;
        if (__all(pm - m_run <= 8.f)) {           // defer-max (THR=8)
            base = m_run;
            resc = 0;
        } else {
            const float mnew = fmaxf(m_run, pm);
            fr = __expf(m_run - mnew);
            m_run = mnew;
            base = mnew;
            resc = 1;
        }
        #pragma unroll
        for (int kcb = 0; kcb < 4; ++kcb)
            #pragma unroll
            for (int i = 0; i < 4; ++i)
                p[kcb][i] = __expf(sc[kcb][i] - base);
        float s0s = (p[0][0] + p[0][1]) + (p[0][2] + p[0][3]);
        float s1s = (p[1][0] + p[1][1]) + (p[1][2] + p[1][3]);
        float s2s = (p[2][0] + p[2][1]) + (p[2][2] + p[2][3]);
        float s3s = (p[3][0] + p[3][1]) + (p[3][2] + p[3][3]);
        float ls = (s0s + s1s) + (s2s + s3s);
        ls += __shfl_xor(ls, 16);
        ls += __shfl_xor(ls, 32);
        if (resc) {
            l_run = l_run * fr + ls;
            #pragma unroll
            for (int db = 0; db < 4; ++db) oacc[db] *= fr;
        } else {
            l_run += ls;
        }

        // ---- pack P to fp16 pairs (per kcb: [i0|i1], [i2|i3]) ----
        u32 pk01[4], pk23[4];
        #pragma unroll
        for (int kcb = 0; kcb < 4; ++kcb) {
            pk01[kcb] = (u32)f2h(p[kcb][0]) | ((u32)f2h(p[kcb][1]) << 16);
            pk23[kcb] = (u32)f2h(p[kcb][2]) | ((u32)f2h(p[kcb][3]) << 16);
        }

        // ---- PV: B-fragment built by shuffles among lanes sharing l15 ----
        const int hiSel = h4 >> 1;
        __builtin_amdgcn_s_setprio(1);
        #pragma unroll
        for (int kc = 0; kc < 2; ++kc) {
            const u32 a0 = (u32)__shfl((int)pk01[kc * 2], sl0);
            const u32 a1 = (u32)__shfl((int)pk23[kc * 2], sl0);
            const u32 a2 = (u32)__shfl((int)pk01[kc * 2], sl1);
            const u32 a3 = (u32)__shfl((int)pk23[kc * 2], sl1);
            const u32 b0 = (u32)__shfl((int)pk01[kc * 2 + 1], sl0);
            const u32 b1 = (u32)__shfl((int)pk23[kc * 2 + 1], sl0);
            const u32 b2 = (u32)__shfl((int)pk01[kc * 2 + 1], sl1);
            const u32 b3 = (u32)__shfl((int)pk23[kc * 2 + 1], sl1);
            union { half8 v; u32 u[4]; } pf;
            pf.u[0] = hiSel ? b0 : a0;
            pf.u[1] = hiSel ? b1 : a1;
            pf.u[2] = hiSel ? b2 : a2;
            pf.u[3] = hiSel ? b3 : a3;
            const int cb = kc * 64 + h4 * 16;     // byte col
            #pragma unroll
            for (int db = 0; db < 4; ++db) {
                const half8 vf = *(const half8*)&Vc[swz64(db * 16 + l15, cb)];
                oacc[db] = MFMA16(vf, pf.v, oacc[db]);
            }
        }
        __builtin_amdgcn_s_setprio(0);
        __syncthreads();   // single per-tile barrier: buf^1 staged + reads done
    };

    {   // pointer-swap loop
        u16 *Kc = Kh0, *Lc = Kl0, *Vc = Vt0;
        u16 *Kn = Kh1, *Ln = Kl1, *Vn = Vt1;
        for (int t = kt0; t < kt1; ++t) {
            tile_body(t, Kc, Lc, Vc, Kn, Ln, Vn);
            u16* tmp;
            tmp = Kc; Kc = Kn; Kn = tmp;
            tmp = Lc; Lc = Ln; Ln = tmp;
            tmp = Vc; Vc = Vn; Vn = tmp;
        }
    }

    // epilogue: NORMALIZED fp16 partial (o/l_run)
    u16* ob = (sp == 0) ? op0 : ((sp == 1) ? op1 : ((sp == 2) ? op2 : op3));
    const float inv = 1.f / l_run;
    #pragma unroll
    for (int db = 0; db < 4; ++db) {
        u32 w0 = (u32)f2h(oacc[db][0] * inv) | ((u32)f2h(oacc[db][1] * inv) << 16);
        u32 w1 = (u32)f2h(oacc[db][2] * inv) | ((u32)f2h(oacc[db][3] * inv) << 16);
        *(uint2*)&ob[(size_t)(q0 + w * 16 + l15) * DIM + h * DH + db * 16 + h4 * 4] =
            make_uint2(w0, w1);
    }
    if (h4 == 0) {
        const int r = w * 16 + l15;
        mpart[((size_t)sp * NN + q0 + r) * NH + h] = m_run;
        lpart[((size_t)sp * NN + q0 + r) * NH + h] = l_run;
    }
}

// ---------------- per-node group adapter: 4 nodes per 256-thr block -------
__global__ __launch_bounds__(256) void adapter_kernel(
    const float* __restrict__ feats, const int* __restrict__ grp,
    const float* __restrict__ AW1, const float* __restrict__ Ab1,
    const float* __restrict__ AW2, const float* __restrict__ Ab2,
    float* __restrict__ out)
{
    const int wv = threadIdx.x >> 6;
    const int n = blockIdx.x * 4 + wv;
    const int lane = threadIdx.x & 63;
    __shared__ float f[4][F1D];
    f[wv][lane]      = feats[(size_t)n * F1D + lane];
    f[wv][lane + 64] = feats[(size_t)n * F1D + 64 + lane];
    // wave-local LDS: compiler waitcnt orders reads (no barrier needed)
    const int g = grp[n];
    const float* W1 = AW1 + (size_t)g * F1D * AD;
    const int a = lane & 31;
    const int half = lane >> 5;
    float hsum = 0.f;
    for (int d = 0; d < 64; ++d)
        hsum = fmaf(f[wv][half * 64 + d], W1[(half * 64 + d) * AD + a], hsum);
    hsum += __shfl_xor(hsum, 32);
    hsum = fmaxf(hsum + Ab1[g * AD + a], 0.f);
    float p = hsum * AW2[g * AD + a];
    #pragma unroll
    for (int mm = 1; mm < 32; mm <<= 1) p += __shfl_xor(p, mm);
    if (lane == 0) out[n] = p + Ab2[g];
}

// ---------------- host-side orchestration ----------------
extern "C" void kernel_launch(void* const* d_in, const int* in_sizes, int n_in,
                              void* d_out, int out_size, void* d_ws, size_t ws_size,
                              hipStream_t stream)
{
    const float* x_in   = (const float*)d_in[0];
    const float* eattr  = (const float*)d_in[1];
    const float* Wself  = (const float*)d_in[2];
    const float* Wnbr   = (const float*)d_in[3];
    const float* convb  = (const float*)d_in[4];
    const float* gamma  = (const float*)d_in[5];
    const float* beta   = (const float*)d_in[6];
    const float* bnmean = (const float*)d_in[7];
    const float* bnvar  = (const float*)d_in[8];
    const float* Wqkv   = (const float*)d_in[9];
    const float* bqkv   = (const float*)d_in[10];
    const float* Wo     = (const float*)d_in[11];
    const float* bo     = (const float*)d_in[12];
    const float* fc1W   = (const float*)d_in[13];
    const float* fc1b   = (const float*)d_in[14];
    const float* AW1    = (const float*)d_in[15];
    const float* Ab1    = (const float*)d_in[16];
    const float* AW2    = (const float*)d_in[17];
    const float* Ab2    = (const float*)d_in[18];
    const int*   eidx   = (const int*)d_in[19];
    const int*   grp    = (const int*)d_in[20];
    const int* srcArr = eidx;
    const int* dstArr = eidx + NE;

    float* fws = (float*)d_ws;
    const size_t NM = (size_t)NN * DIM;
    float* bufA  = fws;                  // x L0 / x L2 (residual)
    float* bufB  = fws + NM;             // attn op0 scratch
    float* bufC  = fws + 2 * NM;         // x L1 / attn op1 scratch
    float* feats = fws + 3 * NM;         // NN x F1D
    float* mpart = fws + 3 * NM + NM / 2;         // [4][NN][NH]
    float* lpart = mpart + 4 * NN * NH;
    u16* up = (u16*)(lpart + 4 * NN * NH);
    u16* xpAh = up;             u16* xpAl = xpAh + NM;   // x planes ping
    u16* xpBh = xpAl + NM;      u16* xpBl = xpBh + NM;   // x planes pong
    u16* aggh = xpBl + NM;      u16* aggl = aggh + NM;   // agg planes
    u16* qh = aggl + NM;        u16* ql = qh + NM;       // Q planes
    u16* kh = ql + NM;          u16* kl = kh + NM;       // K planes / Wo out
    u16* vt = kl + NM;                                   // V^T fp16 [256][NN]
    u16* wcath = vt + NM;                                // [3][256][512]
    u16* wcatl = wcath + 3 * 131072;
    u16* wt4h  = wcatl + 3 * 131072;                     // [4][256][256] qkv+wo
    u16* wt4l  = wt4h + 4 * 65536;
    u16* fc1h  = wt4l + 4 * 65536;                       // [128][256]
    u16* fc1l  = fc1h + 32768;
    int*   esrc = (int*)(fc1l + 32768);                  // NE
    float* ewt  = (float*)(esrc + NE);                   // NE
    int* off    = (int*)(ewt + NE);                      // NN+1
    int* cur    = off + NN + 1;                          // NN
    float* outp = (float*)d_out;

    // 4 normalized-fp16 attn partials in buffers dead during attention:
    u16* o0 = (u16*)bufB;
    u16* o1 = (u16*)bufC;
    u16* o2 = xpAh;                      // xpA region (dead after qkv)
    u16* o3 = xpBh;                      // xpB region (dead after qkv)

    // fused prep: all converts + zero(cur)
    prep_kernel<<<1700, 256, 0, stream>>>(
        x_in, Wself, Wnbr, Wqkv, Wo, fc1W,
        xpAh, xpAl, wcath, wcatl, wt4h, wt4l, fc1h, fc1l, cur);

    // CSR build (csr_scan zeroes cur for csr_fill)
    csr_count<<<NE / 256, 256, 0, stream>>>(dstArr, cur);
    csr_scan<<<1, 1024, 0, stream>>>(cur, off);
    csr_fill<<<NE / 256, 256, 0, stream>>>(dstArr, srcArr, eattr, off, cur, esrc, ewt);

    const dim3 gc(DIM / 64, NN / 32);    // 32-row conv tiles: 512 blocks
    // conv layer 0: x_in -> bufA (fp32) + xpB planes
    agg_kernel<false><<<NN / 4, 256, 0, stream>>>(x_in, esrc, ewt, off, aggh, aggl);
    conv_mfma<1><<<gc, 256, 0, stream>>>(
        xpAh, xpAl, aggh, aggl, wcath, wcatl, convb,
        gamma, beta, bnmean, bnvar, bufA, xpBh, xpBl);
    // conv layer 1: bufA -> bufC + xpA planes
    agg_kernel<false><<<NN / 4, 256, 0, stream>>>(bufA, esrc, ewt, off, aggh, aggl);
    conv_mfma<1><<<gc, 256, 0, stream>>>(
        xpBh, xpBl, aggh, aggl, wcath + 131072, wcatl + 131072, convb + DIM,
        gamma + DIM, beta + DIM, bnmean + DIM, bnvar + DIM, bufC, xpAh, xpAl);
    // conv layer 2 (edge-weighted, bias only): bufC -> bufA + xpB planes
    agg_kernel<true><<<NN / 4, 256, 0, stream>>>(bufC, esrc, ewt, off, aggh, aggl);
    conv_mfma<0><<<gc, 256, 0, stream>>>(
        xpAh, xpAl, aggh, aggl, wcath + 262144, wcatl + 262144, convb + 2 * DIM,
        nullptr, nullptr, nullptr, nullptr, bufA, xpBh, xpBl);

    // QKV (fp16 3-pass MFMA) -> Q/K planes (Q/8) + V^T
    qkv_mfma<<<dim3(12, NN / 64), 256, 0, stream>>>(
        xpBh, xpBl, wt4h, wt4l, bqkv, qh, ql, kh, kl, vt);

    // flash attention (8-wave QB=128, swizzled dbuf, 4-way key split)
    attn_kernel<<<dim3(NN / QB, NH, NSPLIT), 512, 0, stream>>>(
        qh, ql, kh, kl, vt, o0, o1, o2, o3, mpart, lpart);

    // Wo + residual with FUSED 4-partial combine: kh/kl = planes(...)
    wo_fused<<<dim3(DIM / 64, NN / 32), 256, 0, stream>>>(
        o0, o1, o2, o3, mpart, lpart,
        wt4h + 3 * 65536, wt4l + 3 * 65536, bo, bufA, kh, kl);

    // fc1 + ELU (fp16 3-pass MFMA): feats = elu(x' @ fc1W + fc1b)
    fc1_mfma<<<dim3(F1D / 64, NN / 32), 256, 0, stream>>>(
        kh, kl, fc1h, fc1l, fc1b, feats);

    // adapter routing -> out
    adapter_kernel<<<NN / 4, 256, 0, stream>>>(feats, grp, AW1, Ab1, AW2, Ab2, outp);
}